// Round 2
// baseline (7714.496 us; speedup 1.0000x reference)
//
#include <hip/hip_runtime.h>
#include <stdint.h>

#define N_NODES 50000
#define N_EDGES 800000
#define B_GRAPHS 64
#define D_DIM 64
#define HD 128
#define G_GAUSS 50
#define HID_DIM 128
#define L_LAYERS 3
#define LN2 0.69314718055994530942f
#define PI_OVER_8 0.39269908169872414f

__device__ __forceinline__ float sspf(float x) {
    // softplus(x) - ln2, stable
    float ax = fabsf(x);
    return fmaxf(x, 0.f) + __logf(1.f + __expf(-ax)) - LN2;
}
__device__ __forceinline__ void ld8(const float* __restrict__ p, float* wf) {
    float4 a = *(const float4*)p;
    float4 b = *(const float4*)(p + 4);
    wf[0] = a.x; wf[1] = a.y; wf[2] = a.z; wf[3] = a.w;
    wf[4] = b.x; wf[5] = b.y; wf[6] = b.z; wf[7] = b.w;
}
// monotone float<->int order mapping for atomicMax on floats
__device__ __forceinline__ int f2ord(float f) {
    int i = __float_as_int(f);
    return (i >= 0) ? i : (i ^ 0x7fffffff);
}
__device__ __forceinline__ float ord2f(int i) {
    return __int_as_float((i >= 0) ? i : (i ^ 0x7fffffff));
}

// ---------------- edge geometry + cutoff compaction ----------------
__global__ void repr_edge_geom(const float* __restrict__ R,
                               const int* __restrict__ src, const int* __restrict__ dst,
                               float* __restrict__ r_e, float* __restrict__ C_e,
                               int* __restrict__ elist, int* __restrict__ counter) {
    int e = blockIdx.x * blockDim.x + threadIdx.x;
    if (e >= N_EDGES) return;
    int s = src[e], d = dst[e];
    float dx = R[3*s+0] - R[3*d+0];
    float dy = R[3*s+1] - R[3*d+1];
    float dz = R[3*s+2] - R[3*d+2];
    float r = sqrtf(dx*dx + dy*dy + dz*dz);
    r_e[e] = r;
    float C = 0.f;
    if (r < 8.0f) {
        C = 0.5f * (__cosf(r * PI_OVER_8) + 1.f);
        int pos = atomicAdd(counter, 1);
        elist[pos] = e;
    }
    C_e[e] = C;
}

// ---------------- x init from embedding table ----------------
__global__ void repr_embed(const float* __restrict__ emb, const int* __restrict__ Z,
                           float* __restrict__ x) {
    int i = blockIdx.x * blockDim.x + threadIdx.x;
    if (i >= N_NODES * D_DIM) return;
    int n = i >> 6, d = i & 63;
    x[i] = emb[Z[n] * D_DIM + d];
}

// ---------------- h = x @ fc_w ; el/er attention logits ----------------
__global__ void repr_h(const float* __restrict__ x, const float* __restrict__ fc_w,
                       const float* __restrict__ attn_l, const float* __restrict__ attn_r,
                       float* __restrict__ h, float* __restrict__ el, float* __restrict__ er) {
    int wave = threadIdx.x >> 6, lane = threadIdx.x & 63;
    int n = blockIdx.x * 4 + wave;
    if (n >= N_NODES) return;
    float xv = x[n * 64 + lane];
    float a0 = 0.f, a1 = 0.f;
    #pragma unroll 8
    for (int k = 0; k < 64; k++) {
        float xk = __shfl(xv, k, 64);
        a0 = fmaf(xk, fc_w[k * 128 + lane], a0);
        a1 = fmaf(xk, fc_w[k * 128 + 64 + lane], a1);
    }
    h[n * 128 + lane] = a0;
    h[n * 128 + 64 + lane] = a1;
    float p0 = a0 * attn_l[lane];
    float p1 = a1 * attn_l[64 + lane];
    float q0 = a0 * attn_r[lane];
    float q1 = a1 * attn_r[64 + lane];
    #pragma unroll
    for (int off = 32; off > 0; off >>= 1) {
        p0 += __shfl_xor(p0, off, 64);
        p1 += __shfl_xor(p1, off, 64);
        q0 += __shfl_xor(q0, off, 64);
        q1 += __shfl_xor(q1, off, 64);
    }
    if (lane == 0) {
        el[n * 2] = p0; el[n * 2 + 1] = p1;
        er[n * 2] = q0; er[n * 2 + 1] = q1;
    }
}

// ---------------- pass 1: e = leaky(el[s]+er[d]); segment max ----------------
__global__ void repr_logits1(const float* __restrict__ el, const float* __restrict__ er,
                             const int* __restrict__ src, const int* __restrict__ dst,
                             float* __restrict__ ebuf, int* __restrict__ mord) {
    int e = blockIdx.x * blockDim.x + threadIdx.x;
    if (e >= N_EDGES) return;
    int s = src[e], d = dst[e];
    #pragma unroll
    for (int hh = 0; hh < 2; hh++) {
        float v = el[s * 2 + hh] + er[d * 2 + hh];
        v = v >= 0.f ? v : 0.2f * v;
        ebuf[e * 2 + hh] = v;
        atomicMax(&mord[d * 2 + hh], f2ord(v));
    }
}

// ---------------- pass 2: ex = exp(e - m[d]); segment sum ----------------
__global__ void repr_logits2(const int* __restrict__ mord, const int* __restrict__ dst,
                             float* __restrict__ ebuf, float* __restrict__ denom) {
    int e = blockIdx.x * blockDim.x + threadIdx.x;
    if (e >= N_EDGES) return;
    int d = dst[e];
    #pragma unroll
    for (int hh = 0; hh < 2; hh++) {
        float m = ord2f(mord[d * 2 + hh]);
        float ex = __expf(ebuf[e * 2 + hh] - m);
        ebuf[e * 2 + hh] = ex;
        atomicAdd(&denom[d * 2 + hh], ex);
    }
}

// ---------------- fused filter-net + message + scatter ----------------
#define TILE 64
__global__ __launch_bounds__(256, 3) void repr_msg(
    const float* __restrict__ r_e, const float* __restrict__ C_e,
    const int* __restrict__ src, const int* __restrict__ dst,
    const int* __restrict__ elist, const int* __restrict__ counter,
    const float* __restrict__ eex, const float* __restrict__ denom,
    const float* __restrict__ h,
    const float* __restrict__ offs, const float* __restrict__ widths,
    const float* __restrict__ w1, const float* __restrict__ b1,
    const float* __restrict__ w2, const float* __restrict__ b2,
    float* __restrict__ agg)
{
    __shared__ float gs_s[TILE][52];
    __shared__ float hid_s[TILE][132];
    __shared__ float r_s[TILE], C_s[TILE];
    __shared__ float alpha_s[TILE][2];
    __shared__ int src_s[TILE], dst_s[TILE];
    __shared__ float off_s[G_GAUSS], coef_s[G_GAUSS];

    int EC = counter[0];
    int base = blockIdx.x * TILE;
    if (base >= EC) return;
    int nvalid = min(TILE, EC - base);
    int tid = threadIdx.x;

    if (tid < G_GAUSS) {
        float w = widths[tid];
        off_s[tid] = offs[tid];
        coef_s[tid] = -0.5f / (w * w);
    }
    if (tid < TILE) {
        if (tid < nvalid) {
            int e = elist[base + tid];
            int s = src[e], d = dst[e];
            src_s[tid] = s; dst_s[tid] = d;
            r_s[tid] = r_e[e];
            C_s[tid] = C_e[e];
            alpha_s[tid][0] = eex[e * 2 + 0] / denom[d * 2 + 0];
            alpha_s[tid][1] = eex[e * 2 + 1] / denom[d * 2 + 1];
        } else {
            src_s[tid] = 0; dst_s[tid] = 0;
            r_s[tid] = 0.f; C_s[tid] = 0.f;
            alpha_s[tid][0] = 0.f; alpha_s[tid][1] = 0.f;
        }
    }
    __syncthreads();

    // fill gaussian features tile
    for (int i = tid; i < TILE * G_GAUSS; i += 256) {
        int row = i / G_GAUSS, k = i - row * G_GAUSS;
        float dr = r_s[row] - off_s[k];
        gs_s[row][k] = __expf(coef_s[k] * dr * dr);
    }
    __syncthreads();

    const int cg = tid & 15;   // cols cg*8 .. cg*8+7
    const int rg = tid >> 4;   // rows rg*4 .. rg*4+3
    const int rg4 = rg * 4;
    const int c0 = cg * 8;

    // stage 1: hid = ssp(gs @ W1 + b1)   (64x50)@(50x128)
    float acc[4][8];
    #pragma unroll
    for (int r = 0; r < 4; r++)
        #pragma unroll
        for (int c = 0; c < 8; c++) acc[r][c] = 0.f;

    for (int k0 = 0; k0 < 48; k0 += 4) {
        float av[4][4];
        #pragma unroll
        for (int r = 0; r < 4; r++)
            *(float4*)av[r] = *(const float4*)&gs_s[rg4 + r][k0];
        #pragma unroll
        for (int kk = 0; kk < 4; kk++) {
            float wf[8]; ld8(w1 + (k0 + kk) * HID_DIM + c0, wf);
            #pragma unroll
            for (int r = 0; r < 4; r++)
                #pragma unroll
                for (int c = 0; c < 8; c++)
                    acc[r][c] = fmaf(av[r][kk], wf[c], acc[r][c]);
        }
    }
    #pragma unroll
    for (int k = 48; k < 50; k++) {
        float wf[8]; ld8(w1 + k * HID_DIM + c0, wf);
        #pragma unroll
        for (int r = 0; r < 4; r++) {
            float a = gs_s[rg4 + r][k];
            #pragma unroll
            for (int c = 0; c < 8; c++)
                acc[r][c] = fmaf(a, wf[c], acc[r][c]);
        }
    }
    {
        float bf[8]; ld8(b1 + c0, bf);
        #pragma unroll
        for (int r = 0; r < 4; r++)
            #pragma unroll
            for (int c = 0; c < 8; c++)
                hid_s[rg4 + r][c0 + c] = sspf(acc[r][c] + bf[c]);
    }
    __syncthreads();

    // stage 2: wv = hid @ W2 + b2   (64x128)@(128x128)
    float acc2[4][8];
    #pragma unroll
    for (int r = 0; r < 4; r++)
        #pragma unroll
        for (int c = 0; c < 8; c++) acc2[r][c] = 0.f;

    for (int k0 = 0; k0 < HID_DIM; k0 += 4) {
        float av[4][4];
        #pragma unroll
        for (int r = 0; r < 4; r++)
            *(float4*)av[r] = *(const float4*)&hid_s[rg4 + r][k0];
        #pragma unroll
        for (int kk = 0; kk < 4; kk++) {
            float wf[8]; ld8(w2 + (k0 + kk) * HD + c0, wf);
            #pragma unroll
            for (int r = 0; r < 4; r++)
                #pragma unroll
                for (int c = 0; c < 8; c++)
                    acc2[r][c] = fmaf(av[r][kk], wf[c], acc2[r][c]);
        }
    }

    // epilogue: contrib = alpha * C * (wv+b2) * h[src], atomic into agg[dst]
    float b2f_[8]; ld8(b2 + c0, b2f_);
    int head = cg >> 3;
    #pragma unroll
    for (int r = 0; r < 4; r++) {
        int row = rg4 + r;
        float scale = C_s[row] * alpha_s[row][head];
        if (scale != 0.f) {
            int sn = src_s[row], dn = dst_s[row];
            const float* hp = h + (size_t)sn * HD + c0;
            float* ap = agg + (size_t)dn * HD + c0;
            float hv[8]; ld8(hp, hv);
            #pragma unroll
            for (int c = 0; c < 8; c++) {
                float msg = (acc2[r][c] + b2f_[c]) * hv[c] * scale;
                atomicAdd(ap + c, msg);
            }
        }
    }
}

// ---------------- node MLP: x += mlp(ssp(agg)) ----------------
__global__ void repr_node_mlp(const float* __restrict__ agg,
                              const float* __restrict__ w1, const float* __restrict__ b1,
                              const float* __restrict__ w2, const float* __restrict__ b2,
                              float* __restrict__ x) {
    int wave = threadIdx.x >> 6, lane = threadIdx.x & 63;
    int n = blockIdx.x * 4 + wave;
    if (n >= N_NODES) return;
    float t0 = sspf(agg[n * 128 + lane]);
    float t1 = sspf(agg[n * 128 + 64 + lane]);
    float a = 0.f;
    #pragma unroll 8
    for (int k = 0; k < 64; k++) {
        float u0 = __shfl(t0, k, 64);
        float u1 = __shfl(t1, k, 64);
        a = fmaf(u0, w1[k * 64 + lane], a);
        a = fmaf(u1, w1[(64 + k) * 64 + lane], a);
    }
    float v1 = sspf(a + b1[lane]);
    float b = 0.f;
    #pragma unroll 8
    for (int k = 0; k < 64; k++) {
        float u = __shfl(v1, k, 64);
        b = fmaf(u, w2[k * 64 + lane], b);
    }
    x[n * 64 + lane] += b + b2[lane];
}

// ---------------- output MLP + graph segment-sum ----------------
__global__ void repr_out(const float* __restrict__ x,
                         const float* __restrict__ w1, const float* __restrict__ b1,
                         const float* __restrict__ w2, const float* __restrict__ b2,
                         const int* __restrict__ gids, float* __restrict__ out_acc) {
    int wave = threadIdx.x >> 6, lane = threadIdx.x & 63;
    int n = blockIdx.x * 4 + wave;
    if (n >= N_NODES) return;
    float xv = x[n * 64 + lane];
    float a0 = 0.f, a1 = 0.f;
    #pragma unroll 8
    for (int k = 0; k < 64; k++) {
        float xk = __shfl(xv, k, 64);
        a0 = fmaf(xk, w1[k * 128 + lane], a0);
        a1 = fmaf(xk, w1[k * 128 + 64 + lane], a1);
    }
    float y0 = sspf(a0 + b1[lane]);
    float y1 = sspf(a1 + b1[64 + lane]);
    float s = y0 * w2[lane] + y1 * w2[64 + lane];
    #pragma unroll
    for (int off = 32; off > 0; off >>= 1) s += __shfl_xor(s, off, 64);
    if (lane == 0) {
        atomicAdd(&out_acc[gids[n]], s + b2[0]);
    }
}

__global__ void repr_final(const float* __restrict__ out_acc, float* __restrict__ out) {
    int i = threadIdx.x;
    if (i < B_GRAPHS) out[i] = out_acc[i];
}

extern "C" void kernel_launch(void* const* d_in, const int* in_sizes, int n_in,
                              void* d_out, int out_size, void* d_ws, size_t ws_size,
                              hipStream_t stream) {
    (void)in_sizes; (void)n_in; (void)out_size; (void)ws_size;
    const float* R      = (const float*)d_in[0];
    const int*   Z      = (const int*)d_in[1];
    const int*   src    = (const int*)d_in[2];
    const int*   dst    = (const int*)d_in[3];
    const int*   gids   = (const int*)d_in[4];
    const float* emb    = (const float*)d_in[5];
    const float* offs   = (const float*)d_in[6];
    const float* widths = (const float*)d_in[7];
    const float* fc_w   = (const float*)d_in[8];
    const float* attn_l = (const float*)d_in[9];
    const float* attn_r = (const float*)d_in[10];
    const float* fw1    = (const float*)d_in[11];
    const float* fb1    = (const float*)d_in[12];
    const float* fw2    = (const float*)d_in[13];
    const float* fb2    = (const float*)d_in[14];
    const float* mw1    = (const float*)d_in[15];
    const float* mb1    = (const float*)d_in[16];
    const float* mw2    = (const float*)d_in[17];
    const float* mb2    = (const float*)d_in[18];
    const float* ow1    = (const float*)d_in[19];
    const float* ob1    = (const float*)d_in[20];
    const float* ow2    = (const float*)d_in[21];
    const float* ob2    = (const float*)d_in[22];

    char* p = (char*)d_ws;
    float* x     = (float*)p; p += (size_t)N_NODES * 64 * 4;
    float* h     = (float*)p; p += (size_t)N_NODES * 128 * 4;
    float* el    = (float*)p; p += (size_t)N_NODES * 2 * 4;
    float* er    = (float*)p; p += (size_t)N_NODES * 2 * 4;
    float* denom = (float*)p; p += (size_t)N_NODES * 2 * 4;
    int*   mord  = (int*)p;   p += (size_t)N_NODES * 2 * 4;
    float* agg   = (float*)p; p += (size_t)N_NODES * 128 * 4;
    float* eex   = (float*)p; p += (size_t)N_EDGES * 2 * 4;
    float* r_e   = (float*)p; p += (size_t)N_EDGES * 4;
    float* C_e   = (float*)p; p += (size_t)N_EDGES * 4;
    int*   elist = (int*)p;   p += (size_t)N_EDGES * 4;
    int*   counter = (int*)p; p += 256;
    float* oacc  = (float*)p; p += 256;
    // total ~82 MB of d_ws

    hipMemsetAsync(counter, 0, 4, stream);
    hipMemsetAsync(oacc, 0, B_GRAPHS * 4, stream);

    repr_edge_geom<<<N_EDGES / 256, 256, 0, stream>>>(R, src, dst, r_e, C_e, elist, counter);
    repr_embed<<<(N_NODES * 64) / 256, 256, 0, stream>>>(emb, Z, x);

    for (int l = 0; l < L_LAYERS; l++) {
        hipMemsetAsync(denom, 0, (size_t)N_NODES * 2 * 4, stream);
        hipMemsetAsync(mord, 0x80, (size_t)N_NODES * 2 * 4, stream);  // ~ -3.4e38 in ord space
        hipMemsetAsync(agg, 0, (size_t)N_NODES * 128 * 4, stream);
        repr_h<<<(N_NODES + 3) / 4, 256, 0, stream>>>(
            x, fc_w + (size_t)l * 64 * 128, attn_l + l * 128, attn_r + l * 128, h, el, er);
        repr_logits1<<<N_EDGES / 256, 256, 0, stream>>>(el, er, src, dst, eex, mord);
        repr_logits2<<<N_EDGES / 256, 256, 0, stream>>>(mord, dst, eex, denom);
        repr_msg<<<N_EDGES / TILE, 256, 0, stream>>>(
            r_e, C_e, src, dst, elist, counter, eex, denom, h,
            offs, widths,
            fw1 + (size_t)l * G_GAUSS * HID_DIM, fb1 + l * HID_DIM,
            fw2 + (size_t)l * HID_DIM * HD, fb2 + l * HD, agg);
        repr_node_mlp<<<(N_NODES + 3) / 4, 256, 0, stream>>>(
            agg, mw1 + (size_t)l * 128 * 64, mb1 + l * 64,
            mw2 + (size_t)l * 64 * 64, mb2 + l * 64, x);
    }
    repr_out<<<(N_NODES + 3) / 4, 256, 0, stream>>>(x, ow1, ob1, ow2, ob2, gids, oacc);
    repr_final<<<1, 64, 0, stream>>>(oacc, (float*)d_out);
}

// Round 3
// 2806.577 us; speedup vs baseline: 2.7487x; 2.7487x over previous
//
#include <hip/hip_runtime.h>
#include <stdint.h>

#define N_NODES 50000
#define N_EDGES 800000
#define B_GRAPHS 64
#define D_DIM 64
#define HD 128
#define G_GAUSS 50
#define HID_DIM 128
#define L_LAYERS 3
#define LN2 0.69314718055994530942f
#define PI_OVER_8 0.39269908169872414f
#define NCHUNK 196            // ceil(50000/256)
#define BUF_LD 132            // padded leading dim for hid/msg LDS tile

__device__ __forceinline__ float sspf(float x) {
    float ax = fabsf(x);
    return fmaxf(x, 0.f) + __logf(1.f + __expf(-ax)) - LN2;
}
__device__ __forceinline__ void ld8(const float* __restrict__ p, float* wf) {
    float4 a = *(const float4*)p;
    float4 b = *(const float4*)(p + 4);
    wf[0] = a.x; wf[1] = a.y; wf[2] = a.z; wf[3] = a.w;
    wf[4] = b.x; wf[5] = b.y; wf[6] = b.z; wf[7] = b.w;
}
__device__ __forceinline__ int f2ord(float f) {
    int i = __float_as_int(f);
    return (i >= 0) ? i : (i ^ 0x7fffffff);
}
__device__ __forceinline__ float ord2f(int i) {
    return __int_as_float((i >= 0) ? i : (i ^ 0x7fffffff));
}

// ------------- histogram of surviving (r<cutoff) edges by dst -------------
__global__ void repr_hist(const float* __restrict__ R,
                          const int* __restrict__ src, const int* __restrict__ dst,
                          int* __restrict__ count) {
    int e = blockIdx.x * blockDim.x + threadIdx.x;
    if (e >= N_EDGES) return;
    int s = src[e], d = dst[e];
    float dx = R[3*s+0] - R[3*d+0];
    float dy = R[3*s+1] - R[3*d+1];
    float dz = R[3*s+2] - R[3*d+2];
    float r = sqrtf(dx*dx + dy*dy + dz*dz);
    if (r < 8.0f) {
        float C = 0.5f * (__cosf(r * PI_OVER_8) + 1.f);
        if (C > 0.f) atomicAdd(&count[d], 1);
    }
}

// ------------- 2-level exclusive scan over 50000 counts -------------
__global__ void repr_scanA(const int* __restrict__ cnt, int* __restrict__ excl,
                           int* __restrict__ bsum) {
    __shared__ int tmp[256];
    int t = threadIdx.x, b = blockIdx.x;
    int i = b * 256 + t;
    int v = (i < N_NODES) ? cnt[i] : 0;
    tmp[t] = v; __syncthreads();
    for (int off = 1; off < 256; off <<= 1) {
        int add = (t >= off) ? tmp[t - off] : 0;
        __syncthreads();
        tmp[t] += add;
        __syncthreads();
    }
    if (i < N_NODES) excl[i] = tmp[t] - v;
    if (t == 255) bsum[b] = tmp[255];
}
__global__ void repr_scanB(const int* __restrict__ bsum, int* __restrict__ bpref,
                           int* __restrict__ ecount) {
    __shared__ int tmp[256];
    int t = threadIdx.x;
    int v = (t < NCHUNK) ? bsum[t] : 0;
    tmp[t] = v; __syncthreads();
    for (int off = 1; off < 256; off <<= 1) {
        int add = (t >= off) ? tmp[t - off] : 0;
        __syncthreads();
        tmp[t] += add;
        __syncthreads();
    }
    if (t < NCHUNK) bpref[t] = tmp[t] - v;
    if (t == 255) ecount[0] = tmp[255];
}
__global__ void repr_scanC(const int* __restrict__ excl, const int* __restrict__ bpref,
                           int* __restrict__ cursor) {
    int i = blockIdx.x * 256 + threadIdx.x;
    if (i < N_NODES) cursor[i] = excl[i] + bpref[blockIdx.x];
}

// ------------- scatter surviving edges into dst-sorted order -------------
__global__ void repr_scatter(const float* __restrict__ R,
                             const int* __restrict__ src, const int* __restrict__ dst,
                             int* __restrict__ cursor,
                             int* __restrict__ seid, int* __restrict__ ssrc,
                             int* __restrict__ sdst) {
    int e = blockIdx.x * blockDim.x + threadIdx.x;
    if (e >= N_EDGES) return;
    int s = src[e], d = dst[e];
    float dx = R[3*s+0] - R[3*d+0];
    float dy = R[3*s+1] - R[3*d+1];
    float dz = R[3*s+2] - R[3*d+2];
    float r = sqrtf(dx*dx + dy*dy + dz*dz);
    if (r < 8.0f) {
        float C = 0.5f * (__cosf(r * PI_OVER_8) + 1.f);
        if (C > 0.f) {
            int pos = atomicAdd(&cursor[d], 1);
            seid[pos] = e; ssrc[pos] = s; sdst[pos] = d;
        }
    }
}

// ------------- x init from embedding table -------------
__global__ void repr_embed(const float* __restrict__ emb, const int* __restrict__ Z,
                           float* __restrict__ x) {
    int i = blockIdx.x * blockDim.x + threadIdx.x;
    if (i >= N_NODES * D_DIM) return;
    int n = i >> 6, d = i & 63;
    x[i] = emb[Z[n] * D_DIM + d];
}

// ------------- h = x @ fc_w ; attention logits -------------
__global__ void repr_h(const float* __restrict__ x, const float* __restrict__ fc_w,
                       const float* __restrict__ attn_l, const float* __restrict__ attn_r,
                       float* __restrict__ h, float* __restrict__ el, float* __restrict__ er) {
    int wave = threadIdx.x >> 6, lane = threadIdx.x & 63;
    int n = blockIdx.x * 4 + wave;
    if (n >= N_NODES) return;
    float xv = x[n * 64 + lane];
    float a0 = 0.f, a1 = 0.f;
    #pragma unroll 8
    for (int k = 0; k < 64; k++) {
        float xk = __shfl(xv, k, 64);
        a0 = fmaf(xk, fc_w[k * 128 + lane], a0);
        a1 = fmaf(xk, fc_w[k * 128 + 64 + lane], a1);
    }
    h[n * 128 + lane] = a0;
    h[n * 128 + 64 + lane] = a1;
    float p0 = a0 * attn_l[lane];
    float p1 = a1 * attn_l[64 + lane];
    float q0 = a0 * attn_r[lane];
    float q1 = a1 * attn_r[64 + lane];
    #pragma unroll
    for (int off = 32; off > 0; off >>= 1) {
        p0 += __shfl_xor(p0, off, 64);
        p1 += __shfl_xor(p1, off, 64);
        q0 += __shfl_xor(q0, off, 64);
        q1 += __shfl_xor(q1, off, 64);
    }
    if (lane == 0) {
        el[n * 2] = p0; el[n * 2 + 1] = p1;
        er[n * 2] = q0; er[n * 2 + 1] = q1;
    }
}

// ------------- softmax pass 1: leaky logits + segment max (all E edges) -------------
__global__ void repr_logits1(const float* __restrict__ el, const float* __restrict__ er,
                             const int* __restrict__ src, const int* __restrict__ dst,
                             float* __restrict__ ebuf, int* __restrict__ mord) {
    int e = blockIdx.x * blockDim.x + threadIdx.x;
    if (e >= N_EDGES) return;
    int s = src[e], d = dst[e];
    #pragma unroll
    for (int hh = 0; hh < 2; hh++) {
        float v = el[s * 2 + hh] + er[d * 2 + hh];
        v = v >= 0.f ? v : 0.2f * v;
        ebuf[e * 2 + hh] = v;
        atomicMax(&mord[d * 2 + hh], f2ord(v));
    }
}

// ------------- softmax pass 2: exp + segment sum -------------
__global__ void repr_logits2(const int* __restrict__ mord, const int* __restrict__ dst,
                             float* __restrict__ ebuf, float* __restrict__ denom) {
    int e = blockIdx.x * blockDim.x + threadIdx.x;
    if (e >= N_EDGES) return;
    int d = dst[e];
    #pragma unroll
    for (int hh = 0; hh < 2; hh++) {
        float m = ord2f(mord[d * 2 + hh]);
        float ex = __expf(ebuf[e * 2 + hh] - m);
        ebuf[e * 2 + hh] = ex;
        atomicAdd(&denom[d * 2 + hh], ex);
    }
}

// ------------- fused filter-net + message + segmented-reduce scatter -------------
#define TILE 64
__global__ __launch_bounds__(256, 3) void repr_msg(
    const float* __restrict__ R,
    const int* __restrict__ seid, const int* __restrict__ ssrc,
    const int* __restrict__ sdst, const int* __restrict__ ecount,
    const float* __restrict__ eex, const float* __restrict__ denom,
    const float* __restrict__ h,
    const float* __restrict__ offs, const float* __restrict__ widths,
    const float* __restrict__ w1, const float* __restrict__ b1,
    const float* __restrict__ w2, const float* __restrict__ b2,
    float* __restrict__ agg)
{
    __shared__ float gs_s[TILE][52];
    __shared__ float buf_s[TILE * BUF_LD];   // stage1 hid, then msg (reused)
    __shared__ float r_s[TILE];
    __shared__ float scale_s[TILE][2];
    __shared__ int src_s[TILE], dst_s[TILE];
    __shared__ int seg_start_s[TILE];
    __shared__ int nseg_s;
    __shared__ float off_s[G_GAUSS], coef_s[G_GAUSS];

    int EC = ecount[0];
    int base = blockIdx.x * TILE;
    if (base >= EC) return;
    int tid = threadIdx.x;

    if (tid < G_GAUSS) {
        float w = widths[tid];
        off_s[tid] = offs[tid];
        coef_s[tid] = -0.5f / (w * w);
    }
    if (tid < TILE) {
        int i = base + tid;
        int d, sn;
        float sc0, sc1, r;
        if (i < EC) {
            sn = ssrc[i]; d = sdst[i];
            int e = seid[i];
            float dx = R[3*sn+0] - R[3*d+0];
            float dy = R[3*sn+1] - R[3*d+1];
            float dz = R[3*sn+2] - R[3*d+2];
            r = sqrtf(dx*dx + dy*dy + dz*dz);
            float C = 0.5f * (__cosf(r * PI_OVER_8) + 1.f);
            float2 ex = *(const float2*)&eex[(size_t)e * 2];
            sc0 = C * ex.x / denom[d * 2 + 0];
            sc1 = C * ex.y / denom[d * 2 + 1];
        } else {
            sn = 0; d = -1; r = 0.f; sc0 = 0.f; sc1 = 0.f;
        }
        src_s[tid] = sn; dst_s[tid] = d;
        r_s[tid] = r;
        scale_s[tid][0] = sc0; scale_s[tid][1] = sc1;
        // segment detection within the (sorted) tile — wave 0 only
        int dprev = __shfl_up(d, 1, 64);
        bool flag = (tid == 0) || (d != dprev);
        unsigned long long mask = __ballot(flag);
        if (flag) seg_start_s[__popcll(mask & ((1ull << tid) - 1ull))] = tid;
        if (tid == 0) nseg_s = (int)__popcll(mask);
    }
    __syncthreads();

    // gaussian features tile (64 x 50)
    for (int i = tid; i < TILE * G_GAUSS; i += 256) {
        int row = i / G_GAUSS, k = i - row * G_GAUSS;
        float dr = r_s[row] - off_s[k];
        gs_s[row][k] = __expf(coef_s[k] * dr * dr);
    }
    __syncthreads();

    const int cg = tid & 15;   // cols c0..c0+7
    const int rg = tid >> 4;   // rows rg4..rg4+3
    const int rg4 = rg * 4;
    const int c0 = cg * 8;

    // stage 1: hid = ssp(gs @ W1 + b1)   (64x50)@(50x128)
    float acc[4][8];
    #pragma unroll
    for (int r = 0; r < 4; r++)
        #pragma unroll
        for (int c = 0; c < 8; c++) acc[r][c] = 0.f;

    for (int k0 = 0; k0 < 48; k0 += 4) {
        float av[4][4];
        #pragma unroll
        for (int r = 0; r < 4; r++)
            *(float4*)av[r] = *(const float4*)&gs_s[rg4 + r][k0];
        #pragma unroll
        for (int kk = 0; kk < 4; kk++) {
            float wf[8]; ld8(w1 + (k0 + kk) * HID_DIM + c0, wf);
            #pragma unroll
            for (int r = 0; r < 4; r++)
                #pragma unroll
                for (int c = 0; c < 8; c++)
                    acc[r][c] = fmaf(av[r][kk], wf[c], acc[r][c]);
        }
    }
    #pragma unroll
    for (int k = 48; k < 50; k++) {
        float wf[8]; ld8(w1 + k * HID_DIM + c0, wf);
        #pragma unroll
        for (int r = 0; r < 4; r++) {
            float a = gs_s[rg4 + r][k];
            #pragma unroll
            for (int c = 0; c < 8; c++)
                acc[r][c] = fmaf(a, wf[c], acc[r][c]);
        }
    }
    {
        float bf[8]; ld8(b1 + c0, bf);
        #pragma unroll
        for (int r = 0; r < 4; r++) {
            float4 lo, hi;
            lo.x = sspf(acc[r][0] + bf[0]); lo.y = sspf(acc[r][1] + bf[1]);
            lo.z = sspf(acc[r][2] + bf[2]); lo.w = sspf(acc[r][3] + bf[3]);
            hi.x = sspf(acc[r][4] + bf[4]); hi.y = sspf(acc[r][5] + bf[5]);
            hi.z = sspf(acc[r][6] + bf[6]); hi.w = sspf(acc[r][7] + bf[7]);
            *(float4*)&buf_s[(rg4 + r) * BUF_LD + c0] = lo;
            *(float4*)&buf_s[(rg4 + r) * BUF_LD + c0 + 4] = hi;
        }
    }
    __syncthreads();

    // stage 2: wv = hid @ W2   (64x128)@(128x128)
    float acc2[4][8];
    #pragma unroll
    for (int r = 0; r < 4; r++)
        #pragma unroll
        for (int c = 0; c < 8; c++) acc2[r][c] = 0.f;

    for (int k0 = 0; k0 < HID_DIM; k0 += 4) {
        float av[4][4];
        #pragma unroll
        for (int r = 0; r < 4; r++)
            *(float4*)av[r] = *(const float4*)&buf_s[(rg4 + r) * BUF_LD + k0];
        #pragma unroll
        for (int kk = 0; kk < 4; kk++) {
            float wf[8]; ld8(w2 + (k0 + kk) * HD + c0, wf);
            #pragma unroll
            for (int r = 0; r < 4; r++)
                #pragma unroll
                for (int c = 0; c < 8; c++)
                    acc2[r][c] = fmaf(av[r][kk], wf[c], acc2[r][c]);
        }
    }
    __syncthreads();   // everyone done reading hid from buf_s

    // epilogue: msg = alpha*C*(wv+b2)*h[src] into LDS
    {
        float b2f_[8]; ld8(b2 + c0, b2f_);
        int head = cg >> 3;
        #pragma unroll
        for (int r = 0; r < 4; r++) {
            int row = rg4 + r;
            float scale = scale_s[row][head];
            const float* hp = h + (size_t)src_s[row] * HD + c0;
            float hv[8]; ld8(hp, hv);
            float4 lo, hi;
            lo.x = (acc2[r][0] + b2f_[0]) * hv[0] * scale;
            lo.y = (acc2[r][1] + b2f_[1]) * hv[1] * scale;
            lo.z = (acc2[r][2] + b2f_[2]) * hv[2] * scale;
            lo.w = (acc2[r][3] + b2f_[3]) * hv[3] * scale;
            hi.x = (acc2[r][4] + b2f_[4]) * hv[4] * scale;
            hi.y = (acc2[r][5] + b2f_[5]) * hv[5] * scale;
            hi.z = (acc2[r][6] + b2f_[6]) * hv[6] * scale;
            hi.w = (acc2[r][7] + b2f_[7]) * hv[7] * scale;
            *(float4*)&buf_s[row * BUF_LD + c0] = lo;
            *(float4*)&buf_s[row * BUF_LD + c0 + 4] = hi;
        }
    }
    __syncthreads();

    // segmented reduction: one write per (dst,col) per tile.
    // interior segments own their dst exclusively -> plain store (agg pre-zeroed);
    // boundary segments (s==0 or s==nseg-1) may span tiles -> atomicAdd.
    {
        int nseg = nseg_s;
        int col = tid & 127;
        int sp = tid >> 7;
        for (int s = sp; s < nseg; s += 2) {
            int r0 = seg_start_s[s];
            int r1 = (s + 1 < nseg) ? seg_start_s[s + 1] : TILE;
            int d = dst_s[r0];
            if (d < 0) continue;
            float sum = 0.f;
            for (int r = r0; r < r1; r++) sum += buf_s[r * BUF_LD + col];
            float* ap = &agg[(size_t)d * HD + col];
            if (s == 0 || s == nseg - 1) atomicAdd(ap, sum);
            else *ap = sum;
        }
    }
}

// ------------- node MLP: x += mlp(ssp(agg)) -------------
__global__ void repr_node_mlp(const float* __restrict__ agg,
                              const float* __restrict__ w1, const float* __restrict__ b1,
                              const float* __restrict__ w2, const float* __restrict__ b2,
                              float* __restrict__ x) {
    int wave = threadIdx.x >> 6, lane = threadIdx.x & 63;
    int n = blockIdx.x * 4 + wave;
    if (n >= N_NODES) return;
    float t0 = sspf(agg[n * 128 + lane]);
    float t1 = sspf(agg[n * 128 + 64 + lane]);
    float a = 0.f;
    #pragma unroll 8
    for (int k = 0; k < 64; k++) {
        float u0 = __shfl(t0, k, 64);
        float u1 = __shfl(t1, k, 64);
        a = fmaf(u0, w1[k * 64 + lane], a);
        a = fmaf(u1, w1[(64 + k) * 64 + lane], a);
    }
    float v1 = sspf(a + b1[lane]);
    float b = 0.f;
    #pragma unroll 8
    for (int k = 0; k < 64; k++) {
        float u = __shfl(v1, k, 64);
        b = fmaf(u, w2[k * 64 + lane], b);
    }
    x[n * 64 + lane] += b + b2[lane];
}

// ------------- output MLP + graph segment-sum -------------
__global__ void repr_out(const float* __restrict__ x,
                         const float* __restrict__ w1, const float* __restrict__ b1,
                         const float* __restrict__ w2, const float* __restrict__ b2,
                         const int* __restrict__ gids, float* __restrict__ out_acc) {
    int wave = threadIdx.x >> 6, lane = threadIdx.x & 63;
    int n = blockIdx.x * 4 + wave;
    if (n >= N_NODES) return;
    float xv = x[n * 64 + lane];
    float a0 = 0.f, a1 = 0.f;
    #pragma unroll 8
    for (int k = 0; k < 64; k++) {
        float xk = __shfl(xv, k, 64);
        a0 = fmaf(xk, w1[k * 128 + lane], a0);
        a1 = fmaf(xk, w1[k * 128 + 64 + lane], a1);
    }
    float y0 = sspf(a0 + b1[lane]);
    float y1 = sspf(a1 + b1[64 + lane]);
    float s = y0 * w2[lane] + y1 * w2[64 + lane];
    #pragma unroll
    for (int off = 32; off > 0; off >>= 1) s += __shfl_xor(s, off, 64);
    if (lane == 0) atomicAdd(&out_acc[gids[n]], s + b2[0]);
}

__global__ void repr_final(const float* __restrict__ out_acc, float* __restrict__ out) {
    int i = threadIdx.x;
    if (i < B_GRAPHS) out[i] = out_acc[i];
}

extern "C" void kernel_launch(void* const* d_in, const int* in_sizes, int n_in,
                              void* d_out, int out_size, void* d_ws, size_t ws_size,
                              hipStream_t stream) {
    (void)in_sizes; (void)n_in; (void)out_size; (void)ws_size;
    const float* R      = (const float*)d_in[0];
    const int*   Z      = (const int*)d_in[1];
    const int*   src    = (const int*)d_in[2];
    const int*   dst    = (const int*)d_in[3];
    const int*   gids   = (const int*)d_in[4];
    const float* emb    = (const float*)d_in[5];
    const float* offs   = (const float*)d_in[6];
    const float* widths = (const float*)d_in[7];
    const float* fc_w   = (const float*)d_in[8];
    const float* attn_l = (const float*)d_in[9];
    const float* attn_r = (const float*)d_in[10];
    const float* fw1    = (const float*)d_in[11];
    const float* fb1    = (const float*)d_in[12];
    const float* fw2    = (const float*)d_in[13];
    const float* fb2    = (const float*)d_in[14];
    const float* mw1    = (const float*)d_in[15];
    const float* mb1    = (const float*)d_in[16];
    const float* mw2    = (const float*)d_in[17];
    const float* mb2    = (const float*)d_in[18];
    const float* ow1    = (const float*)d_in[19];
    const float* ob1    = (const float*)d_in[20];
    const float* ow2    = (const float*)d_in[21];
    const float* ob2    = (const float*)d_in[22];

    char* p = (char*)d_ws;
    float* x     = (float*)p; p += (size_t)N_NODES * 64 * 4;     // 12.8 MB
    float* h     = (float*)p; p += (size_t)N_NODES * 128 * 4;    // 25.6 MB
    float* el    = (float*)p; p += (size_t)N_NODES * 2 * 4;
    float* er    = (float*)p; p += (size_t)N_NODES * 2 * 4;
    float* denom = (float*)p; p += (size_t)N_NODES * 2 * 4;
    int*   mord  = (int*)p;   p += (size_t)N_NODES * 2 * 4;
    float* agg   = (float*)p; p += (size_t)N_NODES * 128 * 4;    // 25.6 MB
    float* eex   = (float*)p; p += (size_t)N_EDGES * 2 * 4;      // 6.4 MB
    int*   seid  = (int*)p;   p += (size_t)N_EDGES * 4;          // 3.2 MB
    int*   ssrc  = (int*)p;   p += (size_t)N_EDGES * 4;          // 3.2 MB
    int*   sdst  = (int*)p;   p += (size_t)N_EDGES * 4;          // 3.2 MB
    int*   bsum  = (int*)p;   p += 1024;
    int*   bpref = (int*)p;   p += 1024;
    int*   ecount= (int*)p;   p += 256;
    float* oacc  = (float*)p; p += 256;
    // scan temporaries aliased into x (x is only written by repr_embed, which
    // runs strictly after repr_scatter in stream order):
    int* count  = (int*)x;                        // 200 KB
    int* excl   = (int*)((char*)x + 256 * 1024);  // 200 KB
    int* cursor = (int*)((char*)x + 512 * 1024);  // 200 KB
    // total dedicated ~81.6 MB (same footprint as round 2)

    hipMemsetAsync(count, 0, N_NODES * 4, stream);
    hipMemsetAsync(oacc, 0, B_GRAPHS * 4, stream);

    // one-time dst-sorted compacted edge list (dst static across layers)
    repr_hist<<<N_EDGES / 256, 256, 0, stream>>>(R, src, dst, count);
    repr_scanA<<<NCHUNK, 256, 0, stream>>>(count, excl, bsum);
    repr_scanB<<<1, 256, 0, stream>>>(bsum, bpref, ecount);
    repr_scanC<<<NCHUNK, 256, 0, stream>>>(excl, bpref, cursor);
    repr_scatter<<<N_EDGES / 256, 256, 0, stream>>>(R, src, dst, cursor, seid, ssrc, sdst);
    repr_embed<<<(N_NODES * 64) / 256, 256, 0, stream>>>(emb, Z, x);

    for (int l = 0; l < L_LAYERS; l++) {
        hipMemsetAsync(denom, 0, (size_t)N_NODES * 2 * 4, stream);
        hipMemsetAsync(mord, 0x80, (size_t)N_NODES * 2 * 4, stream);  // ~-3.4e38 in ord space
        hipMemsetAsync(agg, 0, (size_t)N_NODES * 128 * 4, stream);
        repr_h<<<(N_NODES + 3) / 4, 256, 0, stream>>>(
            x, fc_w + (size_t)l * 64 * 128, attn_l + l * 128, attn_r + l * 128, h, el, er);
        repr_logits1<<<N_EDGES / 256, 256, 0, stream>>>(el, er, src, dst, eex, mord);
        repr_logits2<<<N_EDGES / 256, 256, 0, stream>>>(mord, dst, eex, denom);
        repr_msg<<<N_EDGES / TILE, 256, 0, stream>>>(
            R, seid, ssrc, sdst, ecount, eex, denom, h, offs, widths,
            fw1 + (size_t)l * G_GAUSS * HID_DIM, fb1 + l * HID_DIM,
            fw2 + (size_t)l * HID_DIM * HD, fb2 + l * HD, agg);
        repr_node_mlp<<<(N_NODES + 3) / 4, 256, 0, stream>>>(
            agg, mw1 + (size_t)l * 128 * 64, mb1 + l * 64,
            mw2 + (size_t)l * 64 * 64, mb2 + l * 64, x);
    }
    repr_out<<<(N_NODES + 3) / 4, 256, 0, stream>>>(x, ow1, ob1, ow2, ob2, gids, oacc);
    repr_final<<<1, 64, 0, stream>>>(oacc, (float*)d_out);
}

// Round 4
// 2421.329 us; speedup vs baseline: 3.1861x; 1.1591x over previous
//
#include <hip/hip_runtime.h>
#include <stdint.h>

#define N_NODES 50000
#define N_EDGES 800000
#define B_GRAPHS 64
#define D_DIM 64
#define HD 128
#define G_GAUSS 50
#define HID_DIM 128
#define L_LAYERS 3
#define LN2 0.69314718055994530942f
#define PI_OVER_8 0.39269908169872414f
#define NCHUNK 196            // ceil(50000/256)
#define BUF_LD 132            // padded leading dim for hid/msg LDS tile

__device__ __forceinline__ float sspf(float x) {
    float ax = fabsf(x);
    return fmaxf(x, 0.f) + __logf(1.f + __expf(-ax)) - LN2;
}
// load two float4 chunks at columns cA and cB of row pointer p
__device__ __forceinline__ void ld4x2(const float* __restrict__ p, int cA, int cB, float* wf) {
    float4 a = *(const float4*)(p + cA);
    float4 b = *(const float4*)(p + cB);
    wf[0] = a.x; wf[1] = a.y; wf[2] = a.z; wf[3] = a.w;
    wf[4] = b.x; wf[5] = b.y; wf[6] = b.z; wf[7] = b.w;
}
__device__ __forceinline__ int f2ord(float f) {
    int i = __float_as_int(f);
    return (i >= 0) ? i : (i ^ 0x7fffffff);
}
__device__ __forceinline__ float ord2f(int i) {
    return __int_as_float((i >= 0) ? i : (i ^ 0x7fffffff));
}

// ------------- histograms: all edges by dst, and survivors by dst -------------
__global__ void repr_hist(const float* __restrict__ R,
                          const int* __restrict__ src, const int* __restrict__ dst,
                          int* __restrict__ count_f, int* __restrict__ count_s) {
    int e = blockIdx.x * blockDim.x + threadIdx.x;
    if (e >= N_EDGES) return;
    int s = src[e], d = dst[e];
    atomicAdd(&count_f[d], 1);
    float dx = R[3*s+0] - R[3*d+0];
    float dy = R[3*s+1] - R[3*d+1];
    float dz = R[3*s+2] - R[3*d+2];
    float r = sqrtf(dx*dx + dy*dy + dz*dz);
    if (r < 8.0f) atomicAdd(&count_s[d], 1);
}

// ------------- 2-level exclusive scan over 50000 counts -------------
__global__ void repr_scanA(const int* __restrict__ cnt, int* __restrict__ excl,
                           int* __restrict__ bsum) {
    __shared__ int tmp[256];
    int t = threadIdx.x, b = blockIdx.x;
    int i = b * 256 + t;
    int v = (i < N_NODES) ? cnt[i] : 0;
    tmp[t] = v; __syncthreads();
    for (int off = 1; off < 256; off <<= 1) {
        int add = (t >= off) ? tmp[t - off] : 0;
        __syncthreads();
        tmp[t] += add;
        __syncthreads();
    }
    if (i < N_NODES) excl[i] = tmp[t] - v;
    if (t == 255) bsum[b] = tmp[255];
}
__global__ void repr_scanB(const int* __restrict__ bsum, int* __restrict__ bpref,
                           int* __restrict__ ecount) {
    __shared__ int tmp[256];
    int t = threadIdx.x;
    int v = (t < NCHUNK) ? bsum[t] : 0;
    tmp[t] = v; __syncthreads();
    for (int off = 1; off < 256; off <<= 1) {
        int add = (t >= off) ? tmp[t - off] : 0;
        __syncthreads();
        tmp[t] += add;
        __syncthreads();
    }
    if (t < NCHUNK) bpref[t] = tmp[t] - v;
    if (t == 255) ecount[0] = tmp[255];
}
__global__ void repr_scanC(const int* __restrict__ excl, const int* __restrict__ bpref,
                           int* __restrict__ cursor) {
    int i = blockIdx.x * 256 + threadIdx.x;
    if (i < N_NODES) cursor[i] = excl[i] + bpref[blockIdx.x];
}

// ------------- scatter: full dst-sorted list + survivor dst-sorted list -------------
__global__ void repr_scatter(const float* __restrict__ R,
                             const int* __restrict__ src, const int* __restrict__ dst,
                             int* __restrict__ cur_f, int* __restrict__ cur_s,
                             int* __restrict__ ssrc_f, int* __restrict__ sdst_f,
                             int* __restrict__ ssrc2, int* __restrict__ sdst2,
                             int* __restrict__ sidx2, float* __restrict__ r2) {
    int e = blockIdx.x * blockDim.x + threadIdx.x;
    if (e >= N_EDGES) return;
    int s = src[e], d = dst[e];
    float dx = R[3*s+0] - R[3*d+0];
    float dy = R[3*s+1] - R[3*d+1];
    float dz = R[3*s+2] - R[3*d+2];
    float r = sqrtf(dx*dx + dy*dy + dz*dz);
    int pos = atomicAdd(&cur_f[d], 1);
    ssrc_f[pos] = s; sdst_f[pos] = d;
    if (r < 8.0f) {
        int p2 = atomicAdd(&cur_s[d], 1);
        ssrc2[p2] = s; sdst2[p2] = d; sidx2[p2] = pos; r2[p2] = r;
    }
}

// ------------- x init from embedding table -------------
__global__ void repr_embed(const float* __restrict__ emb, const int* __restrict__ Z,
                           float* __restrict__ x) {
    int i = blockIdx.x * blockDim.x + threadIdx.x;
    if (i >= N_NODES * D_DIM) return;
    int n = i >> 6, d = i & 63;
    x[i] = emb[Z[n] * D_DIM + d];
}

// ------------- h = x @ fc_w ; attention logits -------------
__global__ void repr_h(const float* __restrict__ x, const float* __restrict__ fc_w,
                       const float* __restrict__ attn_l, const float* __restrict__ attn_r,
                       float* __restrict__ h, float* __restrict__ el, float* __restrict__ er) {
    int wave = threadIdx.x >> 6, lane = threadIdx.x & 63;
    int n = blockIdx.x * 4 + wave;
    if (n >= N_NODES) return;
    float xv = x[n * 64 + lane];
    float a0 = 0.f, a1 = 0.f;
    #pragma unroll 8
    for (int k = 0; k < 64; k++) {
        float xk = __shfl(xv, k, 64);
        a0 = fmaf(xk, fc_w[k * 128 + lane], a0);
        a1 = fmaf(xk, fc_w[k * 128 + 64 + lane], a1);
    }
    h[n * 128 + lane] = a0;
    h[n * 128 + 64 + lane] = a1;
    float p0 = a0 * attn_l[lane];
    float p1 = a1 * attn_l[64 + lane];
    float q0 = a0 * attn_r[lane];
    float q1 = a1 * attn_r[64 + lane];
    #pragma unroll
    for (int off = 32; off > 0; off >>= 1) {
        p0 += __shfl_xor(p0, off, 64);
        p1 += __shfl_xor(p1, off, 64);
        q0 += __shfl_xor(q0, off, 64);
        q1 += __shfl_xor(q1, off, 64);
    }
    if (lane == 0) {
        el[n * 2] = p0; el[n * 2 + 1] = p1;
        er[n * 2] = q0; er[n * 2 + 1] = q1;
    }
}

// ------------- softmax pass 1 over sorted edges: leaky + segmented max -------------
__global__ void repr_smax(const int* __restrict__ ssrc_f, const int* __restrict__ sdst_f,
                          const float* __restrict__ el, const float* __restrict__ er,
                          float* __restrict__ ebuf, int* __restrict__ mord) {
    int t = threadIdx.x;
    int e = blockIdx.x * 256 + t;
    int s = ssrc_f[e], d = sdst_f[e];
    float2 a = *(const float2*)&el[2 * s];
    float2 b = *(const float2*)&er[2 * d];
    float v0 = a.x + b.x; v0 = v0 >= 0.f ? v0 : 0.2f * v0;
    float v1 = a.y + b.y; v1 = v1 >= 0.f ? v1 : 0.2f * v1;
    float2 vo; vo.x = v0; vo.y = v1;
    *(float2*)&ebuf[2 * e] = vo;
    __shared__ float v0s[256], v1s[256];
    __shared__ int ds[256];
    v0s[t] = v0; v1s[t] = v1; ds[t] = d;
    __syncthreads();
    bool leader = (t == 0) || (ds[t - 1] != d);
    if (leader) {
        float m0 = v0, m1 = v1; int j = t + 1;
        while (j < 256 && ds[j] == d) { m0 = fmaxf(m0, v0s[j]); m1 = fmaxf(m1, v1s[j]); j++; }
        bool bound = (t == 0) || (j == 256);   // segment may span block boundary
        if (bound) {
            atomicMax(&mord[2 * d], f2ord(m0));
            atomicMax(&mord[2 * d + 1], f2ord(m1));
        } else {
            mord[2 * d] = f2ord(m0);
            mord[2 * d + 1] = f2ord(m1);
        }
    }
}

// ------------- softmax pass 2: exp + segmented sum -------------
__global__ void repr_ssum(const int* __restrict__ sdst_f, const int* __restrict__ mord,
                          float* __restrict__ ebuf, float* __restrict__ denom) {
    int t = threadIdx.x;
    int e = blockIdx.x * 256 + t;
    int d = sdst_f[e];
    float m0 = ord2f(mord[2 * d]), m1 = ord2f(mord[2 * d + 1]);
    float2 v = *(const float2*)&ebuf[2 * e];
    float ex0 = __expf(v.x - m0), ex1 = __expf(v.y - m1);
    float2 vo; vo.x = ex0; vo.y = ex1;
    *(float2*)&ebuf[2 * e] = vo;
    __shared__ float v0s[256], v1s[256];
    __shared__ int ds[256];
    v0s[t] = ex0; v1s[t] = ex1; ds[t] = d;
    __syncthreads();
    bool leader = (t == 0) || (ds[t - 1] != d);
    if (leader) {
        float s0 = ex0, s1 = ex1; int j = t + 1;
        while (j < 256 && ds[j] == d) { s0 += v0s[j]; s1 += v1s[j]; j++; }
        bool bound = (t == 0) || (j == 256);
        if (bound) {
            atomicAdd(&denom[2 * d], s0);
            atomicAdd(&denom[2 * d + 1], s1);
        } else {
            denom[2 * d] = s0;
            denom[2 * d + 1] = s1;
        }
    }
}

// ------------- fused filter-net + message + segmented-reduce scatter -------------
#define TILE 64
__global__ __launch_bounds__(256, 3) void repr_msg(
    const int* __restrict__ ssrc2, const int* __restrict__ sdst2,
    const int* __restrict__ sidx2, const float* __restrict__ r2,
    const int* __restrict__ ecount,
    const float* __restrict__ eex, const float* __restrict__ denom,
    const float* __restrict__ h,
    const float* __restrict__ offs, const float* __restrict__ widths,
    const float* __restrict__ w1, const float* __restrict__ b1,
    const float* __restrict__ w2, const float* __restrict__ b2,
    float* __restrict__ agg)
{
    __shared__ float gs_s[TILE][52];
    __shared__ float buf_s[TILE * BUF_LD];   // stage1 hid, then msg (reused)
    __shared__ float r_s[TILE];
    __shared__ float scale_s[TILE][2];
    __shared__ int src_s[TILE], dst_s[TILE];
    __shared__ int seg_start_s[TILE];
    __shared__ int nseg_s;
    __shared__ float off_s[G_GAUSS], coef_s[G_GAUSS];

    int EC = ecount[0];
    int base = blockIdx.x * TILE;
    if (base >= EC) return;
    int tid = threadIdx.x;

    if (tid < G_GAUSS) {
        float w = widths[tid];
        off_s[tid] = offs[tid];
        coef_s[tid] = -0.5f / (w * w);
    }
    if (tid < TILE) {
        int i = base + tid;
        int d, sn;
        float sc0, sc1, rr;
        if (i < EC) {
            sn = ssrc2[i]; d = sdst2[i];
            rr = r2[i];
            int fp = sidx2[i];
            float C = 0.5f * (__cosf(rr * PI_OVER_8) + 1.f);
            float2 ex = *(const float2*)&eex[(size_t)fp * 2];
            float2 dn = *(const float2*)&denom[(size_t)d * 2];
            sc0 = C * ex.x / dn.x;
            sc1 = C * ex.y / dn.y;
        } else {
            sn = 0; d = -1; rr = 0.f; sc0 = 0.f; sc1 = 0.f;
        }
        src_s[tid] = sn; dst_s[tid] = d;
        r_s[tid] = rr;
        scale_s[tid][0] = sc0; scale_s[tid][1] = sc1;
        // segment detection within the (sorted) tile — wave 0 only
        int dprev = __shfl_up(d, 1, 64);
        bool flag = (tid == 0) || (d != dprev);
        unsigned long long mask = __ballot(flag);
        if (flag) seg_start_s[__popcll(mask & ((1ull << tid) - 1ull))] = tid;
        if (tid == 0) nseg_s = (int)__popcll(mask);
    }
    __syncthreads();

    // gaussian features tile (64 x 50)
    for (int i = tid; i < TILE * G_GAUSS; i += 256) {
        int row = i / G_GAUSS, k = i - row * G_GAUSS;
        float dr = r_s[row] - off_s[k];
        gs_s[row][k] = __expf(coef_s[k] * dr * dr);
    }
    __syncthreads();

    const int cg = tid & 15;
    const int rg = tid >> 4;
    const int rg4 = rg * 4;
    // column remap for conflict-free LDS stores: thread owns cols
    // [4cg..4cg+3] (head 0) and [64+4cg..64+4cg+3] (head 1)
    const int c0a = cg * 4;
    const int c0b = 64 + cg * 4;

    // stage 1: hid = ssp(gs @ W1 + b1)   (64x50)@(50x128)
    float acc[4][8];
    #pragma unroll
    for (int r = 0; r < 4; r++)
        #pragma unroll
        for (int c = 0; c < 8; c++) acc[r][c] = 0.f;

    for (int k0 = 0; k0 < 48; k0 += 4) {
        float av[4][4];
        #pragma unroll
        for (int r = 0; r < 4; r++)
            *(float4*)av[r] = *(const float4*)&gs_s[rg4 + r][k0];
        #pragma unroll
        for (int kk = 0; kk < 4; kk++) {
            float wf[8]; ld4x2(w1 + (k0 + kk) * HID_DIM, c0a, c0b, wf);
            #pragma unroll
            for (int r = 0; r < 4; r++)
                #pragma unroll
                for (int c = 0; c < 8; c++)
                    acc[r][c] = fmaf(av[r][kk], wf[c], acc[r][c]);
        }
    }
    #pragma unroll
    for (int k = 48; k < 50; k++) {
        float wf[8]; ld4x2(w1 + k * HID_DIM, c0a, c0b, wf);
        #pragma unroll
        for (int r = 0; r < 4; r++) {
            float a = gs_s[rg4 + r][k];
            #pragma unroll
            for (int c = 0; c < 8; c++)
                acc[r][c] = fmaf(a, wf[c], acc[r][c]);
        }
    }
    {
        float bf[8]; ld4x2(b1, c0a, c0b, bf);
        #pragma unroll
        for (int r = 0; r < 4; r++) {
            float4 lo, hi;
            lo.x = sspf(acc[r][0] + bf[0]); lo.y = sspf(acc[r][1] + bf[1]);
            lo.z = sspf(acc[r][2] + bf[2]); lo.w = sspf(acc[r][3] + bf[3]);
            hi.x = sspf(acc[r][4] + bf[4]); hi.y = sspf(acc[r][5] + bf[5]);
            hi.z = sspf(acc[r][6] + bf[6]); hi.w = sspf(acc[r][7] + bf[7]);
            *(float4*)&buf_s[(rg4 + r) * BUF_LD + c0a] = lo;
            *(float4*)&buf_s[(rg4 + r) * BUF_LD + c0b] = hi;
        }
    }
    __syncthreads();

    // stage 2: wv = hid @ W2   (64x128)@(128x128)
    float acc2[4][8];
    #pragma unroll
    for (int r = 0; r < 4; r++)
        #pragma unroll
        for (int c = 0; c < 8; c++) acc2[r][c] = 0.f;

    for (int k0 = 0; k0 < HID_DIM; k0 += 4) {
        float av[4][4];
        #pragma unroll
        for (int r = 0; r < 4; r++)
            *(float4*)av[r] = *(const float4*)&buf_s[(rg4 + r) * BUF_LD + k0];
        #pragma unroll
        for (int kk = 0; kk < 4; kk++) {
            float wf[8]; ld4x2(w2 + (k0 + kk) * HD, c0a, c0b, wf);
            #pragma unroll
            for (int r = 0; r < 4; r++)
                #pragma unroll
                for (int c = 0; c < 8; c++)
                    acc2[r][c] = fmaf(av[r][kk], wf[c], acc2[r][c]);
        }
    }
    __syncthreads();   // everyone done reading hid from buf_s

    // epilogue: msg = alpha*C*(wv+b2)*h[src] into LDS
    {
        float b2f_[8]; ld4x2(b2, c0a, c0b, b2f_);
        #pragma unroll
        for (int r = 0; r < 4; r++) {
            int row = rg4 + r;
            float s0 = scale_s[row][0];   // cols 0..63  -> head 0
            float s1 = scale_s[row][1];   // cols 64..127 -> head 1
            const float* hp = h + (size_t)src_s[row] * HD;
            float hv[8]; ld4x2(hp, c0a, c0b, hv);
            float4 lo, hi;
            lo.x = (acc2[r][0] + b2f_[0]) * hv[0] * s0;
            lo.y = (acc2[r][1] + b2f_[1]) * hv[1] * s0;
            lo.z = (acc2[r][2] + b2f_[2]) * hv[2] * s0;
            lo.w = (acc2[r][3] + b2f_[3]) * hv[3] * s0;
            hi.x = (acc2[r][4] + b2f_[4]) * hv[4] * s1;
            hi.y = (acc2[r][5] + b2f_[5]) * hv[5] * s1;
            hi.z = (acc2[r][6] + b2f_[6]) * hv[6] * s1;
            hi.w = (acc2[r][7] + b2f_[7]) * hv[7] * s1;
            *(float4*)&buf_s[row * BUF_LD + c0a] = lo;
            *(float4*)&buf_s[row * BUF_LD + c0b] = hi;
        }
    }
    __syncthreads();

    // segmented reduction: one write per (dst,col) per tile.
    {
        int nseg = nseg_s;
        int col = tid & 127;
        int sp = tid >> 7;
        for (int s = sp; s < nseg; s += 2) {
            int r0 = seg_start_s[s];
            int r1 = (s + 1 < nseg) ? seg_start_s[s + 1] : TILE;
            int d = dst_s[r0];
            if (d < 0) continue;
            float sum = 0.f;
            for (int r = r0; r < r1; r++) sum += buf_s[r * BUF_LD + col];
            float* ap = &agg[(size_t)d * HD + col];
            if (s == 0 || s == nseg - 1) atomicAdd(ap, sum);
            else *ap = sum;
        }
    }
}

// ------------- node MLP: x += mlp(ssp(agg)) -------------
__global__ void repr_node_mlp(const float* __restrict__ agg,
                              const float* __restrict__ w1, const float* __restrict__ b1,
                              const float* __restrict__ w2, const float* __restrict__ b2,
                              float* __restrict__ x) {
    int wave = threadIdx.x >> 6, lane = threadIdx.x & 63;
    int n = blockIdx.x * 4 + wave;
    if (n >= N_NODES) return;
    float t0 = sspf(agg[n * 128 + lane]);
    float t1 = sspf(agg[n * 128 + 64 + lane]);
    float a = 0.f;
    #pragma unroll 8
    for (int k = 0; k < 64; k++) {
        float u0 = __shfl(t0, k, 64);
        float u1 = __shfl(t1, k, 64);
        a = fmaf(u0, w1[k * 64 + lane], a);
        a = fmaf(u1, w1[(64 + k) * 64 + lane], a);
    }
    float v1 = sspf(a + b1[lane]);
    float b = 0.f;
    #pragma unroll 8
    for (int k = 0; k < 64; k++) {
        float u = __shfl(v1, k, 64);
        b = fmaf(u, w2[k * 64 + lane], b);
    }
    x[n * 64 + lane] += b + b2[lane];
}

// ------------- output MLP + graph segment-sum -------------
__global__ void repr_out(const float* __restrict__ x,
                         const float* __restrict__ w1, const float* __restrict__ b1,
                         const float* __restrict__ w2, const float* __restrict__ b2,
                         const int* __restrict__ gids, float* __restrict__ out_acc) {
    int wave = threadIdx.x >> 6, lane = threadIdx.x & 63;
    int n = blockIdx.x * 4 + wave;
    if (n >= N_NODES) return;
    float xv = x[n * 64 + lane];
    float a0 = 0.f, a1 = 0.f;
    #pragma unroll 8
    for (int k = 0; k < 64; k++) {
        float xk = __shfl(xv, k, 64);
        a0 = fmaf(xk, w1[k * 128 + lane], a0);
        a1 = fmaf(xk, w1[k * 128 + 64 + lane], a1);
    }
    float y0 = sspf(a0 + b1[lane]);
    float y1 = sspf(a1 + b1[64 + lane]);
    float s = y0 * w2[lane] + y1 * w2[64 + lane];
    #pragma unroll
    for (int off = 32; off > 0; off >>= 1) s += __shfl_xor(s, off, 64);
    if (lane == 0) atomicAdd(&out_acc[gids[n]], s + b2[0]);
}

__global__ void repr_final(const float* __restrict__ out_acc, float* __restrict__ out) {
    int i = threadIdx.x;
    if (i < B_GRAPHS) out[i] = out_acc[i];
}

extern "C" void kernel_launch(void* const* d_in, const int* in_sizes, int n_in,
                              void* d_out, int out_size, void* d_ws, size_t ws_size,
                              hipStream_t stream) {
    (void)in_sizes; (void)n_in; (void)out_size; (void)ws_size;
    const float* R      = (const float*)d_in[0];
    const int*   Z      = (const int*)d_in[1];
    const int*   src    = (const int*)d_in[2];
    const int*   dst    = (const int*)d_in[3];
    const int*   gids   = (const int*)d_in[4];
    const float* emb    = (const float*)d_in[5];
    const float* offs   = (const float*)d_in[6];
    const float* widths = (const float*)d_in[7];
    const float* fc_w   = (const float*)d_in[8];
    const float* attn_l = (const float*)d_in[9];
    const float* attn_r = (const float*)d_in[10];
    const float* fw1    = (const float*)d_in[11];
    const float* fb1    = (const float*)d_in[12];
    const float* fw2    = (const float*)d_in[13];
    const float* fb2    = (const float*)d_in[14];
    const float* mw1    = (const float*)d_in[15];
    const float* mb1    = (const float*)d_in[16];
    const float* mw2    = (const float*)d_in[17];
    const float* mb2    = (const float*)d_in[18];
    const float* ow1    = (const float*)d_in[19];
    const float* ob1    = (const float*)d_in[20];
    const float* ow2    = (const float*)d_in[21];
    const float* ob2    = (const float*)d_in[22];

    char* p = (char*)d_ws;
    float* x      = (float*)p; p += (size_t)N_NODES * 64 * 4;     // 12.8 MB
    float* h      = (float*)p; p += (size_t)N_NODES * 128 * 4;    // 25.6 MB
    float* el     = (float*)p; p += (size_t)N_NODES * 2 * 4;
    float* er     = (float*)p; p += (size_t)N_NODES * 2 * 4;
    float* denom  = (float*)p; p += (size_t)N_NODES * 2 * 4;
    int*   mord   = (int*)p;   p += (size_t)N_NODES * 2 * 4;
    float* agg    = (float*)p; p += (size_t)N_NODES * 128 * 4;    // 25.6 MB
    float* ebuf   = (float*)p; p += (size_t)N_EDGES * 2 * 4;      // 6.4 MB (v then ex, sorted order)
    int*   ssrc_f = (int*)p;   p += (size_t)N_EDGES * 4;          // 3.2 MB
    int*   sdst_f = (int*)p;   p += (size_t)N_EDGES * 4;
    int*   ssrc2  = (int*)p;   p += (size_t)N_EDGES * 4;
    int*   sdst2  = (int*)p;   p += (size_t)N_EDGES * 4;
    int*   sidx2  = (int*)p;   p += (size_t)N_EDGES * 4;
    float* r2     = (float*)p; p += (size_t)N_EDGES * 4;
    int*   bsumA  = (int*)p;   p += 1024;
    int*   bprefA = (int*)p;   p += 1024;
    int*   bsumB  = (int*)p;   p += 1024;
    int*   bprefB = (int*)p;   p += 1024;
    int*   ecF    = (int*)p;   p += 256;
    int*   ecS    = (int*)p;   p += 256;
    float* oacc   = (float*)p; p += 256;
    // scan temporaries aliased into x (x written by repr_embed, strictly after
    // repr_scatter in stream order):
    int* count_f = (int*)x;                           // 200 KB each, 256 KB slots
    int* excl_f  = (int*)((char*)x + 256 * 1024);
    int* cur_f   = (int*)((char*)x + 512 * 1024);
    int* count_s = (int*)((char*)x + 768 * 1024);
    int* excl_s  = (int*)((char*)x + 1024 * 1024);
    int* cur_s   = (int*)((char*)x + 1280 * 1024);
    // total dedicated ~90.9 MB

    hipMemsetAsync(x, 0, 1536 * 1024, stream);           // zero count_f..cur_s
    hipMemsetAsync(oacc, 0, B_GRAPHS * 4, stream);

    // one-time: full dst-sorted list + survivor dst-sorted list
    repr_hist<<<N_EDGES / 256, 256, 0, stream>>>(R, src, dst, count_f, count_s);
    repr_scanA<<<NCHUNK, 256, 0, stream>>>(count_f, excl_f, bsumA);
    repr_scanB<<<1, 256, 0, stream>>>(bsumA, bprefA, ecF);
    repr_scanC<<<NCHUNK, 256, 0, stream>>>(excl_f, bprefA, cur_f);
    repr_scanA<<<NCHUNK, 256, 0, stream>>>(count_s, excl_s, bsumB);
    repr_scanB<<<1, 256, 0, stream>>>(bsumB, bprefB, ecS);
    repr_scanC<<<NCHUNK, 256, 0, stream>>>(excl_s, bprefB, cur_s);
    repr_scatter<<<N_EDGES / 256, 256, 0, stream>>>(
        R, src, dst, cur_f, cur_s, ssrc_f, sdst_f, ssrc2, sdst2, sidx2, r2);
    repr_embed<<<(N_NODES * 64) / 256, 256, 0, stream>>>(emb, Z, x);

    for (int l = 0; l < L_LAYERS; l++) {
        hipMemsetAsync(denom, 0, (size_t)N_NODES * 2 * 4, stream);
        hipMemsetAsync(mord, 0x80, (size_t)N_NODES * 2 * 4, stream);
        hipMemsetAsync(agg, 0, (size_t)N_NODES * 128 * 4, stream);
        repr_h<<<(N_NODES + 3) / 4, 256, 0, stream>>>(
            x, fc_w + (size_t)l * 64 * 128, attn_l + l * 128, attn_r + l * 128, h, el, er);
        repr_smax<<<N_EDGES / 256, 256, 0, stream>>>(ssrc_f, sdst_f, el, er, ebuf, mord);
        repr_ssum<<<N_EDGES / 256, 256, 0, stream>>>(sdst_f, mord, ebuf, denom);
        repr_msg<<<N_EDGES / TILE, 256, 0, stream>>>(
            ssrc2, sdst2, sidx2, r2, ecS, ebuf, denom, h, offs, widths,
            fw1 + (size_t)l * G_GAUSS * HID_DIM, fb1 + l * HID_DIM,
            fw2 + (size_t)l * HID_DIM * HD, fb2 + l * HD, agg);
        repr_node_mlp<<<(N_NODES + 3) / 4, 256, 0, stream>>>(
            agg, mw1 + (size_t)l * 128 * 64, mb1 + l * 64,
            mw2 + (size_t)l * 64 * 64, mb2 + l * 64, x);
    }
    repr_out<<<(N_NODES + 3) / 4, 256, 0, stream>>>(x, ow1, ob1, ow2, ob2, gids, oacc);
    repr_final<<<1, 64, 0, stream>>>(oacc, (float*)d_out);
}

// Round 5
// 1669.615 us; speedup vs baseline: 4.6205x; 1.4502x over previous
//
#include <hip/hip_runtime.h>
#include <stdint.h>

#define N_NODES 50000
#define N_EDGES 800000
#define B_GRAPHS 64
#define D_DIM 64
#define HD 128
#define G_GAUSS 50
#define HID_DIM 128
#define L_LAYERS 3
#define LN2 0.69314718055994530942f
#define PI_OVER_8 0.39269908169872414f
#define NCHUNK 196            // ceil(50000/256)

typedef __attribute__((ext_vector_type(8))) short bf16x8;
typedef __attribute__((ext_vector_type(4))) float f32x4;

__device__ __forceinline__ float sspf(float x) {
    float ax = fabsf(x);
    return fmaxf(x, 0.f) + __logf(1.f + __expf(-ax)) - LN2;
}
__device__ __forceinline__ unsigned short f2bf(float f) {
    union { float f; unsigned int i; } v; v.f = f;
    unsigned int u = v.i;
    return (unsigned short)((u + 0x7FFFu + ((u >> 16) & 1u)) >> 16);
}
__device__ __forceinline__ int f2ord(float f) {
    int i = __float_as_int(f);
    return (i >= 0) ? i : (i ^ 0x7fffffff);
}
__device__ __forceinline__ float ord2f(int i) {
    return __int_as_float((i >= 0) ? i : (i ^ 0x7fffffff));
}

// ------------- one-time: bf16 transposed weights for MFMA B-fragments -------------
// w1t: per layer [128][64] (W1^T, K padded 50->64 with zeros)
// w2t: per layer [128][128] (W2^T)
__global__ void repr_prep(const float* __restrict__ fw1, const float* __restrict__ fw2,
                          short* __restrict__ w1t, short* __restrict__ w2t) {
    int i = blockIdx.x * 256 + threadIdx.x;
    if (i >= L_LAYERS * 24576) return;
    int l = i / 24576, rem = i % 24576;
    if (rem < 8192) {
        int n = rem >> 6, k = rem & 63;
        float v = (k < G_GAUSS) ? fw1[(size_t)l * G_GAUSS * HID_DIM + k * HID_DIM + n] : 0.f;
        w1t[(size_t)l * 8192 + rem] = (short)f2bf(v);
    } else {
        int r2 = rem - 8192;
        int n = r2 >> 7, k = r2 & 127;
        float v = fw2[(size_t)l * HID_DIM * HD + k * HD + n];
        w2t[(size_t)l * 16384 + r2] = (short)f2bf(v);
    }
}

// ------------- histograms: all edges by dst, and survivors by dst -------------
__global__ void repr_hist(const float* __restrict__ R,
                          const int* __restrict__ src, const int* __restrict__ dst,
                          int* __restrict__ count_f, int* __restrict__ count_s) {
    int e = blockIdx.x * blockDim.x + threadIdx.x;
    if (e >= N_EDGES) return;
    int s = src[e], d = dst[e];
    atomicAdd(&count_f[d], 1);
    float dx = R[3*s+0] - R[3*d+0];
    float dy = R[3*s+1] - R[3*d+1];
    float dz = R[3*s+2] - R[3*d+2];
    float r = sqrtf(dx*dx + dy*dy + dz*dz);
    if (r < 8.0f) atomicAdd(&count_s[d], 1);
}

// ------------- 2-level exclusive scan over 50000 counts -------------
__global__ void repr_scanA(const int* __restrict__ cnt, int* __restrict__ excl,
                           int* __restrict__ bsum) {
    __shared__ int tmp[256];
    int t = threadIdx.x, b = blockIdx.x;
    int i = b * 256 + t;
    int v = (i < N_NODES) ? cnt[i] : 0;
    tmp[t] = v; __syncthreads();
    for (int off = 1; off < 256; off <<= 1) {
        int add = (t >= off) ? tmp[t - off] : 0;
        __syncthreads();
        tmp[t] += add;
        __syncthreads();
    }
    if (i < N_NODES) excl[i] = tmp[t] - v;
    if (t == 255) bsum[b] = tmp[255];
}
__global__ void repr_scanB(const int* __restrict__ bsum, int* __restrict__ bpref,
                           int* __restrict__ ecount) {
    __shared__ int tmp[256];
    int t = threadIdx.x;
    int v = (t < NCHUNK) ? bsum[t] : 0;
    tmp[t] = v; __syncthreads();
    for (int off = 1; off < 256; off <<= 1) {
        int add = (t >= off) ? tmp[t - off] : 0;
        __syncthreads();
        tmp[t] += add;
        __syncthreads();
    }
    if (t < NCHUNK) bpref[t] = tmp[t] - v;
    if (t == 255) ecount[0] = tmp[255];
}
__global__ void repr_scanC(const int* __restrict__ excl, const int* __restrict__ bpref,
                           int* __restrict__ cursor) {
    int i = blockIdx.x * 256 + threadIdx.x;
    if (i < N_NODES) cursor[i] = excl[i] + bpref[blockIdx.x];
}

// ------------- scatter: full dst-sorted list + survivor dst-sorted list -------------
__global__ void repr_scatter(const float* __restrict__ R,
                             const int* __restrict__ src, const int* __restrict__ dst,
                             int* __restrict__ cur_f, int* __restrict__ cur_s,
                             int* __restrict__ ssrc_f, int* __restrict__ sdst_f,
                             int* __restrict__ ssrc2, int* __restrict__ sdst2,
                             int* __restrict__ sidx2, float* __restrict__ r2) {
    int e = blockIdx.x * blockDim.x + threadIdx.x;
    if (e >= N_EDGES) return;
    int s = src[e], d = dst[e];
    float dx = R[3*s+0] - R[3*d+0];
    float dy = R[3*s+1] - R[3*d+1];
    float dz = R[3*s+2] - R[3*d+2];
    float r = sqrtf(dx*dx + dy*dy + dz*dz);
    int pos = atomicAdd(&cur_f[d], 1);
    ssrc_f[pos] = s; sdst_f[pos] = d;
    if (r < 8.0f) {
        int p2 = atomicAdd(&cur_s[d], 1);
        ssrc2[p2] = s; sdst2[p2] = d; sidx2[p2] = pos; r2[p2] = r;
    }
}

// ------------- x init from embedding table -------------
__global__ void repr_embed(const float* __restrict__ emb, const int* __restrict__ Z,
                           float* __restrict__ x) {
    int i = blockIdx.x * blockDim.x + threadIdx.x;
    if (i >= N_NODES * D_DIM) return;
    int n = i >> 6, d = i & 63;
    x[i] = emb[Z[n] * D_DIM + d];
}

// ------------- h = x @ fc_w ; attention logits -------------
__global__ void repr_h(const float* __restrict__ x, const float* __restrict__ fc_w,
                       const float* __restrict__ attn_l, const float* __restrict__ attn_r,
                       float* __restrict__ h, float* __restrict__ el, float* __restrict__ er) {
    int wave = threadIdx.x >> 6, lane = threadIdx.x & 63;
    int n = blockIdx.x * 4 + wave;
    if (n >= N_NODES) return;
    float xv = x[n * 64 + lane];
    float a0 = 0.f, a1 = 0.f;
    #pragma unroll 8
    for (int k = 0; k < 64; k++) {
        float xk = __shfl(xv, k, 64);
        a0 = fmaf(xk, fc_w[k * 128 + lane], a0);
        a1 = fmaf(xk, fc_w[k * 128 + 64 + lane], a1);
    }
    h[n * 128 + lane] = a0;
    h[n * 128 + 64 + lane] = a1;
    float p0 = a0 * attn_l[lane];
    float p1 = a1 * attn_l[64 + lane];
    float q0 = a0 * attn_r[lane];
    float q1 = a1 * attn_r[64 + lane];
    #pragma unroll
    for (int off = 32; off > 0; off >>= 1) {
        p0 += __shfl_xor(p0, off, 64);
        p1 += __shfl_xor(p1, off, 64);
        q0 += __shfl_xor(q0, off, 64);
        q1 += __shfl_xor(q1, off, 64);
    }
    if (lane == 0) {
        el[n * 2] = p0; el[n * 2 + 1] = p1;
        er[n * 2] = q0; er[n * 2 + 1] = q1;
    }
}

// ------------- softmax pass 1 over sorted edges: leaky + segmented max -------------
__global__ void repr_smax(const int* __restrict__ ssrc_f, const int* __restrict__ sdst_f,
                          const float* __restrict__ el, const float* __restrict__ er,
                          float* __restrict__ ebuf, int* __restrict__ mord) {
    int t = threadIdx.x;
    int e = blockIdx.x * 256 + t;
    int s = ssrc_f[e], d = sdst_f[e];
    float2 a = *(const float2*)&el[2 * s];
    float2 b = *(const float2*)&er[2 * d];
    float v0 = a.x + b.x; v0 = v0 >= 0.f ? v0 : 0.2f * v0;
    float v1 = a.y + b.y; v1 = v1 >= 0.f ? v1 : 0.2f * v1;
    float2 vo; vo.x = v0; vo.y = v1;
    *(float2*)&ebuf[2 * e] = vo;
    __shared__ float v0s[256], v1s[256];
    __shared__ int ds[256];
    v0s[t] = v0; v1s[t] = v1; ds[t] = d;
    __syncthreads();
    bool leader = (t == 0) || (ds[t - 1] != d);
    if (leader) {
        float m0 = v0, m1 = v1; int j = t + 1;
        while (j < 256 && ds[j] == d) { m0 = fmaxf(m0, v0s[j]); m1 = fmaxf(m1, v1s[j]); j++; }
        bool bound = (t == 0) || (j == 256);
        if (bound) {
            atomicMax(&mord[2 * d], f2ord(m0));
            atomicMax(&mord[2 * d + 1], f2ord(m1));
        } else {
            mord[2 * d] = f2ord(m0);
            mord[2 * d + 1] = f2ord(m1);
        }
    }
}

// ------------- softmax pass 2: exp + segmented sum -------------
__global__ void repr_ssum(const int* __restrict__ sdst_f, const int* __restrict__ mord,
                          float* __restrict__ ebuf, float* __restrict__ denom) {
    int t = threadIdx.x;
    int e = blockIdx.x * 256 + t;
    int d = sdst_f[e];
    float m0 = ord2f(mord[2 * d]), m1 = ord2f(mord[2 * d + 1]);
    float2 v = *(const float2*)&ebuf[2 * e];
    float ex0 = __expf(v.x - m0), ex1 = __expf(v.y - m1);
    float2 vo; vo.x = ex0; vo.y = ex1;
    *(float2*)&ebuf[2 * e] = vo;
    __shared__ float v0s[256], v1s[256];
    __shared__ int ds[256];
    v0s[t] = ex0; v1s[t] = ex1; ds[t] = d;
    __syncthreads();
    bool leader = (t == 0) || (ds[t - 1] != d);
    if (leader) {
        float s0 = ex0, s1 = ex1; int j = t + 1;
        while (j < 256 && ds[j] == d) { s0 += v0s[j]; s1 += v1s[j]; j++; }
        bool bound = (t == 0) || (j == 256);
        if (bound) {
            atomicAdd(&denom[2 * d], s0);
            atomicAdd(&denom[2 * d + 1], s1);
        } else {
            denom[2 * d] = s0;
            denom[2 * d + 1] = s1;
        }
    }
}

// ------------- fused filter-net (MFMA) + message + segmented-reduce scatter -------------
#define TILE 64
#define GS_LD 72        // shorts per gs row (144 B)
#define HID_LD 136      // shorts per hid row (272 B)
#define MSG_LD 132      // floats per msg row
#define HID_OFF 9216    // bytes: gs region = 64*72*2
// lds_main = max(9216 + 64*136*2, 64*132*4) = max(26624, 33792)

__global__ __launch_bounds__(256) void repr_msg(
    const int* __restrict__ ssrc2, const int* __restrict__ sdst2,
    const int* __restrict__ sidx2, const float* __restrict__ r2,
    const int* __restrict__ ecount,
    const float* __restrict__ eex, const float* __restrict__ denom,
    const float* __restrict__ h,
    const float* __restrict__ offs, const float* __restrict__ widths,
    const short* __restrict__ w1t, const float* __restrict__ b1,
    const short* __restrict__ w2t, const float* __restrict__ b2,
    float* __restrict__ agg)
{
    __shared__ __attribute__((aligned(16))) char lds_main[33792];
    __shared__ float r_s[TILE];
    __shared__ float scale_s[TILE][2];
    __shared__ int src_s[TILE], dst_s[TILE];
    __shared__ int seg_start_s[TILE];
    __shared__ int nseg_s;
    __shared__ float off_s[G_GAUSS], coef_s[G_GAUSS];

    int EC = ecount[0];
    int base = blockIdx.x * TILE;
    if (base >= EC) return;
    int tid = threadIdx.x;
    int lane = tid & 63;
    int w = tid >> 6;              // wave owns cols [w*32, w*32+32)
    int l15 = lane & 15;
    int q = lane >> 4;
    int wbase = w * 32;

    // preload B-fragments (bf16 transposed weights; B[k=q*8+j][n=l15]) + biases
    bf16x8 bf1[2][2], bf2[2][4];
    float b1c[2], b2c[2];
    #pragma unroll
    for (int nt = 0; nt < 2; nt++) {
        int n = wbase + nt * 16 + l15;
        b1c[nt] = b1[n];
        b2c[nt] = b2[n];
        #pragma unroll
        for (int c = 0; c < 2; c++)
            bf1[nt][c] = *(const bf16x8*)(w1t + n * 64 + c * 32 + q * 8);
        #pragma unroll
        for (int c = 0; c < 4; c++)
            bf2[nt][c] = *(const bf16x8*)(w2t + n * 128 + c * 32 + q * 8);
    }

    if (tid < G_GAUSS) {
        float ww = widths[tid];
        off_s[tid] = offs[tid];
        coef_s[tid] = -0.5f / (ww * ww);
    }
    if (tid < TILE) {
        int i = base + tid;
        int d, sn;
        float sc0, sc1, rr;
        if (i < EC) {
            sn = ssrc2[i]; d = sdst2[i];
            rr = r2[i];
            int fp = sidx2[i];
            float C = 0.5f * (__cosf(rr * PI_OVER_8) + 1.f);
            float2 ex = *(const float2*)&eex[(size_t)fp * 2];
            float2 dn = *(const float2*)&denom[(size_t)d * 2];
            sc0 = C * ex.x / dn.x;
            sc1 = C * ex.y / dn.y;
        } else {
            sn = 0; d = -1; rr = 0.f; sc0 = 0.f; sc1 = 0.f;
        }
        src_s[tid] = sn; dst_s[tid] = d;
        r_s[tid] = rr;
        scale_s[tid][0] = sc0; scale_s[tid][1] = sc1;
        int dprev = __shfl_up(d, 1, 64);
        bool flag = (tid == 0) || (d != dprev);
        unsigned long long mask = __ballot(flag);
        if (flag) seg_start_s[__popcll(mask & ((1ull << tid) - 1ull))] = tid;
        if (tid == 0) nseg_s = (int)__popcll(mask);
    }
    __syncthreads();

    // gaussian tile -> bf16 LDS, A-layout row-major [64][GS_LD], K padded 50->64
    {
        int row = tid >> 2;
        int c16 = (tid & 3) << 4;
        float rr = r_s[row];
        unsigned int pk[8];
        #pragma unroll
        for (int jj = 0; jj < 8; jj++) {
            int k0 = c16 + jj * 2;
            float g0 = 0.f, g1 = 0.f;
            if (k0 < G_GAUSS)     { float dr = rr - off_s[k0];     g0 = __expf(coef_s[k0] * dr * dr); }
            if (k0 + 1 < G_GAUSS) { float dr = rr - off_s[k0 + 1]; g1 = __expf(coef_s[k0 + 1] * dr * dr); }
            pk[jj] = (unsigned int)f2bf(g0) | ((unsigned int)f2bf(g1) << 16);
        }
        char* gp = lds_main + row * (GS_LD * 2) + c16 * 2;
        *(uint4*)gp = *(uint4*)&pk[0];
        *(uint4*)(gp + 16) = *(uint4*)&pk[4];
    }
    __syncthreads();

    // stage 1 MFMA: hid(64x128) = gs(64x64bf16) @ W1(64x128bf16)
    const short* gs_sh = (const short*)lds_main;
    f32x4 acc1[4][2];
    #pragma unroll
    for (int mt = 0; mt < 4; mt++)
        #pragma unroll
        for (int nt = 0; nt < 2; nt++)
            acc1[mt][nt] = (f32x4){0.f, 0.f, 0.f, 0.f};
    #pragma unroll
    for (int mt = 0; mt < 4; mt++) {
        int m = mt * 16 + l15;
        bf16x8 a0 = *(const bf16x8*)(gs_sh + m * GS_LD + q * 8);
        bf16x8 a1 = *(const bf16x8*)(gs_sh + m * GS_LD + 32 + q * 8);
        #pragma unroll
        for (int nt = 0; nt < 2; nt++) {
            acc1[mt][nt] = __builtin_amdgcn_mfma_f32_16x16x32_bf16(a0, bf1[nt][0], acc1[mt][nt], 0, 0, 0);
            acc1[mt][nt] = __builtin_amdgcn_mfma_f32_16x16x32_bf16(a1, bf1[nt][1], acc1[mt][nt], 0, 0, 0);
        }
    }
    // epilogue: hid = ssp(acc + b1) -> bf16 LDS (A-layout for stage 2)
    short* hid_sh = (short*)(lds_main + HID_OFF);
    #pragma unroll
    for (int mt = 0; mt < 4; mt++)
        #pragma unroll
        for (int nt = 0; nt < 2; nt++) {
            int colg = wbase + nt * 16 + l15;
            #pragma unroll
            for (int rg = 0; rg < 4; rg++) {
                int row = mt * 16 + q * 4 + rg;   // C/D: col=lane&15, row=quad*4+reg
                float v = sspf(acc1[mt][nt][rg] + b1c[nt]);
                hid_sh[row * HID_LD + colg] = (short)f2bf(v);
            }
        }
    __syncthreads();

    // stage 2 MFMA: wv(64x128) = hid(64x128bf16) @ W2(128x128bf16)
    f32x4 acc2[4][2];
    #pragma unroll
    for (int mt = 0; mt < 4; mt++)
        #pragma unroll
        for (int nt = 0; nt < 2; nt++)
            acc2[mt][nt] = (f32x4){0.f, 0.f, 0.f, 0.f};
    #pragma unroll
    for (int mt = 0; mt < 4; mt++) {
        int m = mt * 16 + l15;
        #pragma unroll
        for (int c = 0; c < 4; c++) {
            bf16x8 a = *(const bf16x8*)(hid_sh + m * HID_LD + c * 32 + q * 8);
            #pragma unroll
            for (int nt = 0; nt < 2; nt++)
                acc2[mt][nt] = __builtin_amdgcn_mfma_f32_16x16x32_bf16(a, bf2[nt][c], acc2[mt][nt], 0, 0, 0);
        }
    }
    __syncthreads();   // all hid reads done before msg overwrites lds_main

    // epilogue: msg = scale * (wv + b2) * h[src] -> fp32 LDS [64][MSG_LD]
    float* msg_f = (float*)lds_main;
    int head = w >> 1;                  // cols 0..63 head0, 64..127 head1
    #pragma unroll
    for (int mt = 0; mt < 4; mt++)
        #pragma unroll
        for (int nt = 0; nt < 2; nt++) {
            int colg = wbase + nt * 16 + l15;
            #pragma unroll
            for (int rg = 0; rg < 4; rg++) {
                int row = mt * 16 + q * 4 + rg;
                float sc = scale_s[row][head];
                float hv = h[(size_t)src_s[row] * HD + colg];
                msg_f[row * MSG_LD + colg] = (acc2[mt][nt][rg] + b2c[nt]) * hv * sc;
            }
        }
    __syncthreads();

    // segmented reduction: one write per (dst,col) per tile
    {
        int nseg = nseg_s;
        int col = tid & 127;
        int sp = tid >> 7;
        for (int s = sp; s < nseg; s += 2) {
            int r0 = seg_start_s[s];
            int r1 = (s + 1 < nseg) ? seg_start_s[s + 1] : TILE;
            int d = dst_s[r0];
            if (d < 0) continue;
            float sum = 0.f;
            for (int r = r0; r < r1; r++) sum += msg_f[r * MSG_LD + col];
            float* ap = &agg[(size_t)d * HD + col];
            if (s == 0 || s == nseg - 1) atomicAdd(ap, sum);
            else *ap = sum;
        }
    }
}

// ------------- node MLP: x += mlp(ssp(agg)) -------------
__global__ void repr_node_mlp(const float* __restrict__ agg,
                              const float* __restrict__ w1, const float* __restrict__ b1,
                              const float* __restrict__ w2, const float* __restrict__ b2,
                              float* __restrict__ x) {
    int wave = threadIdx.x >> 6, lane = threadIdx.x & 63;
    int n = blockIdx.x * 4 + wave;
    if (n >= N_NODES) return;
    float t0 = sspf(agg[n * 128 + lane]);
    float t1 = sspf(agg[n * 128 + 64 + lane]);
    float a = 0.f;
    #pragma unroll 8
    for (int k = 0; k < 64; k++) {
        float u0 = __shfl(t0, k, 64);
        float u1 = __shfl(t1, k, 64);
        a = fmaf(u0, w1[k * 64 + lane], a);
        a = fmaf(u1, w1[(64 + k) * 64 + lane], a);
    }
    float v1 = sspf(a + b1[lane]);
    float b = 0.f;
    #pragma unroll 8
    for (int k = 0; k < 64; k++) {
        float u = __shfl(v1, k, 64);
        b = fmaf(u, w2[k * 64 + lane], b);
    }
    x[n * 64 + lane] += b + b2[lane];
}

// ------------- output MLP + graph segment-sum -------------
__global__ void repr_out(const float* __restrict__ x,
                         const float* __restrict__ w1, const float* __restrict__ b1,
                         const float* __restrict__ w2, const float* __restrict__ b2,
                         const int* __restrict__ gids, float* __restrict__ out_acc) {
    int wave = threadIdx.x >> 6, lane = threadIdx.x & 63;
    int n = blockIdx.x * 4 + wave;
    if (n >= N_NODES) return;
    float xv = x[n * 64 + lane];
    float a0 = 0.f, a1 = 0.f;
    #pragma unroll 8
    for (int k = 0; k < 64; k++) {
        float xk = __shfl(xv, k, 64);
        a0 = fmaf(xk, w1[k * 128 + lane], a0);
        a1 = fmaf(xk, w1[k * 128 + 64 + lane], a1);
    }
    float y0 = sspf(a0 + b1[lane]);
    float y1 = sspf(a1 + b1[64 + lane]);
    float s = y0 * w2[lane] + y1 * w2[64 + lane];
    #pragma unroll
    for (int off = 32; off > 0; off >>= 1) s += __shfl_xor(s, off, 64);
    if (lane == 0) atomicAdd(&out_acc[gids[n]], s + b2[0]);
}

__global__ void repr_final(const float* __restrict__ out_acc, float* __restrict__ out) {
    int i = threadIdx.x;
    if (i < B_GRAPHS) out[i] = out_acc[i];
}

extern "C" void kernel_launch(void* const* d_in, const int* in_sizes, int n_in,
                              void* d_out, int out_size, void* d_ws, size_t ws_size,
                              hipStream_t stream) {
    (void)in_sizes; (void)n_in; (void)out_size; (void)ws_size;
    const float* R      = (const float*)d_in[0];
    const int*   Z      = (const int*)d_in[1];
    const int*   src    = (const int*)d_in[2];
    const int*   dst    = (const int*)d_in[3];
    const int*   gids   = (const int*)d_in[4];
    const float* emb    = (const float*)d_in[5];
    const float* offs   = (const float*)d_in[6];
    const float* widths = (const float*)d_in[7];
    const float* fc_w   = (const float*)d_in[8];
    const float* attn_l = (const float*)d_in[9];
    const float* attn_r = (const float*)d_in[10];
    const float* fw1    = (const float*)d_in[11];
    const float* fb1    = (const float*)d_in[12];
    const float* fw2    = (const float*)d_in[13];
    const float* fb2    = (const float*)d_in[14];
    const float* mw1    = (const float*)d_in[15];
    const float* mb1    = (const float*)d_in[16];
    const float* mw2    = (const float*)d_in[17];
    const float* mb2    = (const float*)d_in[18];
    const float* ow1    = (const float*)d_in[19];
    const float* ob1    = (const float*)d_in[20];
    const float* ow2    = (const float*)d_in[21];
    const float* ob2    = (const float*)d_in[22];

    char* p = (char*)d_ws;
    float* x      = (float*)p; p += (size_t)N_NODES * 64 * 4;     // 12.8 MB
    float* h      = (float*)p; p += (size_t)N_NODES * 128 * 4;    // 25.6 MB
    float* el     = (float*)p; p += (size_t)N_NODES * 2 * 4;
    float* er     = (float*)p; p += (size_t)N_NODES * 2 * 4;
    float* denom  = (float*)p; p += (size_t)N_NODES * 2 * 4;
    int*   mord   = (int*)p;   p += (size_t)N_NODES * 2 * 4;
    float* agg    = (float*)p; p += (size_t)N_NODES * 128 * 4;    // 25.6 MB
    float* ebuf   = (float*)p; p += (size_t)N_EDGES * 2 * 4;      // 6.4 MB
    int*   ssrc_f = (int*)p;   p += (size_t)N_EDGES * 4;
    int*   sdst_f = (int*)p;   p += (size_t)N_EDGES * 4;
    int*   ssrc2  = (int*)p;   p += (size_t)N_EDGES * 4;
    int*   sdst2  = (int*)p;   p += (size_t)N_EDGES * 4;
    int*   sidx2  = (int*)p;   p += (size_t)N_EDGES * 4;
    float* r2     = (float*)p; p += (size_t)N_EDGES * 4;
    short* w1t    = (short*)p; p += (size_t)L_LAYERS * 8192 * 2;   // 48 KB
    short* w2t    = (short*)p; p += (size_t)L_LAYERS * 16384 * 2;  // 96 KB
    int*   bsumA  = (int*)p;   p += 1024;
    int*   bprefA = (int*)p;   p += 1024;
    int*   bsumB  = (int*)p;   p += 1024;
    int*   bprefB = (int*)p;   p += 1024;
    int*   ecF    = (int*)p;   p += 256;
    int*   ecS    = (int*)p;   p += 256;
    float* oacc   = (float*)p; p += 256;
    // scan temporaries aliased into x (x written by repr_embed, strictly after
    // repr_scatter in stream order):
    int* count_f = (int*)x;
    int* excl_f  = (int*)((char*)x + 256 * 1024);
    int* cur_f   = (int*)((char*)x + 512 * 1024);
    int* count_s = (int*)((char*)x + 768 * 1024);
    int* excl_s  = (int*)((char*)x + 1024 * 1024);
    int* cur_s   = (int*)((char*)x + 1280 * 1024);

    hipMemsetAsync(x, 0, 1536 * 1024, stream);
    hipMemsetAsync(oacc, 0, B_GRAPHS * 4, stream);

    repr_prep<<<(L_LAYERS * 24576 + 255) / 256, 256, 0, stream>>>(fw1, fw2, w1t, w2t);
    repr_hist<<<N_EDGES / 256, 256, 0, stream>>>(R, src, dst, count_f, count_s);
    repr_scanA<<<NCHUNK, 256, 0, stream>>>(count_f, excl_f, bsumA);
    repr_scanB<<<1, 256, 0, stream>>>(bsumA, bprefA, ecF);
    repr_scanC<<<NCHUNK, 256, 0, stream>>>(excl_f, bprefA, cur_f);
    repr_scanA<<<NCHUNK, 256, 0, stream>>>(count_s, excl_s, bsumB);
    repr_scanB<<<1, 256, 0, stream>>>(bsumB, bprefB, ecS);
    repr_scanC<<<NCHUNK, 256, 0, stream>>>(excl_s, bprefB, cur_s);
    repr_scatter<<<N_EDGES / 256, 256, 0, stream>>>(
        R, src, dst, cur_f, cur_s, ssrc_f, sdst_f, ssrc2, sdst2, sidx2, r2);
    repr_embed<<<(N_NODES * 64) / 256, 256, 0, stream>>>(emb, Z, x);

    for (int l = 0; l < L_LAYERS; l++) {
        hipMemsetAsync(denom, 0, (size_t)N_NODES * 2 * 4, stream);
        hipMemsetAsync(mord, 0x80, (size_t)N_NODES * 2 * 4, stream);
        hipMemsetAsync(agg, 0, (size_t)N_NODES * 128 * 4, stream);
        repr_h<<<(N_NODES + 3) / 4, 256, 0, stream>>>(
            x, fc_w + (size_t)l * 64 * 128, attn_l + l * 128, attn_r + l * 128, h, el, er);
        repr_smax<<<N_EDGES / 256, 256, 0, stream>>>(ssrc_f, sdst_f, el, er, ebuf, mord);
        repr_ssum<<<N_EDGES / 256, 256, 0, stream>>>(sdst_f, mord, ebuf, denom);
        repr_msg<<<N_EDGES / TILE, 256, 0, stream>>>(
            ssrc2, sdst2, sidx2, r2, ecS, ebuf, denom, h, offs, widths,
            w1t + (size_t)l * 8192, fb1 + (size_t)l * HID_DIM,
            w2t + (size_t)l * 16384, fb2 + (size_t)l * HD, agg);
        repr_node_mlp<<<(N_NODES + 3) / 4, 256, 0, stream>>>(
            agg, mw1 + (size_t)l * 128 * 64, mb1 + l * 64,
            mw2 + (size_t)l * 64 * 64, mb2 + l * 64, x);
    }
    repr_out<<<(N_NODES + 3) / 4, 256, 0, stream>>>(x, ow1, ob1, ow2, ob2, gids, oacc);
    repr_final<<<1, 64, 0, stream>>>(oacc, (float*)d_out);
}

// Round 6
// 1219.627 us; speedup vs baseline: 6.3253x; 1.3690x over previous
//
#include <hip/hip_runtime.h>
#include <stdint.h>

#define N_NODES 50000
#define N_EDGES 800000
#define B_GRAPHS 64
#define D_DIM 64
#define HD 128
#define G_GAUSS 50
#define HID_DIM 128
#define L_LAYERS 3
#define LN2 0.69314718055994530942f
#define PI_OVER_8 0.39269908169872414f
#define NCHUNK 196            // ceil(50000/256)

typedef __attribute__((ext_vector_type(8))) short bf16x8;
typedef __attribute__((ext_vector_type(4))) float f32x4;

__device__ __forceinline__ float sspf(float x) {
    float ax = fabsf(x);
    return fmaxf(x, 0.f) + __logf(1.f + __expf(-ax)) - LN2;
}
__device__ __forceinline__ unsigned short f2bf(float f) {
    union { float f; unsigned int i; } v; v.f = f;
    unsigned int u = v.i;
    return (unsigned short)((u + 0x7FFFu + ((u >> 16) & 1u)) >> 16);
}
__device__ __forceinline__ int f2ord(float f) {
    int i = __float_as_int(f);
    return (i >= 0) ? i : (i ^ 0x7fffffff);
}
__device__ __forceinline__ float ord2f(int i) {
    return __int_as_float((i >= 0) ? i : (i ^ 0x7fffffff));
}

// ------------- one-time: bf16 transposed weights for MFMA B-fragments -------------
__global__ void repr_prep(const float* __restrict__ fw1, const float* __restrict__ fw2,
                          short* __restrict__ w1t, short* __restrict__ w2t) {
    int i = blockIdx.x * 256 + threadIdx.x;
    if (i >= L_LAYERS * 24576) return;
    int l = i / 24576, rem = i % 24576;
    if (rem < 8192) {
        int n = rem >> 6, k = rem & 63;
        float v = (k < G_GAUSS) ? fw1[(size_t)l * G_GAUSS * HID_DIM + k * HID_DIM + n] : 0.f;
        w1t[(size_t)l * 8192 + rem] = (short)f2bf(v);
    } else {
        int r2 = rem - 8192;
        int n = r2 >> 7, k = r2 & 127;
        float v = fw2[(size_t)l * HID_DIM * HD + k * HD + n];
        w2t[(size_t)l * 16384 + r2] = (short)f2bf(v);
    }
}

// ------------- histograms: all edges by dst, and survivors by dst -------------
__global__ void repr_hist(const float* __restrict__ R,
                          const int* __restrict__ src, const int* __restrict__ dst,
                          int* __restrict__ count_f, int* __restrict__ count_s) {
    int e = blockIdx.x * blockDim.x + threadIdx.x;
    if (e >= N_EDGES) return;
    int s = src[e], d = dst[e];
    atomicAdd(&count_f[d], 1);
    float dx = R[3*s+0] - R[3*d+0];
    float dy = R[3*s+1] - R[3*d+1];
    float dz = R[3*s+2] - R[3*d+2];
    float r = sqrtf(dx*dx + dy*dy + dz*dz);
    if (r < 8.0f) atomicAdd(&count_s[d], 1);
}

// ------------- 2-level exclusive scan over 50000 counts -------------
__global__ void repr_scanA(const int* __restrict__ cnt, int* __restrict__ excl,
                           int* __restrict__ bsum) {
    __shared__ int tmp[256];
    int t = threadIdx.x, b = blockIdx.x;
    int i = b * 256 + t;
    int v = (i < N_NODES) ? cnt[i] : 0;
    tmp[t] = v; __syncthreads();
    for (int off = 1; off < 256; off <<= 1) {
        int add = (t >= off) ? tmp[t - off] : 0;
        __syncthreads();
        tmp[t] += add;
        __syncthreads();
    }
    if (i < N_NODES) excl[i] = tmp[t] - v;
    if (t == 255) bsum[b] = tmp[255];
}
__global__ void repr_scanB(const int* __restrict__ bsum, int* __restrict__ bpref,
                           int* __restrict__ ecount) {
    __shared__ int tmp[256];
    int t = threadIdx.x;
    int v = (t < NCHUNK) ? bsum[t] : 0;
    tmp[t] = v; __syncthreads();
    for (int off = 1; off < 256; off <<= 1) {
        int add = (t >= off) ? tmp[t - off] : 0;
        __syncthreads();
        tmp[t] += add;
        __syncthreads();
    }
    if (t < NCHUNK) bpref[t] = tmp[t] - v;
    if (t == 255) ecount[0] = tmp[255];
}
__global__ void repr_scanC(const int* __restrict__ excl, const int* __restrict__ bpref,
                           int* __restrict__ cursor) {
    int i = blockIdx.x * 256 + threadIdx.x;
    if (i < N_NODES) cursor[i] = excl[i] + bpref[blockIdx.x];
}

// ------------- scatter: full dst-sorted list + survivor dst-sorted list -------------
__global__ void repr_scatter(const float* __restrict__ R,
                             const int* __restrict__ src, const int* __restrict__ dst,
                             int* __restrict__ cur_f, int* __restrict__ cur_s,
                             int* __restrict__ ssrc_f, int* __restrict__ sdst_f,
                             int* __restrict__ ssrc2, int* __restrict__ sdst2,
                             int* __restrict__ sidx2, float* __restrict__ r2) {
    int e = blockIdx.x * blockDim.x + threadIdx.x;
    if (e >= N_EDGES) return;
    int s = src[e], d = dst[e];
    float dx = R[3*s+0] - R[3*d+0];
    float dy = R[3*s+1] - R[3*d+1];
    float dz = R[3*s+2] - R[3*d+2];
    float r = sqrtf(dx*dx + dy*dy + dz*dz);
    int pos = atomicAdd(&cur_f[d], 1);
    ssrc_f[pos] = s; sdst_f[pos] = d;
    if (r < 8.0f) {
        int p2 = atomicAdd(&cur_s[d], 1);
        ssrc2[p2] = s; sdst2[p2] = d; sidx2[p2] = pos; r2[p2] = r;
    }
}

// ------------- x init from embedding table -------------
__global__ void repr_embed(const float* __restrict__ emb, const int* __restrict__ Z,
                           float* __restrict__ x) {
    int i = blockIdx.x * blockDim.x + threadIdx.x;
    if (i >= N_NODES * D_DIM) return;
    int n = i >> 6, d = i & 63;
    x[i] = emb[Z[n] * D_DIM + d];
}

// ------------- h = x @ fc_w ; attention logits -------------
__global__ void repr_h(const float* __restrict__ x, const float* __restrict__ fc_w,
                       const float* __restrict__ attn_l, const float* __restrict__ attn_r,
                       float* __restrict__ h, float* __restrict__ el, float* __restrict__ er) {
    int wave = threadIdx.x >> 6, lane = threadIdx.x & 63;
    int n = blockIdx.x * 4 + wave;
    if (n >= N_NODES) return;
    float xv = x[n * 64 + lane];
    float a0 = 0.f, a1 = 0.f;
    #pragma unroll 8
    for (int k = 0; k < 64; k++) {
        float xk = __shfl(xv, k, 64);
        a0 = fmaf(xk, fc_w[k * 128 + lane], a0);
        a1 = fmaf(xk, fc_w[k * 128 + 64 + lane], a1);
    }
    h[n * 128 + lane] = a0;
    h[n * 128 + 64 + lane] = a1;
    float p0 = a0 * attn_l[lane];
    float p1 = a1 * attn_l[64 + lane];
    float q0 = a0 * attn_r[lane];
    float q1 = a1 * attn_r[64 + lane];
    #pragma unroll
    for (int off = 32; off > 0; off >>= 1) {
        p0 += __shfl_xor(p0, off, 64);
        p1 += __shfl_xor(p1, off, 64);
        q0 += __shfl_xor(q0, off, 64);
        q1 += __shfl_xor(q1, off, 64);
    }
    if (lane == 0) {
        el[n * 2] = p0; el[n * 2 + 1] = p1;
        er[n * 2] = q0; er[n * 2 + 1] = q1;
    }
}

// ------------- softmax pass 1 over sorted edges: leaky + segmented max -------------
__global__ void repr_smax(const int* __restrict__ ssrc_f, const int* __restrict__ sdst_f,
                          const float* __restrict__ el, const float* __restrict__ er,
                          float* __restrict__ ebuf, int* __restrict__ mord) {
    int t = threadIdx.x;
    int e = blockIdx.x * 256 + t;
    int s = ssrc_f[e], d = sdst_f[e];
    float2 a = *(const float2*)&el[2 * s];
    float2 b = *(const float2*)&er[2 * d];
    float v0 = a.x + b.x; v0 = v0 >= 0.f ? v0 : 0.2f * v0;
    float v1 = a.y + b.y; v1 = v1 >= 0.f ? v1 : 0.2f * v1;
    float2 vo; vo.x = v0; vo.y = v1;
    *(float2*)&ebuf[2 * e] = vo;
    __shared__ float v0s[256], v1s[256];
    __shared__ int ds[256];
    v0s[t] = v0; v1s[t] = v1; ds[t] = d;
    __syncthreads();
    bool leader = (t == 0) || (ds[t - 1] != d);
    if (leader) {
        float m0 = v0, m1 = v1; int j = t + 1;
        while (j < 256 && ds[j] == d) { m0 = fmaxf(m0, v0s[j]); m1 = fmaxf(m1, v1s[j]); j++; }
        bool bound = (t == 0) || (j == 256);
        if (bound) {
            atomicMax(&mord[2 * d], f2ord(m0));
            atomicMax(&mord[2 * d + 1], f2ord(m1));
        } else {
            mord[2 * d] = f2ord(m0);
            mord[2 * d + 1] = f2ord(m1);
        }
    }
}

// ------------- softmax pass 2: exp + segmented sum -------------
__global__ void repr_ssum(const int* __restrict__ sdst_f, const int* __restrict__ mord,
                          float* __restrict__ ebuf, float* __restrict__ denom) {
    int t = threadIdx.x;
    int e = blockIdx.x * 256 + t;
    int d = sdst_f[e];
    float m0 = ord2f(mord[2 * d]), m1 = ord2f(mord[2 * d + 1]);
    float2 v = *(const float2*)&ebuf[2 * e];
    float ex0 = __expf(v.x - m0), ex1 = __expf(v.y - m1);
    float2 vo; vo.x = ex0; vo.y = ex1;
    *(float2*)&ebuf[2 * e] = vo;
    __shared__ float v0s[256], v1s[256];
    __shared__ int ds[256];
    v0s[t] = ex0; v1s[t] = ex1; ds[t] = d;
    __syncthreads();
    bool leader = (t == 0) || (ds[t - 1] != d);
    if (leader) {
        float s0 = ex0, s1 = ex1; int j = t + 1;
        while (j < 256 && ds[j] == d) { s0 += v0s[j]; s1 += v1s[j]; j++; }
        bool bound = (t == 0) || (j == 256);
        if (bound) {
            atomicAdd(&denom[2 * d], s0);
            atomicAdd(&denom[2 * d + 1], s1);
        } else {
            denom[2 * d] = s0;
            denom[2 * d + 1] = s1;
        }
    }
}

// ------------- fused filter-net (MFMA) + message + segmented-reduce scatter -------------
#define TILE 64
#define GS_LD 72        // shorts per gs row (144 B)
#define HID_LD 136      // shorts per hid row (272 B)
#define MSG_LD 132      // floats per msg row
#define HID_OFF 9216    // bytes: gs region = 64*72*2

__global__ __launch_bounds__(256) void repr_msg(
    const int* __restrict__ ssrc2, const int* __restrict__ sdst2,
    const int* __restrict__ sidx2, const float* __restrict__ r2,
    const int* __restrict__ ecount,
    const float* __restrict__ eex, const float* __restrict__ denom,
    const float* __restrict__ h,
    const float* __restrict__ offs, const float* __restrict__ widths,
    const short* __restrict__ w1t, const float* __restrict__ b1,
    const short* __restrict__ w2t, const float* __restrict__ b2,
    float* __restrict__ agg)
{
    __shared__ __attribute__((aligned(16))) char lds_main[33792];
    __shared__ float r_s[TILE];
    __shared__ float scale_s[TILE][2];
    __shared__ int src_s[TILE], dst_s[TILE];
    __shared__ int seg_start_s[TILE];
    __shared__ int nseg_s;
    __shared__ float off_s[G_GAUSS], coef_s[G_GAUSS];

    int EC = ecount[0];
    int base = blockIdx.x * TILE;
    if (base >= EC) return;
    int tid = threadIdx.x;
    int lane = tid & 63;
    int w = tid >> 6;
    int l15 = lane & 15;
    int q = lane >> 4;
    int wbase = w * 32;

    bf16x8 bf1[2][2], bf2[2][4];
    float b1c[2], b2c[2];
    #pragma unroll
    for (int nt = 0; nt < 2; nt++) {
        int n = wbase + nt * 16 + l15;
        b1c[nt] = b1[n];
        b2c[nt] = b2[n];
        #pragma unroll
        for (int c = 0; c < 2; c++)
            bf1[nt][c] = *(const bf16x8*)(w1t + n * 64 + c * 32 + q * 8);
        #pragma unroll
        for (int c = 0; c < 4; c++)
            bf2[nt][c] = *(const bf16x8*)(w2t + n * 128 + c * 32 + q * 8);
    }

    if (tid < G_GAUSS) {
        float ww = widths[tid];
        off_s[tid] = offs[tid];
        coef_s[tid] = -0.5f / (ww * ww);
    }
    if (tid < TILE) {
        int i = base + tid;
        int d, sn;
        float sc0, sc1, rr;
        if (i < EC) {
            sn = ssrc2[i]; d = sdst2[i];
            rr = r2[i];
            int fp = sidx2[i];
            float C = 0.5f * (__cosf(rr * PI_OVER_8) + 1.f);
            float2 ex = *(const float2*)&eex[(size_t)fp * 2];
            float2 dn = *(const float2*)&denom[(size_t)d * 2];
            sc0 = C * ex.x / dn.x;
            sc1 = C * ex.y / dn.y;
        } else {
            sn = 0; d = -1; rr = 0.f; sc0 = 0.f; sc1 = 0.f;
        }
        src_s[tid] = sn; dst_s[tid] = d;
        r_s[tid] = rr;
        scale_s[tid][0] = sc0; scale_s[tid][1] = sc1;
        int dprev = __shfl_up(d, 1, 64);
        bool flag = (tid == 0) || (d != dprev);
        unsigned long long mask = __ballot(flag);
        if (flag) seg_start_s[__popcll(mask & ((1ull << tid) - 1ull))] = tid;
        if (tid == 0) nseg_s = (int)__popcll(mask);
    }
    __syncthreads();

    // gaussian tile -> bf16 LDS, A-layout row-major [64][GS_LD], K padded 50->64
    {
        int row = tid >> 2;
        int c16 = (tid & 3) << 4;
        float rr = r_s[row];
        unsigned int pk[8];
        #pragma unroll
        for (int jj = 0; jj < 8; jj++) {
            int k0 = c16 + jj * 2;
            float g0 = 0.f, g1 = 0.f;
            if (k0 < G_GAUSS)     { float dr = rr - off_s[k0];     g0 = __expf(coef_s[k0] * dr * dr); }
            if (k0 + 1 < G_GAUSS) { float dr = rr - off_s[k0 + 1]; g1 = __expf(coef_s[k0 + 1] * dr * dr); }
            pk[jj] = (unsigned int)f2bf(g0) | ((unsigned int)f2bf(g1) << 16);
        }
        char* gp = lds_main + row * (GS_LD * 2) + c16 * 2;
        *(uint4*)gp = *(uint4*)&pk[0];
        *(uint4*)(gp + 16) = *(uint4*)&pk[4];
    }
    __syncthreads();

    // stage 1 MFMA: hid(64x128) = gs(64x64bf16) @ W1(64x128bf16)
    const short* gs_sh = (const short*)lds_main;
    f32x4 acc1[4][2];
    #pragma unroll
    for (int mt = 0; mt < 4; mt++)
        #pragma unroll
        for (int nt = 0; nt < 2; nt++)
            acc1[mt][nt] = (f32x4){0.f, 0.f, 0.f, 0.f};
    #pragma unroll
    for (int mt = 0; mt < 4; mt++) {
        int m = mt * 16 + l15;
        bf16x8 a0 = *(const bf16x8*)(gs_sh + m * GS_LD + q * 8);
        bf16x8 a1 = *(const bf16x8*)(gs_sh + m * GS_LD + 32 + q * 8);
        #pragma unroll
        for (int nt = 0; nt < 2; nt++) {
            acc1[mt][nt] = __builtin_amdgcn_mfma_f32_16x16x32_bf16(a0, bf1[nt][0], acc1[mt][nt], 0, 0, 0);
            acc1[mt][nt] = __builtin_amdgcn_mfma_f32_16x16x32_bf16(a1, bf1[nt][1], acc1[mt][nt], 0, 0, 0);
        }
    }
    short* hid_sh = (short*)(lds_main + HID_OFF);
    #pragma unroll
    for (int mt = 0; mt < 4; mt++)
        #pragma unroll
        for (int nt = 0; nt < 2; nt++) {
            int colg = wbase + nt * 16 + l15;
            #pragma unroll
            for (int rg = 0; rg < 4; rg++) {
                int row = mt * 16 + q * 4 + rg;   // C/D: col=lane&15, row=quad*4+reg
                float v = sspf(acc1[mt][nt][rg] + b1c[nt]);
                hid_sh[row * HID_LD + colg] = (short)f2bf(v);
            }
        }
    __syncthreads();

    // stage 2 MFMA: wv(64x128) = hid(64x128bf16) @ W2(128x128bf16)
    f32x4 acc2[4][2];
    #pragma unroll
    for (int mt = 0; mt < 4; mt++)
        #pragma unroll
        for (int nt = 0; nt < 2; nt++)
            acc2[mt][nt] = (f32x4){0.f, 0.f, 0.f, 0.f};
    #pragma unroll
    for (int mt = 0; mt < 4; mt++) {
        int m = mt * 16 + l15;
        #pragma unroll
        for (int c = 0; c < 4; c++) {
            bf16x8 a = *(const bf16x8*)(hid_sh + m * HID_LD + c * 32 + q * 8);
            #pragma unroll
            for (int nt = 0; nt < 2; nt++)
                acc2[mt][nt] = __builtin_amdgcn_mfma_f32_16x16x32_bf16(a, bf2[nt][c], acc2[mt][nt], 0, 0, 0);
        }
    }
    __syncthreads();

    // epilogue: msg = scale * (wv + b2) * h[src] -> fp32 LDS [64][MSG_LD]
    float* msg_f = (float*)lds_main;
    int head = w >> 1;
    #pragma unroll
    for (int mt = 0; mt < 4; mt++)
        #pragma unroll
        for (int nt = 0; nt < 2; nt++) {
            int colg = wbase + nt * 16 + l15;
            #pragma unroll
            for (int rg = 0; rg < 4; rg++) {
                int row = mt * 16 + q * 4 + rg;
                float sc = scale_s[row][head];
                float hv = h[(size_t)src_s[row] * HD + colg];
                msg_f[row * MSG_LD + colg] = (acc2[mt][nt][rg] + b2c[nt]) * hv * sc;
            }
        }
    __syncthreads();

    // segmented reduction: one write per (dst,col) per tile
    {
        int nseg = nseg_s;
        int col = tid & 127;
        int sp = tid >> 7;
        for (int s = sp; s < nseg; s += 2) {
            int r0 = seg_start_s[s];
            int r1 = (s + 1 < nseg) ? seg_start_s[s + 1] : TILE;
            int d = dst_s[r0];
            if (d < 0) continue;
            float sum = 0.f;
            for (int r = r0; r < r1; r++) sum += msg_f[r * MSG_LD + col];
            float* ap = &agg[(size_t)d * HD + col];
            if (s == 0 || s == nseg - 1) atomicAdd(ap, sum);
            else *ap = sum;
        }
    }
}

// ------------- node MLP: x += mlp(ssp(agg)) -------------
__global__ void repr_node_mlp(const float* __restrict__ agg,
                              const float* __restrict__ w1, const float* __restrict__ b1,
                              const float* __restrict__ w2, const float* __restrict__ b2,
                              float* __restrict__ x) {
    int wave = threadIdx.x >> 6, lane = threadIdx.x & 63;
    int n = blockIdx.x * 4 + wave;
    if (n >= N_NODES) return;
    float t0 = sspf(agg[n * 128 + lane]);
    float t1 = sspf(agg[n * 128 + 64 + lane]);
    float a = 0.f;
    #pragma unroll 8
    for (int k = 0; k < 64; k++) {
        float u0 = __shfl(t0, k, 64);
        float u1 = __shfl(t1, k, 64);
        a = fmaf(u0, w1[k * 64 + lane], a);
        a = fmaf(u1, w1[(64 + k) * 64 + lane], a);
    }
    float v1 = sspf(a + b1[lane]);
    float b = 0.f;
    #pragma unroll 8
    for (int k = 0; k < 64; k++) {
        float u = __shfl(v1, k, 64);
        b = fmaf(u, w2[k * 64 + lane], b);
    }
    x[n * 64 + lane] += b + b2[lane];
}

// ------------- output MLP: per-node scalar, coalesced store (NO atomics) -------------
__global__ void repr_out(const float* __restrict__ x,
                         const float* __restrict__ w1, const float* __restrict__ b1,
                         const float* __restrict__ w2, const float* __restrict__ b2,
                         float* __restrict__ hh) {
    int wave = threadIdx.x >> 6, lane = threadIdx.x & 63;
    int n = blockIdx.x * 4 + wave;
    if (n >= N_NODES) return;
    float xv = x[n * 64 + lane];
    float a0 = 0.f, a1 = 0.f;
    #pragma unroll 8
    for (int k = 0; k < 64; k++) {
        float xk = __shfl(xv, k, 64);
        a0 = fmaf(xk, w1[k * 128 + lane], a0);
        a1 = fmaf(xk, w1[k * 128 + 64 + lane], a1);
    }
    float y0 = sspf(a0 + b1[lane]);
    float y1 = sspf(a1 + b1[64 + lane]);
    float s = y0 * w2[lane] + y1 * w2[64 + lane];
    #pragma unroll
    for (int off = 32; off > 0; off >>= 1) s += __shfl_xor(s, off, 64);
    if (lane == 0) hh[n] = s + b2[0];
}

// ------------- graph segment-sum with LDS privatization (~2 atomics/block) -------------
__global__ void repr_gsum(const float* __restrict__ hh, const int* __restrict__ gids,
                          float* __restrict__ out_acc) {
    __shared__ float bins[B_GRAPHS];
    int t = threadIdx.x;
    if (t < B_GRAPHS) bins[t] = 0.f;
    __syncthreads();
    int i = blockIdx.x * 256 + t;
    if (i < N_NODES) atomicAdd(&bins[gids[i]], hh[i]);
    __syncthreads();
    if (t < B_GRAPHS && bins[t] != 0.f) atomicAdd(&out_acc[t], bins[t]);
}

__global__ void repr_final(const float* __restrict__ out_acc, float* __restrict__ out) {
    int i = threadIdx.x;
    if (i < B_GRAPHS) out[i] = out_acc[i];
}

extern "C" void kernel_launch(void* const* d_in, const int* in_sizes, int n_in,
                              void* d_out, int out_size, void* d_ws, size_t ws_size,
                              hipStream_t stream) {
    (void)in_sizes; (void)n_in; (void)out_size; (void)ws_size;
    const float* R      = (const float*)d_in[0];
    const int*   Z      = (const int*)d_in[1];
    const int*   src    = (const int*)d_in[2];
    const int*   dst    = (const int*)d_in[3];
    const int*   gids   = (const int*)d_in[4];
    const float* emb    = (const float*)d_in[5];
    const float* offs   = (const float*)d_in[6];
    const float* widths = (const float*)d_in[7];
    const float* fc_w   = (const float*)d_in[8];
    const float* attn_l = (const float*)d_in[9];
    const float* attn_r = (const float*)d_in[10];
    const float* fw1    = (const float*)d_in[11];
    const float* fb1    = (const float*)d_in[12];
    const float* fw2    = (const float*)d_in[13];
    const float* fb2    = (const float*)d_in[14];
    const float* mw1    = (const float*)d_in[15];
    const float* mb1    = (const float*)d_in[16];
    const float* mw2    = (const float*)d_in[17];
    const float* mb2    = (const float*)d_in[18];
    const float* ow1    = (const float*)d_in[19];
    const float* ob1    = (const float*)d_in[20];
    const float* ow2    = (const float*)d_in[21];
    const float* ob2    = (const float*)d_in[22];

    char* p = (char*)d_ws;
    float* x      = (float*)p; p += (size_t)N_NODES * 64 * 4;     // 12.8 MB
    float* h      = (float*)p; p += (size_t)N_NODES * 128 * 4;    // 25.6 MB
    float* el     = (float*)p; p += (size_t)N_NODES * 2 * 4;
    float* er     = (float*)p; p += (size_t)N_NODES * 2 * 4;
    float* denom  = (float*)p; p += (size_t)N_NODES * 2 * 4;
    int*   mord   = (int*)p;   p += (size_t)N_NODES * 2 * 4;
    float* agg    = (float*)p; p += (size_t)N_NODES * 128 * 4;    // 25.6 MB
    float* ebuf   = (float*)p; p += (size_t)N_EDGES * 2 * 4;      // 6.4 MB
    int*   ssrc_f = (int*)p;   p += (size_t)N_EDGES * 4;
    int*   sdst_f = (int*)p;   p += (size_t)N_EDGES * 4;
    int*   ssrc2  = (int*)p;   p += (size_t)N_EDGES * 4;
    int*   sdst2  = (int*)p;   p += (size_t)N_EDGES * 4;
    int*   sidx2  = (int*)p;   p += (size_t)N_EDGES * 4;
    float* r2     = (float*)p; p += (size_t)N_EDGES * 4;
    short* w1t    = (short*)p; p += (size_t)L_LAYERS * 8192 * 2;   // 48 KB
    short* w2t    = (short*)p; p += (size_t)L_LAYERS * 16384 * 2;  // 96 KB
    int*   bsumA  = (int*)p;   p += 1024;
    int*   bprefA = (int*)p;   p += 1024;
    int*   bsumB  = (int*)p;   p += 1024;
    int*   bprefB = (int*)p;   p += 1024;
    int*   ecF    = (int*)p;   p += 256;
    int*   ecS    = (int*)p;   p += 256;
    float* oacc   = (float*)p; p += 256;
    // scan temporaries aliased into x (x written by repr_embed, strictly after
    // repr_scatter in stream order):
    int* count_f = (int*)x;
    int* excl_f  = (int*)((char*)x + 256 * 1024);
    int* cur_f   = (int*)((char*)x + 512 * 1024);
    int* count_s = (int*)((char*)x + 768 * 1024);
    int* excl_s  = (int*)((char*)x + 1024 * 1024);
    int* cur_s   = (int*)((char*)x + 1280 * 1024);
    // hh scratch aliased into agg (agg dead after last repr_node_mlp)
    float* hh = agg;

    hipMemsetAsync(x, 0, 1536 * 1024, stream);
    hipMemsetAsync(oacc, 0, B_GRAPHS * 4, stream);

    repr_prep<<<(L_LAYERS * 24576 + 255) / 256, 256, 0, stream>>>(fw1, fw2, w1t, w2t);
    repr_hist<<<N_EDGES / 256, 256, 0, stream>>>(R, src, dst, count_f, count_s);
    repr_scanA<<<NCHUNK, 256, 0, stream>>>(count_f, excl_f, bsumA);
    repr_scanB<<<1, 256, 0, stream>>>(bsumA, bprefA, ecF);
    repr_scanC<<<NCHUNK, 256, 0, stream>>>(excl_f, bprefA, cur_f);
    repr_scanA<<<NCHUNK, 256, 0, stream>>>(count_s, excl_s, bsumB);
    repr_scanB<<<1, 256, 0, stream>>>(bsumB, bprefB, ecS);
    repr_scanC<<<NCHUNK, 256, 0, stream>>>(excl_s, bprefB, cur_s);
    repr_scatter<<<N_EDGES / 256, 256, 0, stream>>>(
        R, src, dst, cur_f, cur_s, ssrc_f, sdst_f, ssrc2, sdst2, sidx2, r2);
    repr_embed<<<(N_NODES * 64) / 256, 256, 0, stream>>>(emb, Z, x);

    for (int l = 0; l < L_LAYERS; l++) {
        hipMemsetAsync(denom, 0, (size_t)N_NODES * 2 * 4, stream);
        hipMemsetAsync(mord, 0x80, (size_t)N_NODES * 2 * 4, stream);
        hipMemsetAsync(agg, 0, (size_t)N_NODES * 128 * 4, stream);
        repr_h<<<(N_NODES + 3) / 4, 256, 0, stream>>>(
            x, fc_w + (size_t)l * 64 * 128, attn_l + l * 128, attn_r + l * 128, h, el, er);
        repr_smax<<<N_EDGES / 256, 256, 0, stream>>>(ssrc_f, sdst_f, el, er, ebuf, mord);
        repr_ssum<<<N_EDGES / 256, 256, 0, stream>>>(sdst_f, mord, ebuf, denom);
        repr_msg<<<N_EDGES / TILE, 256, 0, stream>>>(
            ssrc2, sdst2, sidx2, r2, ecS, ebuf, denom, h, offs, widths,
            w1t + (size_t)l * 8192, fb1 + (size_t)l * HID_DIM,
            w2t + (size_t)l * 16384, fb2 + (size_t)l * HD, agg);
        repr_node_mlp<<<(N_NODES + 3) / 4, 256, 0, stream>>>(
            agg, mw1 + (size_t)l * 128 * 64, mb1 + l * 64,
            mw2 + (size_t)l * 64 * 64, mb2 + l * 64, x);
    }
    repr_out<<<(N_NODES + 3) / 4, 256, 0, stream>>>(x, ow1, ob1, ow2, ob2, hh);
    repr_gsum<<<NCHUNK, 256, 0, stream>>>(hh, gids, oacc);
    repr_final<<<1, 64, 0, stream>>>(oacc, (float*)d_out);
}

// Round 7
// 1151.230 us; speedup vs baseline: 6.7011x; 1.0594x over previous
//
#include <hip/hip_runtime.h>
#include <stdint.h>

#define N_NODES 50000
#define N_EDGES 800000
#define B_GRAPHS 64
#define D_DIM 64
#define HD 128
#define G_GAUSS 50
#define HID_DIM 128
#define L_LAYERS 3
#define LN2 0.69314718055994530942f
#define PI_OVER_8 0.39269908169872414f
#define NCHUNK 196            // ceil(50000/256)

typedef __attribute__((ext_vector_type(8))) short bf16x8;
typedef __attribute__((ext_vector_type(4))) float f32x4;

__device__ __forceinline__ float sspf(float x) {
    float ax = fabsf(x);
    return fmaxf(x, 0.f) + __logf(1.f + __expf(-ax)) - LN2;
}
__device__ __forceinline__ unsigned short f2bf(float f) {
    union { float f; unsigned int i; } v; v.f = f;
    unsigned int u = v.i;
    return (unsigned short)((u + 0x7FFFu + ((u >> 16) & 1u)) >> 16);
}

// ------------- one-time: bf16 transposed weights for MFMA B-fragments -------------
__global__ void repr_prep(const float* __restrict__ fw1, const float* __restrict__ fw2,
                          short* __restrict__ w1t, short* __restrict__ w2t) {
    int i = blockIdx.x * 256 + threadIdx.x;
    if (i >= L_LAYERS * 24576) return;
    int l = i / 24576, rem = i % 24576;
    if (rem < 8192) {
        int n = rem >> 6, k = rem & 63;
        float v = (k < G_GAUSS) ? fw1[(size_t)l * G_GAUSS * HID_DIM + k * HID_DIM + n] : 0.f;
        w1t[(size_t)l * 8192 + rem] = (short)f2bf(v);
    } else {
        int r2 = rem - 8192;
        int n = r2 >> 7, k = r2 & 127;
        float v = fw2[(size_t)l * HID_DIM * HD + k * HD + n];
        w2t[(size_t)l * 16384 + r2] = (short)f2bf(v);
    }
}

// ------------- histograms: all edges by dst, and survivors by dst -------------
__global__ void repr_hist(const float* __restrict__ R,
                          const int* __restrict__ src, const int* __restrict__ dst,
                          int* __restrict__ count_f, int* __restrict__ count_s) {
    int e = blockIdx.x * blockDim.x + threadIdx.x;
    if (e >= N_EDGES) return;
    int s = src[e], d = dst[e];
    atomicAdd(&count_f[d], 1);
    float dx = R[3*s+0] - R[3*d+0];
    float dy = R[3*s+1] - R[3*d+1];
    float dz = R[3*s+2] - R[3*d+2];
    float r = sqrtf(dx*dx + dy*dy + dz*dz);
    if (r < 8.0f) atomicAdd(&count_s[d], 1);
}

// ------------- 2-level exclusive scan over 50000 counts -------------
__global__ void repr_scanA(const int* __restrict__ cnt, int* __restrict__ excl,
                           int* __restrict__ bsum) {
    __shared__ int tmp[256];
    int t = threadIdx.x, b = blockIdx.x;
    int i = b * 256 + t;
    int v = (i < N_NODES) ? cnt[i] : 0;
    tmp[t] = v; __syncthreads();
    for (int off = 1; off < 256; off <<= 1) {
        int add = (t >= off) ? tmp[t - off] : 0;
        __syncthreads();
        tmp[t] += add;
        __syncthreads();
    }
    if (i < N_NODES) excl[i] = tmp[t] - v;
    if (t == 255) bsum[b] = tmp[255];
}
__global__ void repr_scanB(const int* __restrict__ bsum, int* __restrict__ bpref,
                           int* __restrict__ ecount) {
    __shared__ int tmp[256];
    int t = threadIdx.x;
    int v = (t < NCHUNK) ? bsum[t] : 0;
    tmp[t] = v; __syncthreads();
    for (int off = 1; off < 256; off <<= 1) {
        int add = (t >= off) ? tmp[t - off] : 0;
        __syncthreads();
        tmp[t] += add;
        __syncthreads();
    }
    if (t < NCHUNK) bpref[t] = tmp[t] - v;
    if (t == 255) ecount[0] = tmp[255];
}
__global__ void repr_scanC(const int* __restrict__ excl, const int* __restrict__ bpref,
                           int* __restrict__ cursor, int* __restrict__ rowptr) {
    int i = blockIdx.x * 256 + threadIdx.x;
    if (i < N_NODES) {
        int v = excl[i] + bpref[blockIdx.x];
        cursor[i] = v;
        if (rowptr) rowptr[i] = v;
    }
}

// ------------- scatter: full dst-sorted list + survivor dst-sorted list -------------
__global__ void repr_scatter(const float* __restrict__ R,
                             const int* __restrict__ src, const int* __restrict__ dst,
                             int* __restrict__ cur_f, int* __restrict__ cur_s,
                             int* __restrict__ ssrc_f, int* __restrict__ sdst_f,
                             int* __restrict__ ssrc2, int* __restrict__ sdst2,
                             float* __restrict__ r2) {
    int e = blockIdx.x * blockDim.x + threadIdx.x;
    if (e >= N_EDGES) return;
    int s = src[e], d = dst[e];
    float dx = R[3*s+0] - R[3*d+0];
    float dy = R[3*s+1] - R[3*d+1];
    float dz = R[3*s+2] - R[3*d+2];
    float r = sqrtf(dx*dx + dy*dy + dz*dz);
    int pos = atomicAdd(&cur_f[d], 1);
    ssrc_f[pos] = s; sdst_f[pos] = d;
    if (r < 8.0f) {
        int p2 = atomicAdd(&cur_s[d], 1);
        ssrc2[p2] = s; sdst2[p2] = d; r2[p2] = r;
    }
}

// ------------- x init from embedding table -------------
__global__ void repr_embed(const float* __restrict__ emb, const int* __restrict__ Z,
                           float* __restrict__ x) {
    int i = blockIdx.x * blockDim.x + threadIdx.x;
    if (i >= N_NODES * D_DIM) return;
    int n = i >> 6, d = i & 63;
    x[i] = emb[Z[n] * D_DIM + d];
}

// ------------- h = x @ fc_w ; attention logits -------------
__global__ void repr_h(const float* __restrict__ x, const float* __restrict__ fc_w,
                       const float* __restrict__ attn_l, const float* __restrict__ attn_r,
                       float* __restrict__ h, float* __restrict__ el, float* __restrict__ er) {
    int wave = threadIdx.x >> 6, lane = threadIdx.x & 63;
    int n = blockIdx.x * 4 + wave;
    if (n >= N_NODES) return;
    float xv = x[n * 64 + lane];
    float a0 = 0.f, a1 = 0.f;
    #pragma unroll 8
    for (int k = 0; k < 64; k++) {
        float xk = __shfl(xv, k, 64);
        a0 = fmaf(xk, fc_w[k * 128 + lane], a0);
        a1 = fmaf(xk, fc_w[k * 128 + 64 + lane], a1);
    }
    h[n * 128 + lane] = a0;
    h[n * 128 + 64 + lane] = a1;
    float p0 = a0 * attn_l[lane];
    float p1 = a1 * attn_l[64 + lane];
    float q0 = a0 * attn_r[lane];
    float q1 = a1 * attn_r[64 + lane];
    #pragma unroll
    for (int off = 32; off > 0; off >>= 1) {
        p0 += __shfl_xor(p0, off, 64);
        p1 += __shfl_xor(p1, off, 64);
        q0 += __shfl_xor(q0, off, 64);
        q1 += __shfl_xor(q1, off, 64);
    }
    if (lane == 0) {
        el[n * 2] = p0; el[n * 2 + 1] = p1;
        er[n * 2] = q0; er[n * 2 + 1] = q1;
    }
}

// ------------- fused softmax stats: one quarter-wave (16 lanes) per dst node -------------
// md[d] = {m0, m1, denom0, denom1}
__global__ void repr_alpha(const int* __restrict__ ssrc_f, const int* __restrict__ rowptr,
                           const float* __restrict__ el, const float* __restrict__ er,
                           float4* __restrict__ md) {
    int t = blockIdx.x * 256 + threadIdx.x;
    int d = t >> 4;
    int lane16 = t & 15;
    if (d >= N_NODES) return;
    int rs = rowptr[d];
    int re = (d == N_NODES - 1) ? N_EDGES : rowptr[d + 1];
    float2 erd = *(const float2*)&er[2 * d];
    float m0 = -3.0e38f, m1 = -3.0e38f;
    for (int i = rs + lane16; i < re; i += 16) {
        int s = ssrc_f[i];
        float2 a = *(const float2*)&el[2 * s];
        float v0 = a.x + erd.x; v0 = v0 >= 0.f ? v0 : 0.2f * v0;
        float v1 = a.y + erd.y; v1 = v1 >= 0.f ? v1 : 0.2f * v1;
        m0 = fmaxf(m0, v0); m1 = fmaxf(m1, v1);
    }
    #pragma unroll
    for (int off = 8; off > 0; off >>= 1) {
        m0 = fmaxf(m0, __shfl_xor(m0, off, 64));
        m1 = fmaxf(m1, __shfl_xor(m1, off, 64));
    }
    float s0 = 0.f, s1 = 0.f;
    for (int i = rs + lane16; i < re; i += 16) {
        int s = ssrc_f[i];
        float2 a = *(const float2*)&el[2 * s];
        float v0 = a.x + erd.x; v0 = v0 >= 0.f ? v0 : 0.2f * v0;
        float v1 = a.y + erd.y; v1 = v1 >= 0.f ? v1 : 0.2f * v1;
        s0 += __expf(v0 - m0); s1 += __expf(v1 - m1);
    }
    #pragma unroll
    for (int off = 8; off > 0; off >>= 1) {
        s0 += __shfl_xor(s0, off, 64);
        s1 += __shfl_xor(s1, off, 64);
    }
    if (lane16 == 0) md[d] = make_float4(m0, m1, s0, s1);
}

// ------------- fused filter-net (MFMA) + message + segmented-reduce scatter -------------
#define TILE 64
#define GS_LD 72        // shorts per gs row (144 B)
#define HID_LD 136      // shorts per hid row (272 B)
#define MSG_LD 132      // floats per msg row
#define HID_OFF 9216    // bytes: gs region = 64*72*2

__global__ __launch_bounds__(256) void repr_msg(
    const int* __restrict__ ssrc2, const int* __restrict__ sdst2,
    const float* __restrict__ r2, const int* __restrict__ ecount,
    const float* __restrict__ el, const float* __restrict__ er,
    const float4* __restrict__ md,
    const float* __restrict__ h,
    const float* __restrict__ offs, const float* __restrict__ widths,
    const short* __restrict__ w1t, const float* __restrict__ b1,
    const short* __restrict__ w2t, const float* __restrict__ b2,
    float* __restrict__ agg)
{
    __shared__ __attribute__((aligned(16))) char lds_main[33792];
    __shared__ float r_s[TILE];
    __shared__ float scale_s[TILE][2];
    __shared__ int src_s[TILE], dst_s[TILE];
    __shared__ int seg_start_s[TILE];
    __shared__ int nseg_s;
    __shared__ float off_s[G_GAUSS], coef_s[G_GAUSS];

    int EC = ecount[0];
    int base = blockIdx.x * TILE;
    if (base >= EC) return;
    int tid = threadIdx.x;
    int lane = tid & 63;
    int w = tid >> 6;
    int l15 = lane & 15;
    int q = lane >> 4;
    int wbase = w * 32;

    bf16x8 bf1[2][2], bf2[2][4];
    float b1c[2], b2c[2];
    #pragma unroll
    for (int nt = 0; nt < 2; nt++) {
        int n = wbase + nt * 16 + l15;
        b1c[nt] = b1[n];
        b2c[nt] = b2[n];
        #pragma unroll
        for (int c = 0; c < 2; c++)
            bf1[nt][c] = *(const bf16x8*)(w1t + n * 64 + c * 32 + q * 8);
        #pragma unroll
        for (int c = 0; c < 4; c++)
            bf2[nt][c] = *(const bf16x8*)(w2t + n * 128 + c * 32 + q * 8);
    }

    if (tid < G_GAUSS) {
        float ww = widths[tid];
        off_s[tid] = offs[tid];
        coef_s[tid] = -0.5f / (ww * ww);
    }
    if (tid < TILE) {
        int i = base + tid;
        int d, sn;
        float sc0, sc1, rr;
        if (i < EC) {
            sn = ssrc2[i]; d = sdst2[i];
            rr = r2[i];
            float C = 0.5f * (__cosf(rr * PI_OVER_8) + 1.f);
            float2 a = *(const float2*)&el[2 * sn];
            float2 b = *(const float2*)&er[2 * d];
            float4 m4 = md[d];
            float v0 = a.x + b.x; v0 = v0 >= 0.f ? v0 : 0.2f * v0;
            float v1 = a.y + b.y; v1 = v1 >= 0.f ? v1 : 0.2f * v1;
            sc0 = C * __expf(v0 - m4.x) / m4.z;
            sc1 = C * __expf(v1 - m4.y) / m4.w;
        } else {
            sn = 0; d = -1; rr = 0.f; sc0 = 0.f; sc1 = 0.f;
        }
        src_s[tid] = sn; dst_s[tid] = d;
        r_s[tid] = rr;
        scale_s[tid][0] = sc0; scale_s[tid][1] = sc1;
        int dprev = __shfl_up(d, 1, 64);
        bool flag = (tid == 0) || (d != dprev);
        unsigned long long mask = __ballot(flag);
        if (flag) seg_start_s[__popcll(mask & ((1ull << tid) - 1ull))] = tid;
        if (tid == 0) nseg_s = (int)__popcll(mask);
    }
    __syncthreads();

    // gaussian tile -> bf16 LDS, A-layout row-major [64][GS_LD], K padded 50->64
    {
        int row = tid >> 2;
        int c16 = (tid & 3) << 4;
        float rr = r_s[row];
        unsigned int pk[8];
        #pragma unroll
        for (int jj = 0; jj < 8; jj++) {
            int k0 = c16 + jj * 2;
            float g0 = 0.f, g1 = 0.f;
            if (k0 < G_GAUSS)     { float dr = rr - off_s[k0];     g0 = __expf(coef_s[k0] * dr * dr); }
            if (k0 + 1 < G_GAUSS) { float dr = rr - off_s[k0 + 1]; g1 = __expf(coef_s[k0 + 1] * dr * dr); }
            pk[jj] = (unsigned int)f2bf(g0) | ((unsigned int)f2bf(g1) << 16);
        }
        char* gp = lds_main + row * (GS_LD * 2) + c16 * 2;
        *(uint4*)gp = *(uint4*)&pk[0];
        *(uint4*)(gp + 16) = *(uint4*)&pk[4];
    }
    __syncthreads();

    // stage 1 MFMA: hid(64x128) = gs(64x64bf16) @ W1(64x128bf16)
    const short* gs_sh = (const short*)lds_main;
    f32x4 acc1[4][2];
    #pragma unroll
    for (int mt = 0; mt < 4; mt++)
        #pragma unroll
        for (int nt = 0; nt < 2; nt++)
            acc1[mt][nt] = (f32x4){0.f, 0.f, 0.f, 0.f};
    #pragma unroll
    for (int mt = 0; mt < 4; mt++) {
        int m = mt * 16 + l15;
        bf16x8 a0 = *(const bf16x8*)(gs_sh + m * GS_LD + q * 8);
        bf16x8 a1 = *(const bf16x8*)(gs_sh + m * GS_LD + 32 + q * 8);
        #pragma unroll
        for (int nt = 0; nt < 2; nt++) {
            acc1[mt][nt] = __builtin_amdgcn_mfma_f32_16x16x32_bf16(a0, bf1[nt][0], acc1[mt][nt], 0, 0, 0);
            acc1[mt][nt] = __builtin_amdgcn_mfma_f32_16x16x32_bf16(a1, bf1[nt][1], acc1[mt][nt], 0, 0, 0);
        }
    }
    short* hid_sh = (short*)(lds_main + HID_OFF);
    #pragma unroll
    for (int mt = 0; mt < 4; mt++)
        #pragma unroll
        for (int nt = 0; nt < 2; nt++) {
            int colg = wbase + nt * 16 + l15;
            #pragma unroll
            for (int rg = 0; rg < 4; rg++) {
                int row = mt * 16 + q * 4 + rg;   // C/D: col=lane&15, row=quad*4+reg
                float v = sspf(acc1[mt][nt][rg] + b1c[nt]);
                hid_sh[row * HID_LD + colg] = (short)f2bf(v);
            }
        }
    __syncthreads();

    // stage 2 MFMA: wv(64x128) = hid(64x128bf16) @ W2(128x128bf16)
    f32x4 acc2[4][2];
    #pragma unroll
    for (int mt = 0; mt < 4; mt++)
        #pragma unroll
        for (int nt = 0; nt < 2; nt++)
            acc2[mt][nt] = (f32x4){0.f, 0.f, 0.f, 0.f};
    #pragma unroll
    for (int mt = 0; mt < 4; mt++) {
        int m = mt * 16 + l15;
        #pragma unroll
        for (int c = 0; c < 4; c++) {
            bf16x8 a = *(const bf16x8*)(hid_sh + m * HID_LD + c * 32 + q * 8);
            #pragma unroll
            for (int nt = 0; nt < 2; nt++)
                acc2[mt][nt] = __builtin_amdgcn_mfma_f32_16x16x32_bf16(a, bf2[nt][c], acc2[mt][nt], 0, 0, 0);
        }
    }
    __syncthreads();

    // epilogue: msg = scale * (wv + b2) * h[src] -> fp32 LDS [64][MSG_LD]
    float* msg_f = (float*)lds_main;
    int head = w >> 1;
    #pragma unroll
    for (int mt = 0; mt < 4; mt++)
        #pragma unroll
        for (int nt = 0; nt < 2; nt++) {
            int colg = wbase + nt * 16 + l15;
            #pragma unroll
            for (int rg = 0; rg < 4; rg++) {
                int row = mt * 16 + q * 4 + rg;
                float sc = scale_s[row][head];
                float hv = h[(size_t)src_s[row] * HD + colg];
                msg_f[row * MSG_LD + colg] = (acc2[mt][nt][rg] + b2c[nt]) * hv * sc;
            }
        }
    __syncthreads();

    // segmented reduction: one write per (dst,col) per tile
    {
        int nseg = nseg_s;
        int col = tid & 127;
        int sp = tid >> 7;
        for (int s = sp; s < nseg; s += 2) {
            int r0 = seg_start_s[s];
            int r1 = (s + 1 < nseg) ? seg_start_s[s + 1] : TILE;
            int d = dst_s[r0];
            if (d < 0) continue;
            float sum = 0.f;
            for (int r = r0; r < r1; r++) sum += msg_f[r * MSG_LD + col];
            float* ap = &agg[(size_t)d * HD + col];
            if (s == 0 || s == nseg - 1) atomicAdd(ap, sum);
            else *ap = sum;
        }
    }
}

// ------------- node MLP: x += mlp(ssp(agg)) -------------
__global__ void repr_node_mlp(const float* __restrict__ agg,
                              const float* __restrict__ w1, const float* __restrict__ b1,
                              const float* __restrict__ w2, const float* __restrict__ b2,
                              float* __restrict__ x) {
    int wave = threadIdx.x >> 6, lane = threadIdx.x & 63;
    int n = blockIdx.x * 4 + wave;
    if (n >= N_NODES) return;
    float t0 = sspf(agg[n * 128 + lane]);
    float t1 = sspf(agg[n * 128 + 64 + lane]);
    float a = 0.f;
    #pragma unroll 8
    for (int k = 0; k < 64; k++) {
        float u0 = __shfl(t0, k, 64);
        float u1 = __shfl(t1, k, 64);
        a = fmaf(u0, w1[k * 64 + lane], a);
        a = fmaf(u1, w1[(64 + k) * 64 + lane], a);
    }
    float v1 = sspf(a + b1[lane]);
    float b = 0.f;
    #pragma unroll 8
    for (int k = 0; k < 64; k++) {
        float u = __shfl(v1, k, 64);
        b = fmaf(u, w2[k * 64 + lane], b);
    }
    x[n * 64 + lane] += b + b2[lane];
}

// ------------- output MLP: per-node scalar, coalesced store (NO atomics) -------------
__global__ void repr_out(const float* __restrict__ x,
                         const float* __restrict__ w1, const float* __restrict__ b1,
                         const float* __restrict__ w2, const float* __restrict__ b2,
                         float* __restrict__ hh) {
    int wave = threadIdx.x >> 6, lane = threadIdx.x & 63;
    int n = blockIdx.x * 4 + wave;
    if (n >= N_NODES) return;
    float xv = x[n * 64 + lane];
    float a0 = 0.f, a1 = 0.f;
    #pragma unroll 8
    for (int k = 0; k < 64; k++) {
        float xk = __shfl(xv, k, 64);
        a0 = fmaf(xk, w1[k * 128 + lane], a0);
        a1 = fmaf(xk, w1[k * 128 + 64 + lane], a1);
    }
    float y0 = sspf(a0 + b1[lane]);
    float y1 = sspf(a1 + b1[64 + lane]);
    float s = y0 * w2[lane] + y1 * w2[64 + lane];
    #pragma unroll
    for (int off = 32; off > 0; off >>= 1) s += __shfl_xor(s, off, 64);
    if (lane == 0) hh[n] = s + b2[0];
}

// ------------- graph segment-sum with LDS privatization (~2 atomics/block) -------------
__global__ void repr_gsum(const float* __restrict__ hh, const int* __restrict__ gids,
                          float* __restrict__ out_acc) {
    __shared__ float bins[B_GRAPHS];
    int t = threadIdx.x;
    if (t < B_GRAPHS) bins[t] = 0.f;
    __syncthreads();
    int i = blockIdx.x * 256 + t;
    if (i < N_NODES) atomicAdd(&bins[gids[i]], hh[i]);
    __syncthreads();
    if (t < B_GRAPHS && bins[t] != 0.f) atomicAdd(&out_acc[t], bins[t]);
}

__global__ void repr_final(const float* __restrict__ out_acc, float* __restrict__ out) {
    int i = threadIdx.x;
    if (i < B_GRAPHS) out[i] = out_acc[i];
}

extern "C" void kernel_launch(void* const* d_in, const int* in_sizes, int n_in,
                              void* d_out, int out_size, void* d_ws, size_t ws_size,
                              hipStream_t stream) {
    (void)in_sizes; (void)n_in; (void)out_size; (void)ws_size;
    const float* R      = (const float*)d_in[0];
    const int*   Z      = (const int*)d_in[1];
    const int*   src    = (const int*)d_in[2];
    const int*   dst    = (const int*)d_in[3];
    const int*   gids   = (const int*)d_in[4];
    const float* emb    = (const float*)d_in[5];
    const float* offs   = (const float*)d_in[6];
    const float* widths = (const float*)d_in[7];
    const float* fc_w   = (const float*)d_in[8];
    const float* attn_l = (const float*)d_in[9];
    const float* attn_r = (const float*)d_in[10];
    const float* fw1    = (const float*)d_in[11];
    const float* fb1    = (const float*)d_in[12];
    const float* fw2    = (const float*)d_in[13];
    const float* fb2    = (const float*)d_in[14];
    const float* mw1    = (const float*)d_in[15];
    const float* mb1    = (const float*)d_in[16];
    const float* mw2    = (const float*)d_in[17];
    const float* mb2    = (const float*)d_in[18];
    const float* ow1    = (const float*)d_in[19];
    const float* ob1    = (const float*)d_in[20];
    const float* ow2    = (const float*)d_in[21];
    const float* ob2    = (const float*)d_in[22];

    char* p = (char*)d_ws;
    float* x      = (float*)p; p += (size_t)N_NODES * 64 * 4;     // 12.8 MB
    float* h      = (float*)p; p += (size_t)N_NODES * 128 * 4;    // 25.6 MB
    float* el     = (float*)p; p += (size_t)N_NODES * 2 * 4;
    float* er     = (float*)p; p += (size_t)N_NODES * 2 * 4;
    float4* md    = (float4*)p; p += (size_t)N_NODES * 16;        // 800 KB
    float* agg    = (float*)p; p += (size_t)N_NODES * 128 * 4;    // 25.6 MB
    int*   ssrc_f = (int*)p;   p += (size_t)N_EDGES * 4;
    int*   sdst_f = (int*)p;   p += (size_t)N_EDGES * 4;
    int*   rowptr = (int*)p;   p += (size_t)N_NODES * 4;          // 200 KB (persistent)
    int*   ssrc2  = (int*)p;   p += (size_t)N_EDGES * 4;
    int*   sdst2  = (int*)p;   p += (size_t)N_EDGES * 4;
    float* r2     = (float*)p; p += (size_t)N_EDGES * 4;
    short* w1t    = (short*)p; p += (size_t)L_LAYERS * 8192 * 2;   // 48 KB
    short* w2t    = (short*)p; p += (size_t)L_LAYERS * 16384 * 2;  // 96 KB
    int*   bsumA  = (int*)p;   p += 1024;
    int*   bprefA = (int*)p;   p += 1024;
    int*   bsumB  = (int*)p;   p += 1024;
    int*   bprefB = (int*)p;   p += 1024;
    int*   ecF    = (int*)p;   p += 256;
    int*   ecS    = (int*)p;   p += 256;
    float* oacc   = (float*)p; p += 256;
    // scan temporaries aliased into x (x written by repr_embed, strictly after
    // repr_scatter in stream order):
    int* count_f = (int*)x;
    int* excl_f  = (int*)((char*)x + 256 * 1024);
    int* cur_f   = (int*)((char*)x + 512 * 1024);
    int* count_s = (int*)((char*)x + 768 * 1024);
    int* excl_s  = (int*)((char*)x + 1024 * 1024);
    int* cur_s   = (int*)((char*)x + 1280 * 1024);
    // hh scratch aliased into agg (agg dead after last repr_node_mlp)
    float* hh = agg;

    hipMemsetAsync(x, 0, 1536 * 1024, stream);
    hipMemsetAsync(oacc, 0, B_GRAPHS * 4, stream);

    repr_prep<<<(L_LAYERS * 24576 + 255) / 256, 256, 0, stream>>>(fw1, fw2, w1t, w2t);
    repr_hist<<<N_EDGES / 256, 256, 0, stream>>>(R, src, dst, count_f, count_s);
    repr_scanA<<<NCHUNK, 256, 0, stream>>>(count_f, excl_f, bsumA);
    repr_scanB<<<1, 256, 0, stream>>>(bsumA, bprefA, ecF);
    repr_scanC<<<NCHUNK, 256, 0, stream>>>(excl_f, bprefA, cur_f, rowptr);
    repr_scanA<<<NCHUNK, 256, 0, stream>>>(count_s, excl_s, bsumB);
    repr_scanB<<<1, 256, 0, stream>>>(bsumB, bprefB, ecS);
    repr_scanC<<<NCHUNK, 256, 0, stream>>>(excl_s, bprefB, cur_s, (int*)nullptr);
    repr_scatter<<<N_EDGES / 256, 256, 0, stream>>>(
        R, src, dst, cur_f, cur_s, ssrc_f, sdst_f, ssrc2, sdst2, r2);
    repr_embed<<<(N_NODES * 64) / 256, 256, 0, stream>>>(emb, Z, x);

    for (int l = 0; l < L_LAYERS; l++) {
        hipMemsetAsync(agg, 0, (size_t)N_NODES * 128 * 4, stream);
        repr_h<<<(N_NODES + 3) / 4, 256, 0, stream>>>(
            x, fc_w + (size_t)l * 64 * 128, attn_l + l * 128, attn_r + l * 128, h, el, er);
        repr_alpha<<<(N_NODES * 16 + 255) / 256, 256, 0, stream>>>(ssrc_f, rowptr, el, er, md);
        repr_msg<<<N_EDGES / TILE, 256, 0, stream>>>(
            ssrc2, sdst2, r2, ecS, el, er, md, h, offs, widths,
            w1t + (size_t)l * 8192, fb1 + (size_t)l * HID_DIM,
            w2t + (size_t)l * 16384, fb2 + (size_t)l * HD, agg);
        repr_node_mlp<<<(N_NODES + 3) / 4, 256, 0, stream>>>(
            agg, mw1 + (size_t)l * 128 * 64, mb1 + l * 64,
            mw2 + (size_t)l * 64 * 64, mb2 + l * 64, x);
    }
    repr_out<<<(N_NODES + 3) / 4, 256, 0, stream>>>(x, ow1, ob1, ow2, ob2, hh);
    repr_gsum<<<NCHUNK, 256, 0, stream>>>(hh, gids, oacc);
    repr_final<<<1, 64, 0, stream>>>(oacc, (float*)d_out);
}

// Round 8
// 1099.417 us; speedup vs baseline: 7.0169x; 1.0471x over previous
//
#include <hip/hip_runtime.h>
#include <stdint.h>

#define N_NODES 50000
#define N_EDGES 800000
#define B_GRAPHS 64
#define D_DIM 64
#define HD 128
#define G_GAUSS 50
#define HID_DIM 128
#define L_LAYERS 3
#define LN2 0.69314718055994530942f
#define PI_OVER_8 0.39269908169872414f
#define NCHUNK 196            // ceil(50000/256)

typedef __attribute__((ext_vector_type(8))) short bf16x8;
typedef __attribute__((ext_vector_type(4))) float f32x4;

__device__ __forceinline__ float sspf(float x) {
    float ax = fabsf(x);
    return fmaxf(x, 0.f) + __logf(1.f + __expf(-ax)) - LN2;
}
__device__ __forceinline__ unsigned short f2bf(float f) {
    union { float f; unsigned int i; } v; v.f = f;
    unsigned int u = v.i;
    return (unsigned short)((u + 0x7FFFu + ((u >> 16) & 1u)) >> 16);
}

// ------------- one-time: bf16 transposed weights for MFMA B-fragments -------------
__global__ void repr_prep(const float* __restrict__ fw1, const float* __restrict__ fw2,
                          short* __restrict__ w1t, short* __restrict__ w2t) {
    int i = blockIdx.x * 256 + threadIdx.x;
    if (i >= L_LAYERS * 24576) return;
    int l = i / 24576, rem = i % 24576;
    if (rem < 8192) {
        int n = rem >> 6, k = rem & 63;
        float v = (k < G_GAUSS) ? fw1[(size_t)l * G_GAUSS * HID_DIM + k * HID_DIM + n] : 0.f;
        w1t[(size_t)l * 8192 + rem] = (short)f2bf(v);
    } else {
        int r2 = rem - 8192;
        int n = r2 >> 7, k = r2 & 127;
        float v = fw2[(size_t)l * HID_DIM * HD + k * HD + n];
        w2t[(size_t)l * 16384 + r2] = (short)f2bf(v);
    }
}

// ------------- histograms (+ store r per edge) -------------
__global__ void repr_hist(const float* __restrict__ R,
                          const int* __restrict__ src, const int* __restrict__ dst,
                          int* __restrict__ count_f, int* __restrict__ count_s,
                          float* __restrict__ r_full) {
    int e = blockIdx.x * blockDim.x + threadIdx.x;
    if (e >= N_EDGES) return;
    int s = src[e], d = dst[e];
    atomicAdd(&count_f[d], 1);
    float dx = R[3*s+0] - R[3*d+0];
    float dy = R[3*s+1] - R[3*d+1];
    float dz = R[3*s+2] - R[3*d+2];
    float r = sqrtf(dx*dx + dy*dy + dz*dz);
    r_full[e] = r;
    if (r < 8.0f) atomicAdd(&count_s[d], 1);
}

// ------------- dual 2-level exclusive scan over 50000 counts -------------
__global__ void repr_scanA2(const int* __restrict__ cntA, int* __restrict__ exclA,
                            int* __restrict__ bsumA,
                            const int* __restrict__ cntB, int* __restrict__ exclB,
                            int* __restrict__ bsumB) {
    __shared__ int tmp[256];
    int t = threadIdx.x, b = blockIdx.x;
    const int* cnt; int* excl; int* bsum; int bb;
    if (b < NCHUNK) { cnt = cntA; excl = exclA; bsum = bsumA; bb = b; }
    else            { cnt = cntB; excl = exclB; bsum = bsumB; bb = b - NCHUNK; }
    int i = bb * 256 + t;
    int v = (i < N_NODES) ? cnt[i] : 0;
    tmp[t] = v; __syncthreads();
    for (int off = 1; off < 256; off <<= 1) {
        int add = (t >= off) ? tmp[t - off] : 0;
        __syncthreads();
        tmp[t] += add;
        __syncthreads();
    }
    if (i < N_NODES) excl[i] = tmp[t] - v;
    if (t == 255) bsum[bb] = tmp[255];
}
__global__ void repr_scanB2(const int* __restrict__ bsumA, int* __restrict__ bprefA,
                            int* __restrict__ ecA,
                            const int* __restrict__ bsumB, int* __restrict__ bprefB,
                            int* __restrict__ ecB) {
    __shared__ int tmp[256];
    const int* bsum = blockIdx.x ? bsumB : bsumA;
    int* bpref = blockIdx.x ? bprefB : bprefA;
    int* ec = blockIdx.x ? ecB : ecA;
    int t = threadIdx.x;
    int v = (t < NCHUNK) ? bsum[t] : 0;
    tmp[t] = v; __syncthreads();
    for (int off = 1; off < 256; off <<= 1) {
        int add = (t >= off) ? tmp[t - off] : 0;
        __syncthreads();
        tmp[t] += add;
        __syncthreads();
    }
    if (t < NCHUNK) bpref[t] = tmp[t] - v;
    if (t == 255) ec[0] = tmp[255];
}
__global__ void repr_scanC2(const int* __restrict__ exclA, const int* __restrict__ bprefA,
                            int* __restrict__ curA, int* __restrict__ rowptr,
                            const int* __restrict__ exclB, const int* __restrict__ bprefB,
                            int* __restrict__ curB) {
    int b = blockIdx.x;
    if (b < NCHUNK) {
        int i = b * 256 + threadIdx.x;
        if (i < N_NODES) { int v = exclA[i] + bprefA[b]; curA[i] = v; rowptr[i] = v; }
    } else {
        int i = (b - NCHUNK) * 256 + threadIdx.x;
        if (i < N_NODES) curB[i] = exclB[i] + bprefB[b - NCHUNK];
    }
}

// ------------- scatter: full dst-sorted list + survivor dst-sorted list -------------
__global__ void repr_scatter(const float* __restrict__ r_full,
                             const int* __restrict__ src, const int* __restrict__ dst,
                             int* __restrict__ cur_f, int* __restrict__ cur_s,
                             int* __restrict__ ssrc_f, int* __restrict__ sdst_f,
                             int* __restrict__ ssrc2, int* __restrict__ sdst2,
                             float* __restrict__ r2) {
    int e = blockIdx.x * blockDim.x + threadIdx.x;
    if (e >= N_EDGES) return;
    int s = src[e], d = dst[e];
    float r = r_full[e];
    int pos = atomicAdd(&cur_f[d], 1);
    ssrc_f[pos] = s; sdst_f[pos] = d;
    if (r < 8.0f) {
        int p2 = atomicAdd(&cur_s[d], 1);
        ssrc2[p2] = s; sdst2[p2] = d; r2[p2] = r;
    }
}

// ------------- shared h/el/er body -------------
__device__ __forceinline__ void h_body(float xv, int n, int lane,
                                       const float* __restrict__ fc_w,
                                       const float* __restrict__ attn_l,
                                       const float* __restrict__ attn_r,
                                       float* __restrict__ h, float* __restrict__ el,
                                       float* __restrict__ er) {
    float a0 = 0.f, a1 = 0.f;
    #pragma unroll 8
    for (int k = 0; k < 64; k++) {
        float xk = __shfl(xv, k, 64);
        a0 = fmaf(xk, fc_w[k * 128 + lane], a0);
        a1 = fmaf(xk, fc_w[k * 128 + 64 + lane], a1);
    }
    h[n * 128 + lane] = a0;
    h[n * 128 + 64 + lane] = a1;
    float p0 = a0 * attn_l[lane];
    float p1 = a1 * attn_l[64 + lane];
    float q0 = a0 * attn_r[lane];
    float q1 = a1 * attn_r[64 + lane];
    #pragma unroll
    for (int off = 32; off > 0; off >>= 1) {
        p0 += __shfl_xor(p0, off, 64);
        p1 += __shfl_xor(p1, off, 64);
        q0 += __shfl_xor(q0, off, 64);
        q1 += __shfl_xor(q1, off, 64);
    }
    if (lane == 0) {
        el[n * 2] = p0; el[n * 2 + 1] = p1;
        er[n * 2] = q0; er[n * 2 + 1] = q1;
    }
}

// ------------- layer 0: embed + h -------------
__global__ void repr_embed_h(const float* __restrict__ emb, const int* __restrict__ Z,
                             const float* __restrict__ fc_w, const float* __restrict__ attn_l,
                             const float* __restrict__ attn_r,
                             float* __restrict__ x, float* __restrict__ h,
                             float* __restrict__ el, float* __restrict__ er) {
    int wave = threadIdx.x >> 6, lane = threadIdx.x & 63;
    int n = blockIdx.x * 4 + wave;
    if (n >= N_NODES) return;
    float xv = emb[Z[n] * D_DIM + lane];
    x[n * 64 + lane] = xv;
    h_body(xv, n, lane, fc_w, attn_l, attn_r, h, el, er);
}

// ------------- shared node-MLP body: returns x_new for this (n,lane) -------------
__device__ __forceinline__ float mlp_body(const float* __restrict__ agg, int n, int lane,
                                          const float* __restrict__ w1,
                                          const float* __restrict__ b1,
                                          const float* __restrict__ w2,
                                          const float* __restrict__ b2,
                                          const float* __restrict__ x) {
    float t0 = sspf(agg[n * 128 + lane]);
    float t1 = sspf(agg[n * 128 + 64 + lane]);
    float a = 0.f;
    #pragma unroll 8
    for (int k = 0; k < 64; k++) {
        float u0 = __shfl(t0, k, 64);
        float u1 = __shfl(t1, k, 64);
        a = fmaf(u0, w1[k * 64 + lane], a);
        a = fmaf(u1, w1[(64 + k) * 64 + lane], a);
    }
    float v1 = sspf(a + b1[lane]);
    float b = 0.f;
    #pragma unroll 8
    for (int k = 0; k < 64; k++) {
        float u = __shfl(v1, k, 64);
        b = fmaf(u, w2[k * 64 + lane], b);
    }
    return x[n * 64 + lane] + b + b2[lane];
}

// ------------- mid layers: node MLP + h of next layer -------------
__global__ void repr_mlp_h(const float* __restrict__ agg,
                           const float* __restrict__ w1, const float* __restrict__ b1,
                           const float* __restrict__ w2, const float* __restrict__ b2,
                           const float* __restrict__ fc_w, const float* __restrict__ attn_l,
                           const float* __restrict__ attn_r,
                           float* __restrict__ x, float* __restrict__ h,
                           float* __restrict__ el, float* __restrict__ er) {
    int wave = threadIdx.x >> 6, lane = threadIdx.x & 63;
    int n = blockIdx.x * 4 + wave;
    if (n >= N_NODES) return;
    float xv = mlp_body(agg, n, lane, w1, b1, w2, b2, x);
    x[n * 64 + lane] = xv;
    h_body(xv, n, lane, fc_w, attn_l, attn_r, h, el, er);
}

// ------------- last layer: node MLP + output MLP -> hh (no atomics) -------------
__global__ void repr_mlp_out(const float* __restrict__ agg,
                             const float* __restrict__ w1, const float* __restrict__ b1,
                             const float* __restrict__ w2, const float* __restrict__ b2,
                             const float* __restrict__ ow1, const float* __restrict__ ob1,
                             const float* __restrict__ ow2, const float* __restrict__ ob2,
                             const float* __restrict__ x, float* __restrict__ hh) {
    int wave = threadIdx.x >> 6, lane = threadIdx.x & 63;
    int n = blockIdx.x * 4 + wave;
    if (n >= N_NODES) return;
    float xv = mlp_body(agg, n, lane, w1, b1, w2, b2, x);
    float a0 = 0.f, a1 = 0.f;
    #pragma unroll 8
    for (int k = 0; k < 64; k++) {
        float xk = __shfl(xv, k, 64);
        a0 = fmaf(xk, ow1[k * 128 + lane], a0);
        a1 = fmaf(xk, ow1[k * 128 + 64 + lane], a1);
    }
    float y0 = sspf(a0 + ob1[lane]);
    float y1 = sspf(a1 + ob1[64 + lane]);
    float s = y0 * ow2[lane] + y1 * ow2[64 + lane];
    #pragma unroll
    for (int off = 32; off > 0; off >>= 1) s += __shfl_xor(s, off, 64);
    if (lane == 0) hh[n] = s + ob2[0];
}

// ------------- online softmax stats (single pass) + agg zeroing -------------
// md[d] = {m0, m1, denom0, denom1}; one quarter-wave (16 lanes) per dst node
__global__ void repr_alpha(const int* __restrict__ ssrc_f, const int* __restrict__ rowptr,
                           const float* __restrict__ el, const float* __restrict__ er,
                           float4* __restrict__ md, float* __restrict__ agg) {
    int t = blockIdx.x * 256 + threadIdx.x;
    int d = t >> 4;
    int lane16 = t & 15;
    if (d >= N_NODES) return;
    // zero agg row d (16 lanes x 32 B)
    float4 z = make_float4(0.f, 0.f, 0.f, 0.f);
    float4* ar = (float4*)(agg + (size_t)d * HD);
    ar[lane16 * 2] = z;
    ar[lane16 * 2 + 1] = z;
    int rs = rowptr[d];
    int re = (d == N_NODES - 1) ? N_EDGES : rowptr[d + 1];
    float2 erd = *(const float2*)&er[2 * d];
    float m0 = -3.0e38f, m1 = -3.0e38f, s0 = 0.f, s1 = 0.f;
    for (int i = rs + lane16; i < re; i += 16) {
        int s = ssrc_f[i];
        float2 a = *(const float2*)&el[2 * s];
        float v0 = a.x + erd.x; v0 = v0 >= 0.f ? v0 : 0.2f * v0;
        float v1 = a.y + erd.y; v1 = v1 >= 0.f ? v1 : 0.2f * v1;
        float mn0 = fmaxf(m0, v0);
        s0 = s0 * __expf(m0 - mn0) + __expf(v0 - mn0);
        m0 = mn0;
        float mn1 = fmaxf(m1, v1);
        s1 = s1 * __expf(m1 - mn1) + __expf(v1 - mn1);
        m1 = mn1;
    }
    #pragma unroll
    for (int off = 8; off > 0; off >>= 1) {
        float mo = __shfl_xor(m0, off, 64);
        float so = __shfl_xor(s0, off, 64);
        float mn = fmaxf(m0, mo);
        s0 = s0 * __expf(m0 - mn) + so * __expf(mo - mn);
        m0 = mn;
        float mo1 = __shfl_xor(m1, off, 64);
        float so1 = __shfl_xor(s1, off, 64);
        float mn1 = fmaxf(m1, mo1);
        s1 = s1 * __expf(m1 - mn1) + so1 * __expf(mo1 - mn1);
        m1 = mn1;
    }
    if (lane16 == 0) md[d] = make_float4(m0, m1, s0, s1);
}

// ------------- fused filter-net (MFMA) + message + segmented-reduce scatter -------------
#define TILE 64
#define GS_LD 72        // shorts per gs row (144 B)
#define HID_LD 136      // shorts per hid row (272 B)
#define MSG_LD 132      // floats per msg row
#define HID_OFF 9216    // bytes: gs region = 64*72*2

__global__ __launch_bounds__(256) void repr_msg(
    const int* __restrict__ ssrc2, const int* __restrict__ sdst2,
    const float* __restrict__ r2, const int* __restrict__ ecount,
    const float* __restrict__ el, const float* __restrict__ er,
    const float4* __restrict__ md,
    const float* __restrict__ h,
    const float* __restrict__ offs, const float* __restrict__ widths,
    const short* __restrict__ w1t, const float* __restrict__ b1,
    const short* __restrict__ w2t, const float* __restrict__ b2,
    float* __restrict__ agg)
{
    __shared__ __attribute__((aligned(16))) char lds_main[33792];
    __shared__ float r_s[TILE];
    __shared__ float scale_s[TILE][2];
    __shared__ int src_s[TILE], dst_s[TILE];
    __shared__ int seg_start_s[TILE];
    __shared__ int nseg_s;
    __shared__ float off_s[G_GAUSS], coef_s[G_GAUSS];

    int EC = ecount[0];
    int base = blockIdx.x * TILE;
    if (base >= EC) return;
    int tid = threadIdx.x;
    int lane = tid & 63;
    int w = tid >> 6;
    int l15 = lane & 15;
    int q = lane >> 4;
    int wbase = w * 32;

    bf16x8 bf1[2][2], bf2[2][4];
    float b1c[2], b2c[2];
    #pragma unroll
    for (int nt = 0; nt < 2; nt++) {
        int n = wbase + nt * 16 + l15;
        b1c[nt] = b1[n];
        b2c[nt] = b2[n];
        #pragma unroll
        for (int c = 0; c < 2; c++)
            bf1[nt][c] = *(const bf16x8*)(w1t + n * 64 + c * 32 + q * 8);
        #pragma unroll
        for (int c = 0; c < 4; c++)
            bf2[nt][c] = *(const bf16x8*)(w2t + n * 128 + c * 32 + q * 8);
    }

    if (tid < G_GAUSS) {
        float ww = widths[tid];
        off_s[tid] = offs[tid];
        coef_s[tid] = -0.5f / (ww * ww);
    }
    if (tid < TILE) {
        int i = base + tid;
        int d, sn;
        float sc0, sc1, rr;
        if (i < EC) {
            sn = ssrc2[i]; d = sdst2[i];
            rr = r2[i];
            float C = 0.5f * (__cosf(rr * PI_OVER_8) + 1.f);
            float2 a = *(const float2*)&el[2 * sn];
            float2 b = *(const float2*)&er[2 * d];
            float4 m4 = md[d];
            float v0 = a.x + b.x; v0 = v0 >= 0.f ? v0 : 0.2f * v0;
            float v1 = a.y + b.y; v1 = v1 >= 0.f ? v1 : 0.2f * v1;
            sc0 = C * __expf(v0 - m4.x) / m4.z;
            sc1 = C * __expf(v1 - m4.y) / m4.w;
        } else {
            sn = 0; d = -1; rr = 0.f; sc0 = 0.f; sc1 = 0.f;
        }
        src_s[tid] = sn; dst_s[tid] = d;
        r_s[tid] = rr;
        scale_s[tid][0] = sc0; scale_s[tid][1] = sc1;
        int dprev = __shfl_up(d, 1, 64);
        bool flag = (tid == 0) || (d != dprev);
        unsigned long long mask = __ballot(flag);
        if (flag) seg_start_s[__popcll(mask & ((1ull << tid) - 1ull))] = tid;
        if (tid == 0) nseg_s = (int)__popcll(mask);
    }
    __syncthreads();

    // gaussian tile -> bf16 LDS, A-layout row-major [64][GS_LD], K padded 50->64
    {
        int row = tid >> 2;
        int c16 = (tid & 3) << 4;
        float rr = r_s[row];
        unsigned int pk[8];
        #pragma unroll
        for (int jj = 0; jj < 8; jj++) {
            int k0 = c16 + jj * 2;
            float g0 = 0.f, g1 = 0.f;
            if (k0 < G_GAUSS)     { float dr = rr - off_s[k0];     g0 = __expf(coef_s[k0] * dr * dr); }
            if (k0 + 1 < G_GAUSS) { float dr = rr - off_s[k0 + 1]; g1 = __expf(coef_s[k0 + 1] * dr * dr); }
            pk[jj] = (unsigned int)f2bf(g0) | ((unsigned int)f2bf(g1) << 16);
        }
        char* gp = lds_main + row * (GS_LD * 2) + c16 * 2;
        *(uint4*)gp = *(uint4*)&pk[0];
        *(uint4*)(gp + 16) = *(uint4*)&pk[4];
    }
    __syncthreads();

    // stage 1 MFMA: hid(64x128) = gs(64x64bf16) @ W1(64x128bf16)
    const short* gs_sh = (const short*)lds_main;
    f32x4 acc1[4][2];
    #pragma unroll
    for (int mt = 0; mt < 4; mt++)
        #pragma unroll
        for (int nt = 0; nt < 2; nt++)
            acc1[mt][nt] = (f32x4){0.f, 0.f, 0.f, 0.f};
    #pragma unroll
    for (int mt = 0; mt < 4; mt++) {
        int m = mt * 16 + l15;
        bf16x8 a0 = *(const bf16x8*)(gs_sh + m * GS_LD + q * 8);
        bf16x8 a1 = *(const bf16x8*)(gs_sh + m * GS_LD + 32 + q * 8);
        #pragma unroll
        for (int nt = 0; nt < 2; nt++) {
            acc1[mt][nt] = __builtin_amdgcn_mfma_f32_16x16x32_bf16(a0, bf1[nt][0], acc1[mt][nt], 0, 0, 0);
            acc1[mt][nt] = __builtin_amdgcn_mfma_f32_16x16x32_bf16(a1, bf1[nt][1], acc1[mt][nt], 0, 0, 0);
        }
    }
    short* hid_sh = (short*)(lds_main + HID_OFF);
    #pragma unroll
    for (int mt = 0; mt < 4; mt++)
        #pragma unroll
        for (int nt = 0; nt < 2; nt++) {
            int colg = wbase + nt * 16 + l15;
            #pragma unroll
            for (int rg = 0; rg < 4; rg++) {
                int row = mt * 16 + q * 4 + rg;   // C/D: col=lane&15, row=quad*4+reg
                float v = sspf(acc1[mt][nt][rg] + b1c[nt]);
                hid_sh[row * HID_LD + colg] = (short)f2bf(v);
            }
        }
    __syncthreads();

    // stage 2 MFMA: wv(64x128) = hid(64x128bf16) @ W2(128x128bf16)
    f32x4 acc2[4][2];
    #pragma unroll
    for (int mt = 0; mt < 4; mt++)
        #pragma unroll
        for (int nt = 0; nt < 2; nt++)
            acc2[mt][nt] = (f32x4){0.f, 0.f, 0.f, 0.f};
    #pragma unroll
    for (int mt = 0; mt < 4; mt++) {
        int m = mt * 16 + l15;
        #pragma unroll
        for (int c = 0; c < 4; c++) {
            bf16x8 a = *(const bf16x8*)(hid_sh + m * HID_LD + c * 32 + q * 8);
            #pragma unroll
            for (int nt = 0; nt < 2; nt++)
                acc2[mt][nt] = __builtin_amdgcn_mfma_f32_16x16x32_bf16(a, bf2[nt][c], acc2[mt][nt], 0, 0, 0);
        }
    }
    __syncthreads();

    // epilogue: msg = scale * (wv + b2) * h[src] -> fp32 LDS [64][MSG_LD]
    float* msg_f = (float*)lds_main;
    int head = w >> 1;
    #pragma unroll
    for (int mt = 0; mt < 4; mt++)
        #pragma unroll
        for (int nt = 0; nt < 2; nt++) {
            int colg = wbase + nt * 16 + l15;
            #pragma unroll
            for (int rg = 0; rg < 4; rg++) {
                int row = mt * 16 + q * 4 + rg;
                float sc = scale_s[row][head];
                float hv = h[(size_t)src_s[row] * HD + colg];
                msg_f[row * MSG_LD + colg] = (acc2[mt][nt][rg] + b2c[nt]) * hv * sc;
            }
        }
    __syncthreads();

    // segmented reduction: one write per (dst,col) per tile
    {
        int nseg = nseg_s;
        int col = tid & 127;
        int sp = tid >> 7;
        for (int s = sp; s < nseg; s += 2) {
            int r0 = seg_start_s[s];
            int r1 = (s + 1 < nseg) ? seg_start_s[s + 1] : TILE;
            int d = dst_s[r0];
            if (d < 0) continue;
            float sum = 0.f;
            for (int r = r0; r < r1; r++) sum += msg_f[r * MSG_LD + col];
            float* ap = &agg[(size_t)d * HD + col];
            if (s == 0 || s == nseg - 1) atomicAdd(ap, sum);
            else *ap = sum;
        }
    }
}

// ------------- graph segment-sum with LDS privatization (~2 atomics/block) -------------
__global__ void repr_gsum(const float* __restrict__ hh, const int* __restrict__ gids,
                          float* __restrict__ out_acc) {
    __shared__ float bins[B_GRAPHS];
    int t = threadIdx.x;
    if (t < B_GRAPHS) bins[t] = 0.f;
    __syncthreads();
    int i = blockIdx.x * 256 + t;
    if (i < N_NODES) atomicAdd(&bins[gids[i]], hh[i]);
    __syncthreads();
    if (t < B_GRAPHS && bins[t] != 0.f) atomicAdd(&out_acc[t], bins[t]);
}

__global__ void repr_final(const float* __restrict__ out_acc, float* __restrict__ out) {
    int i = threadIdx.x;
    if (i < B_GRAPHS) out[i] = out_acc[i];
}

extern "C" void kernel_launch(void* const* d_in, const int* in_sizes, int n_in,
                              void* d_out, int out_size, void* d_ws, size_t ws_size,
                              hipStream_t stream) {
    (void)in_sizes; (void)n_in; (void)out_size; (void)ws_size;
    const float* R      = (const float*)d_in[0];
    const int*   Z      = (const int*)d_in[1];
    const int*   src    = (const int*)d_in[2];
    const int*   dst    = (const int*)d_in[3];
    const int*   gids   = (const int*)d_in[4];
    const float* emb    = (const float*)d_in[5];
    const float* offs   = (const float*)d_in[6];
    const float* widths = (const float*)d_in[7];
    const float* fc_w   = (const float*)d_in[8];
    const float* attn_l = (const float*)d_in[9];
    const float* attn_r = (const float*)d_in[10];
    const float* fw1    = (const float*)d_in[11];
    const float* fb1    = (const float*)d_in[12];
    const float* fw2    = (const float*)d_in[13];
    const float* fb2    = (const float*)d_in[14];
    const float* mw1    = (const float*)d_in[15];
    const float* mb1    = (const float*)d_in[16];
    const float* mw2    = (const float*)d_in[17];
    const float* mb2    = (const float*)d_in[18];
    const float* ow1    = (const float*)d_in[19];
    const float* ob1    = (const float*)d_in[20];
    const float* ow2    = (const float*)d_in[21];
    const float* ob2    = (const float*)d_in[22];

    char* p = (char*)d_ws;
    float* x      = (float*)p; p += (size_t)N_NODES * 64 * 4;     // 12.8 MB
    float* h      = (float*)p; p += (size_t)N_NODES * 128 * 4;    // 25.6 MB
    float* el     = (float*)p; p += (size_t)N_NODES * 2 * 4;
    float* er     = (float*)p; p += (size_t)N_NODES * 2 * 4;
    float4* md    = (float4*)p; p += (size_t)N_NODES * 16;        // 800 KB
    float* agg    = (float*)p; p += (size_t)N_NODES * 128 * 4;    // 25.6 MB
    int*   ssrc_f = (int*)p;   p += (size_t)N_EDGES * 4;
    int*   sdst_f = (int*)p;   p += (size_t)N_EDGES * 4;
    int*   rowptr = (int*)p;   p += (size_t)N_NODES * 4;          // 200 KB
    int*   ssrc2  = (int*)p;   p += (size_t)N_EDGES * 4;
    int*   sdst2  = (int*)p;   p += (size_t)N_EDGES * 4;
    float* r2     = (float*)p; p += (size_t)N_EDGES * 4;
    float* r_full = (float*)p; p += (size_t)N_EDGES * 4;          // 3.2 MB
    float* hh     = (float*)p; p += (size_t)N_NODES * 4;          // 200 KB
    short* w1t    = (short*)p; p += (size_t)L_LAYERS * 8192 * 2;   // 48 KB
    short* w2t    = (short*)p; p += (size_t)L_LAYERS * 16384 * 2;  // 96 KB
    int*   bsumA  = (int*)p;   p += 1024;
    int*   bprefA = (int*)p;   p += 1024;
    int*   bsumB  = (int*)p;   p += 1024;
    int*   bprefB = (int*)p;   p += 1024;
    int*   ecF    = (int*)p;   p += 256;
    int*   ecS    = (int*)p;   p += 256;
    float* oacc   = (float*)p; p += 256;
    // scan temporaries aliased into x (x written by repr_embed_h, strictly after
    // repr_scatter in stream order):
    int* count_f = (int*)x;
    int* excl_f  = (int*)((char*)x + 256 * 1024);
    int* cur_f   = (int*)((char*)x + 512 * 1024);
    int* count_s = (int*)((char*)x + 768 * 1024);
    int* excl_s  = (int*)((char*)x + 1024 * 1024);
    int* cur_s   = (int*)((char*)x + 1280 * 1024);

    hipMemsetAsync(x, 0, 1536 * 1024, stream);
    hipMemsetAsync(oacc, 0, B_GRAPHS * 4, stream);

    // one-time prep: weight transpose, dst-sorted edge lists
    repr_prep<<<(L_LAYERS * 24576 + 255) / 256, 256, 0, stream>>>(fw1, fw2, w1t, w2t);
    repr_hist<<<N_EDGES / 256, 256, 0, stream>>>(R, src, dst, count_f, count_s, r_full);
    repr_scanA2<<<2 * NCHUNK, 256, 0, stream>>>(count_f, excl_f, bsumA,
                                                count_s, excl_s, bsumB);
    repr_scanB2<<<2, 256, 0, stream>>>(bsumA, bprefA, ecF, bsumB, bprefB, ecS);
    repr_scanC2<<<2 * NCHUNK, 256, 0, stream>>>(excl_f, bprefA, cur_f, rowptr,
                                                excl_s, bprefB, cur_s);
    repr_scatter<<<N_EDGES / 256, 256, 0, stream>>>(
        r_full, src, dst, cur_f, cur_s, ssrc_f, sdst_f, ssrc2, sdst2, r2);

    // layer 0 node path
    repr_embed_h<<<(N_NODES + 3) / 4, 256, 0, stream>>>(
        emb, Z, fc_w, attn_l, attn_r, x, h, el, er);

    for (int l = 0; l < L_LAYERS; l++) {
        repr_alpha<<<(N_NODES * 16 + 255) / 256, 256, 0, stream>>>(
            ssrc_f, rowptr, el, er, md, agg);
        repr_msg<<<N_EDGES / TILE, 256, 0, stream>>>(
            ssrc2, sdst2, r2, ecS, el, er, md, h, offs, widths,
            w1t + (size_t)l * 8192, fb1 + (size_t)l * HID_DIM,
            w2t + (size_t)l * 16384, fb2 + (size_t)l * HD, agg);
        if (l < L_LAYERS - 1) {
            repr_mlp_h<<<(N_NODES + 3) / 4, 256, 0, stream>>>(
                agg, mw1 + (size_t)l * 128 * 64, mb1 + l * 64,
                mw2 + (size_t)l * 64 * 64, mb2 + l * 64,
                fc_w + (size_t)(l + 1) * 64 * 128, attn_l + (l + 1) * 128,
                attn_r + (l + 1) * 128, x, h, el, er);
        } else {
            repr_mlp_out<<<(N_NODES + 3) / 4, 256, 0, stream>>>(
                agg, mw1 + (size_t)l * 128 * 64, mb1 + l * 64,
                mw2 + (size_t)l * 64 * 64, mb2 + l * 64,
                ow1, ob1, ow2, ob2, x, hh);
        }
    }
    repr_gsum<<<NCHUNK, 256, 0, stream>>>(hh, gids, oacc);
    repr_final<<<1, 64, 0, stream>>>(oacc, (float*)d_out);
}

// Round 9
// 796.109 us; speedup vs baseline: 9.6903x; 1.3810x over previous
//
#include <hip/hip_runtime.h>
#include <stdint.h>

#define N_NODES 50000
#define N_EDGES 800000
#define B_GRAPHS 64
#define D_DIM 64
#define HD 128
#define G_GAUSS 50
#define HID_DIM 128
#define L_LAYERS 3
#define LN2 0.69314718055994530942f
#define PI_OVER_8 0.39269908169872414f
#define NCHUNK 196            // ceil(50000/256)

#define TN 64                 // nodes per node-GEMM block
#define TLD 132               // fp32 LDS leading dim for 128-wide tiles
#define XLD 68                // fp32 LDS leading dim for 64-wide tiles
#define NBLK ((N_NODES + TN - 1) / TN)   // 782

typedef __attribute__((ext_vector_type(8))) short bf16x8;
typedef __attribute__((ext_vector_type(4))) float f32x4;

__device__ __forceinline__ float sspf(float x) {
    float ax = fabsf(x);
    return fmaxf(x, 0.f) + __logf(1.f + __expf(-ax)) - LN2;
}
__device__ __forceinline__ unsigned short f2bf(float f) {
    union { float f; unsigned int i; } v; v.f = f;
    unsigned int u = v.i;
    return (unsigned short)((u + 0x7FFFu + ((u >> 16) & 1u)) >> 16);
}

// ------------- one-time: bf16 transposed weights for MFMA B-fragments -------------
__global__ void repr_prep(const float* __restrict__ fw1, const float* __restrict__ fw2,
                          short* __restrict__ w1t, short* __restrict__ w2t) {
    int i = blockIdx.x * 256 + threadIdx.x;
    if (i >= L_LAYERS * 24576) return;
    int l = i / 24576, rem = i % 24576;
    if (rem < 8192) {
        int n = rem >> 6, k = rem & 63;
        float v = (k < G_GAUSS) ? fw1[(size_t)l * G_GAUSS * HID_DIM + k * HID_DIM + n] : 0.f;
        w1t[(size_t)l * 8192 + rem] = (short)f2bf(v);
    } else {
        int r2 = rem - 8192;
        int n = r2 >> 7, k = r2 & 127;
        float v = fw2[(size_t)l * HID_DIM * HD + k * HD + n];
        w2t[(size_t)l * 16384 + r2] = (short)f2bf(v);
    }
}

// ------------- histograms (+ store r per edge) -------------
__global__ void repr_hist(const float* __restrict__ R,
                          const int* __restrict__ src, const int* __restrict__ dst,
                          int* __restrict__ count_f, int* __restrict__ count_s,
                          float* __restrict__ r_full) {
    int e = blockIdx.x * blockDim.x + threadIdx.x;
    if (e >= N_EDGES) return;
    int s = src[e], d = dst[e];
    atomicAdd(&count_f[d], 1);
    float dx = R[3*s+0] - R[3*d+0];
    float dy = R[3*s+1] - R[3*d+1];
    float dz = R[3*s+2] - R[3*d+2];
    float r = sqrtf(dx*dx + dy*dy + dz*dz);
    r_full[e] = r;
    if (r < 8.0f) atomicAdd(&count_s[d], 1);
}

// ------------- dual 2-level exclusive scan over 50000 counts -------------
__global__ void repr_scanA2(const int* __restrict__ cntA, int* __restrict__ exclA,
                            int* __restrict__ bsumA,
                            const int* __restrict__ cntB, int* __restrict__ exclB,
                            int* __restrict__ bsumB) {
    __shared__ int tmp[256];
    int t = threadIdx.x, b = blockIdx.x;
    const int* cnt; int* excl; int* bsum; int bb;
    if (b < NCHUNK) { cnt = cntA; excl = exclA; bsum = bsumA; bb = b; }
    else            { cnt = cntB; excl = exclB; bsum = bsumB; bb = b - NCHUNK; }
    int i = bb * 256 + t;
    int v = (i < N_NODES) ? cnt[i] : 0;
    tmp[t] = v; __syncthreads();
    for (int off = 1; off < 256; off <<= 1) {
        int add = (t >= off) ? tmp[t - off] : 0;
        __syncthreads();
        tmp[t] += add;
        __syncthreads();
    }
    if (i < N_NODES) excl[i] = tmp[t] - v;
    if (t == 255) bsum[bb] = tmp[255];
}
__global__ void repr_scanB2(const int* __restrict__ bsumA, int* __restrict__ bprefA,
                            int* __restrict__ ecA,
                            const int* __restrict__ bsumB, int* __restrict__ bprefB,
                            int* __restrict__ ecB) {
    __shared__ int tmp[256];
    const int* bsum = blockIdx.x ? bsumB : bsumA;
    int* bpref = blockIdx.x ? bprefB : bprefA;
    int* ec = blockIdx.x ? ecB : ecA;
    int t = threadIdx.x;
    int v = (t < NCHUNK) ? bsum[t] : 0;
    tmp[t] = v; __syncthreads();
    for (int off = 1; off < 256; off <<= 1) {
        int add = (t >= off) ? tmp[t - off] : 0;
        __syncthreads();
        tmp[t] += add;
        __syncthreads();
    }
    if (t < NCHUNK) bpref[t] = tmp[t] - v;
    if (t == 255) ec[0] = tmp[255];
}
__global__ void repr_scanC2(const int* __restrict__ exclA, const int* __restrict__ bprefA,
                            int* __restrict__ curA, int* __restrict__ rowptr,
                            const int* __restrict__ exclB, const int* __restrict__ bprefB,
                            int* __restrict__ curB) {
    int b = blockIdx.x;
    if (b < NCHUNK) {
        int i = b * 256 + threadIdx.x;
        if (i < N_NODES) { int v = exclA[i] + bprefA[b]; curA[i] = v; rowptr[i] = v; }
    } else {
        int i = (b - NCHUNK) * 256 + threadIdx.x;
        if (i < N_NODES) curB[i] = exclB[i] + bprefB[b - NCHUNK];
    }
}

// ------------- scatter: full dst-sorted list + survivor dst-sorted list -------------
__global__ void repr_scatter(const float* __restrict__ r_full,
                             const int* __restrict__ src, const int* __restrict__ dst,
                             int* __restrict__ cur_f, int* __restrict__ cur_s,
                             int* __restrict__ ssrc_f, int* __restrict__ sdst_f,
                             int* __restrict__ ssrc2, int* __restrict__ sdst2,
                             float* __restrict__ r2) {
    int e = blockIdx.x * blockDim.x + threadIdx.x;
    if (e >= N_EDGES) return;
    int s = src[e], d = dst[e];
    float r = r_full[e];
    int pos = atomicAdd(&cur_f[d], 1);
    ssrc_f[pos] = s; sdst_f[pos] = d;
    if (r < 8.0f) {
        int p2 = atomicAdd(&cur_s[d], 1);
        ssrc2[p2] = s; sdst2[p2] = d; r2[p2] = r;
    }
}

// ================= tiled fp32 node GEMMs (64 nodes / block, 256 threads) =================

// t = ssp(agg tile) -> bufA[TLD]
__device__ __forceinline__ void load_ssp_agg(int base, int tid,
        const float* __restrict__ agg, float* __restrict__ bufA) {
    int row = tid >> 2;
    int c0 = (tid & 3) << 5;   // 0,32,64,96
    const float* ap = agg + (size_t)(base + row) * HD + c0;
    float* tp = bufA + row * TLD + c0;
    #pragma unroll
    for (int j = 0; j < 8; j++) {
        float4 v = *(const float4*)(ap + j * 4);
        tp[j*4+0] = sspf(v.x); tp[j*4+1] = sspf(v.y);
        tp[j*4+2] = sspf(v.z); tp[j*4+3] = sspf(v.w);
    }
}

// GEMM1 (t@w1,K=128) -> ssp -> v1s; GEMM2 (v1@w2,K=64) + b2 + x -> xn in bufA[XLD] + x global
__device__ __forceinline__ void gemm_mlp(int base, int tid,
        const float* __restrict__ w1, const float* __restrict__ b1,
        const float* __restrict__ w2, const float* __restrict__ b2,
        float* __restrict__ x, float* __restrict__ bufA, float* __restrict__ v1s)
{
    const int rg = tid >> 4, cg = tid & 15;
    const int r0 = rg * 4, c0 = cg * 4;
    float acc[4][4];
    #pragma unroll
    for (int r = 0; r < 4; r++)
        #pragma unroll
        for (int c = 0; c < 4; c++) acc[r][c] = 0.f;
    for (int k0 = 0; k0 < 128; k0 += 4) {
        float av[4][4];
        #pragma unroll
        for (int r = 0; r < 4; r++)
            *(float4*)av[r] = *(const float4*)&bufA[(r0 + r) * TLD + k0];
        #pragma unroll
        for (int kk = 0; kk < 4; kk++) {
            float4 wv = *(const float4*)(w1 + (k0 + kk) * 64 + c0);
            float wf[4] = {wv.x, wv.y, wv.z, wv.w};
            #pragma unroll
            for (int r = 0; r < 4; r++)
                #pragma unroll
                for (int c = 0; c < 4; c++)
                    acc[r][c] = fmaf(av[r][kk], wf[c], acc[r][c]);
        }
    }
    {
        float4 bv = *(const float4*)(b1 + c0);
        float ba[4] = {bv.x, bv.y, bv.z, bv.w};
        #pragma unroll
        for (int r = 0; r < 4; r++)
            #pragma unroll
            for (int c = 0; c < 4; c++)
                v1s[(r0 + r) * XLD + c0 + c] = sspf(acc[r][c] + ba[c]);
    }
    __syncthreads();
    float acc2[4][4];
    #pragma unroll
    for (int r = 0; r < 4; r++)
        #pragma unroll
        for (int c = 0; c < 4; c++) acc2[r][c] = 0.f;
    for (int k0 = 0; k0 < 64; k0 += 4) {
        float av[4][4];
        #pragma unroll
        for (int r = 0; r < 4; r++)
            *(float4*)av[r] = *(const float4*)&v1s[(r0 + r) * XLD + k0];
        #pragma unroll
        for (int kk = 0; kk < 4; kk++) {
            float4 wv = *(const float4*)(w2 + (k0 + kk) * 64 + c0);
            float wf[4] = {wv.x, wv.y, wv.z, wv.w};
            #pragma unroll
            for (int r = 0; r < 4; r++)
                #pragma unroll
                for (int c = 0; c < 4; c++)
                    acc2[r][c] = fmaf(av[r][kk], wf[c], acc2[r][c]);
        }
    }
    {
        float4 bv = *(const float4*)(b2 + c0);
        #pragma unroll
        for (int r = 0; r < 4; r++) {
            int n = base + r0 + r;
            float4 xv = *(const float4*)(x + (size_t)n * 64 + c0);
            float4 o;
            o.x = acc2[r][0] + bv.x + xv.x;
            o.y = acc2[r][1] + bv.y + xv.y;
            o.z = acc2[r][2] + bv.z + xv.z;
            o.w = acc2[r][3] + bv.w + xv.w;
            *(float4*)&bufA[(r0 + r) * XLD + c0] = o;
            if (n < N_NODES) *(float4*)(x + (size_t)n * 64 + c0) = o;
        }
    }
    __syncthreads();
}

// GEMM3: h = xn @ fc_w (K=64, N=128) + attention logits
__device__ __forceinline__ void gemm_h(int base, int tid,
        const float* __restrict__ bufA,
        const float* __restrict__ fc_w, const float* __restrict__ attn_l,
        const float* __restrict__ attn_r,
        float* __restrict__ h, float* __restrict__ el, float* __restrict__ er)
{
    const int rg = tid >> 4, cg = tid & 15;
    const int r0 = rg * 4, c0 = cg * 8;
    float acc[4][8];
    #pragma unroll
    for (int r = 0; r < 4; r++)
        #pragma unroll
        for (int c = 0; c < 8; c++) acc[r][c] = 0.f;
    for (int k0 = 0; k0 < 64; k0 += 4) {
        float av[4][4];
        #pragma unroll
        for (int r = 0; r < 4; r++)
            *(float4*)av[r] = *(const float4*)&bufA[(r0 + r) * XLD + k0];
        #pragma unroll
        for (int kk = 0; kk < 4; kk++) {
            float4 w0 = *(const float4*)(fc_w + (k0 + kk) * 128 + c0);
            float4 w1v = *(const float4*)(fc_w + (k0 + kk) * 128 + c0 + 4);
            float wf[8] = {w0.x, w0.y, w0.z, w0.w, w1v.x, w1v.y, w1v.z, w1v.w};
            #pragma unroll
            for (int r = 0; r < 4; r++)
                #pragma unroll
                for (int c = 0; c < 8; c++)
                    acc[r][c] = fmaf(av[r][kk], wf[c], acc[r][c]);
        }
    }
    float al[8], ar[8];
    #pragma unroll
    for (int c = 0; c < 8; c++) { al[c] = attn_l[c0 + c]; ar[c] = attn_r[c0 + c]; }
    int head = cg >> 3;
    #pragma unroll
    for (int r = 0; r < 4; r++) {
        int n = base + r0 + r;
        float pel = 0.f, per = 0.f;
        #pragma unroll
        for (int c = 0; c < 8; c++) {
            pel = fmaf(acc[r][c], al[c], pel);
            per = fmaf(acc[r][c], ar[c], per);
        }
        if (n < N_NODES) {
            float4 lo = {acc[r][0], acc[r][1], acc[r][2], acc[r][3]};
            float4 hi = {acc[r][4], acc[r][5], acc[r][6], acc[r][7]};
            *(float4*)(h + (size_t)n * HD + c0) = lo;
            *(float4*)(h + (size_t)n * HD + c0 + 4) = hi;
        }
        #pragma unroll
        for (int off = 1; off < 8; off <<= 1) {
            pel += __shfl_xor(pel, off, 64);
            per += __shfl_xor(per, off, 64);
        }
        if ((cg & 7) == 0 && n < N_NODES) {
            el[n * 2 + head] = pel;
            er[n * 2 + head] = per;
        }
    }
}

// ------------- layer 0: embed + h -------------
__global__ __launch_bounds__(256) void repr_embed_h(
        const float* __restrict__ emb, const int* __restrict__ Z,
        const float* __restrict__ fc_w, const float* __restrict__ attn_l,
        const float* __restrict__ attn_r,
        float* __restrict__ x, float* __restrict__ h,
        float* __restrict__ el, float* __restrict__ er) {
    __shared__ float bufA[TN * XLD];
    int base = blockIdx.x * TN, tid = threadIdx.x;
    int row = tid >> 2;
    int c0 = (tid & 3) << 4;   // 0,16,32,48
    int n = base + row;
    int z = (n < N_NODES) ? Z[n] : 0;
    const float* ep = emb + (size_t)z * D_DIM + c0;
    float* bp = bufA + row * XLD + c0;
    #pragma unroll
    for (int j = 0; j < 4; j++) {
        float4 v = *(const float4*)(ep + j * 4);
        *(float4*)(bp + j * 4) = v;
        if (n < N_NODES) *(float4*)(x + (size_t)n * D_DIM + c0 + j * 4) = v;
    }
    __syncthreads();
    gemm_h(base, tid, bufA, fc_w, attn_l, attn_r, h, el, er);
}

// ------------- mid layers: node MLP + h of next layer -------------
__global__ __launch_bounds__(256) void repr_mlp_h(
        const float* __restrict__ agg,
        const float* __restrict__ w1, const float* __restrict__ b1,
        const float* __restrict__ w2, const float* __restrict__ b2,
        const float* __restrict__ fc_w, const float* __restrict__ attn_l,
        const float* __restrict__ attn_r,
        float* __restrict__ x, float* __restrict__ h,
        float* __restrict__ el, float* __restrict__ er) {
    __shared__ float bufA[TN * TLD];
    __shared__ float v1s[TN * XLD];
    int base = blockIdx.x * TN, tid = threadIdx.x;
    load_ssp_agg(base, tid, agg, bufA);
    __syncthreads();
    gemm_mlp(base, tid, w1, b1, w2, b2, x, bufA, v1s);
    gemm_h(base, tid, bufA, fc_w, attn_l, attn_r, h, el, er);
}

// ------------- last layer: node MLP + output MLP -> hh -------------
__global__ __launch_bounds__(256) void repr_mlp_out(
        const float* __restrict__ agg,
        const float* __restrict__ w1, const float* __restrict__ b1,
        const float* __restrict__ w2, const float* __restrict__ b2,
        const float* __restrict__ ow1, const float* __restrict__ ob1,
        const float* __restrict__ ow2, const float* __restrict__ ob2,
        float* __restrict__ x, float* __restrict__ hh) {
    __shared__ float bufA[TN * TLD];
    __shared__ float v1s[TN * XLD];
    int base = blockIdx.x * TN, tid = threadIdx.x;
    load_ssp_agg(base, tid, agg, bufA);
    __syncthreads();
    gemm_mlp(base, tid, w1, b1, w2, b2, x, bufA, v1s);
    // out MLP: y = ssp(xn @ ow1 + ob1), hh = y @ ow2 + ob2
    const int rg = tid >> 4, cg = tid & 15;
    const int r0 = rg * 4, c0 = cg * 8;
    float acc[4][8];
    #pragma unroll
    for (int r = 0; r < 4; r++)
        #pragma unroll
        for (int c = 0; c < 8; c++) acc[r][c] = 0.f;
    for (int k0 = 0; k0 < 64; k0 += 4) {
        float av[4][4];
        #pragma unroll
        for (int r = 0; r < 4; r++)
            *(float4*)av[r] = *(const float4*)&bufA[(r0 + r) * XLD + k0];
        #pragma unroll
        for (int kk = 0; kk < 4; kk++) {
            float4 w0 = *(const float4*)(ow1 + (k0 + kk) * 128 + c0);
            float4 w1v = *(const float4*)(ow1 + (k0 + kk) * 128 + c0 + 4);
            float wf[8] = {w0.x, w0.y, w0.z, w0.w, w1v.x, w1v.y, w1v.z, w1v.w};
            #pragma unroll
            for (int r = 0; r < 4; r++)
                #pragma unroll
                for (int c = 0; c < 8; c++)
                    acc[r][c] = fmaf(av[r][kk], wf[c], acc[r][c]);
        }
    }
    float o1[8], w2c[8];
    #pragma unroll
    for (int c = 0; c < 8; c++) { o1[c] = ob1[c0 + c]; w2c[c] = ow2[c0 + c]; }
    #pragma unroll
    for (int r = 0; r < 4; r++) {
        int n = base + r0 + r;
        float s = 0.f;
        #pragma unroll
        for (int c = 0; c < 8; c++)
            s = fmaf(sspf(acc[r][c] + o1[c]), w2c[c], s);
        #pragma unroll
        for (int off = 1; off < 16; off <<= 1)
            s += __shfl_xor(s, off, 64);
        if (cg == 0 && n < N_NODES) hh[n] = s + ob2[0];
    }
}

// ------------- online softmax stats (single pass) + agg zeroing -------------
__global__ void repr_alpha(const int* __restrict__ ssrc_f, const int* __restrict__ rowptr,
                           const float* __restrict__ el, const float* __restrict__ er,
                           float4* __restrict__ md, float* __restrict__ agg) {
    int t = blockIdx.x * 256 + threadIdx.x;
    int d = t >> 4;
    int lane16 = t & 15;
    if (d >= N_NODES) return;
    float4 z = make_float4(0.f, 0.f, 0.f, 0.f);
    float4* ar = (float4*)(agg + (size_t)d * HD);
    ar[lane16 * 2] = z;
    ar[lane16 * 2 + 1] = z;
    int rs = rowptr[d];
    int re = (d == N_NODES - 1) ? N_EDGES : rowptr[d + 1];
    float2 erd = *(const float2*)&er[2 * d];
    float m0 = -3.0e38f, m1 = -3.0e38f, s0 = 0.f, s1 = 0.f;
    for (int i = rs + lane16; i < re; i += 16) {
        int s = ssrc_f[i];
        float2 a = *(const float2*)&el[2 * s];
        float v0 = a.x + erd.x; v0 = v0 >= 0.f ? v0 : 0.2f * v0;
        float v1 = a.y + erd.y; v1 = v1 >= 0.f ? v1 : 0.2f * v1;
        float mn0 = fmaxf(m0, v0);
        s0 = s0 * __expf(m0 - mn0) + __expf(v0 - mn0);
        m0 = mn0;
        float mn1 = fmaxf(m1, v1);
        s1 = s1 * __expf(m1 - mn1) + __expf(v1 - mn1);
        m1 = mn1;
    }
    #pragma unroll
    for (int off = 8; off > 0; off >>= 1) {
        float mo = __shfl_xor(m0, off, 64);
        float so = __shfl_xor(s0, off, 64);
        float mn = fmaxf(m0, mo);
        s0 = s0 * __expf(m0 - mn) + so * __expf(mo - mn);
        m0 = mn;
        float mo1 = __shfl_xor(m1, off, 64);
        float so1 = __shfl_xor(s1, off, 64);
        float mn1 = fmaxf(m1, mo1);
        s1 = s1 * __expf(m1 - mn1) + so1 * __expf(mo1 - mn1);
        m1 = mn1;
    }
    if (lane16 == 0) md[d] = make_float4(m0, m1, s0, s1);
}

// ------------- fused filter-net (MFMA) + message + segmented-reduce scatter -------------
#define TILE 64
#define GS_LD 72
#define HID_LD 136
#define MSG_LD 132
#define HID_OFF 9216

__global__ __launch_bounds__(256) void repr_msg(
    const int* __restrict__ ssrc2, const int* __restrict__ sdst2,
    const float* __restrict__ r2, const int* __restrict__ ecount,
    const float* __restrict__ el, const float* __restrict__ er,
    const float4* __restrict__ md,
    const float* __restrict__ h,
    const float* __restrict__ offs, const float* __restrict__ widths,
    const short* __restrict__ w1t, const float* __restrict__ b1,
    const short* __restrict__ w2t, const float* __restrict__ b2,
    float* __restrict__ agg)
{
    __shared__ __attribute__((aligned(16))) char lds_main[33792];
    __shared__ float r_s[TILE];
    __shared__ float scale_s[TILE][2];
    __shared__ int src_s[TILE], dst_s[TILE];
    __shared__ int seg_start_s[TILE];
    __shared__ int nseg_s;
    __shared__ float off_s[G_GAUSS], coef_s[G_GAUSS];

    int EC = ecount[0];
    int base = blockIdx.x * TILE;
    if (base >= EC) return;
    int tid = threadIdx.x;
    int lane = tid & 63;
    int w = tid >> 6;
    int l15 = lane & 15;
    int q = lane >> 4;
    int wbase = w * 32;

    bf16x8 bf1[2][2], bf2[2][4];
    float b1c[2], b2c[2];
    #pragma unroll
    for (int nt = 0; nt < 2; nt++) {
        int n = wbase + nt * 16 + l15;
        b1c[nt] = b1[n];
        b2c[nt] = b2[n];
        #pragma unroll
        for (int c = 0; c < 2; c++)
            bf1[nt][c] = *(const bf16x8*)(w1t + n * 64 + c * 32 + q * 8);
        #pragma unroll
        for (int c = 0; c < 4; c++)
            bf2[nt][c] = *(const bf16x8*)(w2t + n * 128 + c * 32 + q * 8);
    }

    if (tid < G_GAUSS) {
        float ww = widths[tid];
        off_s[tid] = offs[tid];
        coef_s[tid] = -0.5f / (ww * ww);
    }
    if (tid < TILE) {
        int i = base + tid;
        int d, sn;
        float sc0, sc1, rr;
        if (i < EC) {
            sn = ssrc2[i]; d = sdst2[i];
            rr = r2[i];
            float C = 0.5f * (__cosf(rr * PI_OVER_8) + 1.f);
            float2 a = *(const float2*)&el[2 * sn];
            float2 b = *(const float2*)&er[2 * d];
            float4 m4 = md[d];
            float v0 = a.x + b.x; v0 = v0 >= 0.f ? v0 : 0.2f * v0;
            float v1 = a.y + b.y; v1 = v1 >= 0.f ? v1 : 0.2f * v1;
            sc0 = C * __expf(v0 - m4.x) / m4.z;
            sc1 = C * __expf(v1 - m4.y) / m4.w;
        } else {
            sn = 0; d = -1; rr = 0.f; sc0 = 0.f; sc1 = 0.f;
        }
        src_s[tid] = sn; dst_s[tid] = d;
        r_s[tid] = rr;
        scale_s[tid][0] = sc0; scale_s[tid][1] = sc1;
        int dprev = __shfl_up(d, 1, 64);
        bool flag = (tid == 0) || (d != dprev);
        unsigned long long mask = __ballot(flag);
        if (flag) seg_start_s[__popcll(mask & ((1ull << tid) - 1ull))] = tid;
        if (tid == 0) nseg_s = (int)__popcll(mask);
    }
    __syncthreads();

    {
        int row = tid >> 2;
        int c16 = (tid & 3) << 4;
        float rr = r_s[row];
        unsigned int pk[8];
        #pragma unroll
        for (int jj = 0; jj < 8; jj++) {
            int k0 = c16 + jj * 2;
            float g0 = 0.f, g1 = 0.f;
            if (k0 < G_GAUSS)     { float dr = rr - off_s[k0];     g0 = __expf(coef_s[k0] * dr * dr); }
            if (k0 + 1 < G_GAUSS) { float dr = rr - off_s[k0 + 1]; g1 = __expf(coef_s[k0 + 1] * dr * dr); }
            pk[jj] = (unsigned int)f2bf(g0) | ((unsigned int)f2bf(g1) << 16);
        }
        char* gp = lds_main + row * (GS_LD * 2) + c16 * 2;
        *(uint4*)gp = *(uint4*)&pk[0];
        *(uint4*)(gp + 16) = *(uint4*)&pk[4];
    }
    __syncthreads();

    const short* gs_sh = (const short*)lds_main;
    f32x4 acc1[4][2];
    #pragma unroll
    for (int mt = 0; mt < 4; mt++)
        #pragma unroll
        for (int nt = 0; nt < 2; nt++)
            acc1[mt][nt] = (f32x4){0.f, 0.f, 0.f, 0.f};
    #pragma unroll
    for (int mt = 0; mt < 4; mt++) {
        int m = mt * 16 + l15;
        bf16x8 a0 = *(const bf16x8*)(gs_sh + m * GS_LD + q * 8);
        bf16x8 a1 = *(const bf16x8*)(gs_sh + m * GS_LD + 32 + q * 8);
        #pragma unroll
        for (int nt = 0; nt < 2; nt++) {
            acc1[mt][nt] = __builtin_amdgcn_mfma_f32_16x16x32_bf16(a0, bf1[nt][0], acc1[mt][nt], 0, 0, 0);
            acc1[mt][nt] = __builtin_amdgcn_mfma_f32_16x16x32_bf16(a1, bf1[nt][1], acc1[mt][nt], 0, 0, 0);
        }
    }
    short* hid_sh = (short*)(lds_main + HID_OFF);
    #pragma unroll
    for (int mt = 0; mt < 4; mt++)
        #pragma unroll
        for (int nt = 0; nt < 2; nt++) {
            int colg = wbase + nt * 16 + l15;
            #pragma unroll
            for (int rg = 0; rg < 4; rg++) {
                int row = mt * 16 + q * 4 + rg;
                float v = sspf(acc1[mt][nt][rg] + b1c[nt]);
                hid_sh[row * HID_LD + colg] = (short)f2bf(v);
            }
        }
    __syncthreads();

    f32x4 acc2[4][2];
    #pragma unroll
    for (int mt = 0; mt < 4; mt++)
        #pragma unroll
        for (int nt = 0; nt < 2; nt++)
            acc2[mt][nt] = (f32x4){0.f, 0.f, 0.f, 0.f};
    #pragma unroll
    for (int mt = 0; mt < 4; mt++) {
        int m = mt * 16 + l15;
        #pragma unroll
        for (int c = 0; c < 4; c++) {
            bf16x8 a = *(const bf16x8*)(hid_sh + m * HID_LD + c * 32 + q * 8);
            #pragma unroll
            for (int nt = 0; nt < 2; nt++)
                acc2[mt][nt] = __builtin_amdgcn_mfma_f32_16x16x32_bf16(a, bf2[nt][c], acc2[mt][nt], 0, 0, 0);
        }
    }
    __syncthreads();

    float* msg_f = (float*)lds_main;
    int head = w >> 1;
    #pragma unroll
    for (int mt = 0; mt < 4; mt++)
        #pragma unroll
        for (int nt = 0; nt < 2; nt++) {
            int colg = wbase + nt * 16 + l15;
            #pragma unroll
            for (int rg = 0; rg < 4; rg++) {
                int row = mt * 16 + q * 4 + rg;
                float sc = scale_s[row][head];
                float hv = h[(size_t)src_s[row] * HD + colg];
                msg_f[row * MSG_LD + colg] = (acc2[mt][nt][rg] + b2c[nt]) * hv * sc;
            }
        }
    __syncthreads();

    {
        int nseg = nseg_s;
        int col = tid & 127;
        int sp = tid >> 7;
        for (int s = sp; s < nseg; s += 2) {
            int r0 = seg_start_s[s];
            int r1 = (s + 1 < nseg) ? seg_start_s[s + 1] : TILE;
            int d = dst_s[r0];
            if (d < 0) continue;
            float sum = 0.f;
            for (int r = r0; r < r1; r++) sum += msg_f[r * MSG_LD + col];
            float* ap = &agg[(size_t)d * HD + col];
            if (s == 0 || s == nseg - 1) atomicAdd(ap, sum);
            else *ap = sum;
        }
    }
}

// ------------- graph segment-sum with LDS privatization -------------
__global__ void repr_gsum(const float* __restrict__ hh, const int* __restrict__ gids,
                          float* __restrict__ out_acc) {
    __shared__ float bins[B_GRAPHS];
    int t = threadIdx.x;
    if (t < B_GRAPHS) bins[t] = 0.f;
    __syncthreads();
    int i = blockIdx.x * 256 + t;
    if (i < N_NODES) atomicAdd(&bins[gids[i]], hh[i]);
    __syncthreads();
    if (t < B_GRAPHS && bins[t] != 0.f) atomicAdd(&out_acc[t], bins[t]);
}

__global__ void repr_final(const float* __restrict__ out_acc, float* __restrict__ out) {
    int i = threadIdx.x;
    if (i < B_GRAPHS) out[i] = out_acc[i];
}

extern "C" void kernel_launch(void* const* d_in, const int* in_sizes, int n_in,
                              void* d_out, int out_size, void* d_ws, size_t ws_size,
                              hipStream_t stream) {
    (void)in_sizes; (void)n_in; (void)out_size; (void)ws_size;
    const float* R      = (const float*)d_in[0];
    const int*   Z      = (const int*)d_in[1];
    const int*   src    = (const int*)d_in[2];
    const int*   dst    = (const int*)d_in[3];
    const int*   gids   = (const int*)d_in[4];
    const float* emb    = (const float*)d_in[5];
    const float* offs   = (const float*)d_in[6];
    const float* widths = (const float*)d_in[7];
    const float* fc_w   = (const float*)d_in[8];
    const float* attn_l = (const float*)d_in[9];
    const float* attn_r = (const float*)d_in[10];
    const float* fw1    = (const float*)d_in[11];
    const float* fb1    = (const float*)d_in[12];
    const float* fw2    = (const float*)d_in[13];
    const float* fb2    = (const float*)d_in[14];
    const float* mw1    = (const float*)d_in[15];
    const float* mb1    = (const float*)d_in[16];
    const float* mw2    = (const float*)d_in[17];
    const float* mb2    = (const float*)d_in[18];
    const float* ow1    = (const float*)d_in[19];
    const float* ob1    = (const float*)d_in[20];
    const float* ow2    = (const float*)d_in[21];
    const float* ob2    = (const float*)d_in[22];

    char* p = (char*)d_ws;
    float* x      = (float*)p; p += (size_t)N_NODES * 64 * 4;
    float* h      = (float*)p; p += (size_t)N_NODES * 128 * 4;
    float* el     = (float*)p; p += (size_t)N_NODES * 2 * 4;
    float* er     = (float*)p; p += (size_t)N_NODES * 2 * 4;
    float4* md    = (float4*)p; p += (size_t)N_NODES * 16;
    float* agg    = (float*)p; p += (size_t)N_NODES * 128 * 4;
    int*   ssrc_f = (int*)p;   p += (size_t)N_EDGES * 4;
    int*   sdst_f = (int*)p;   p += (size_t)N_EDGES * 4;
    int*   rowptr = (int*)p;   p += (size_t)N_NODES * 4;
    int*   ssrc2  = (int*)p;   p += (size_t)N_EDGES * 4;
    int*   sdst2  = (int*)p;   p += (size_t)N_EDGES * 4;
    float* r2     = (float*)p; p += (size_t)N_EDGES * 4;
    float* r_full = (float*)p; p += (size_t)N_EDGES * 4;
    float* hh     = (float*)p; p += (size_t)N_NODES * 4;
    short* w1t    = (short*)p; p += (size_t)L_LAYERS * 8192 * 2;
    short* w2t    = (short*)p; p += (size_t)L_LAYERS * 16384 * 2;
    int*   bsumA  = (int*)p;   p += 1024;
    int*   bprefA = (int*)p;   p += 1024;
    int*   bsumB  = (int*)p;   p += 1024;
    int*   bprefB = (int*)p;   p += 1024;
    int*   ecF    = (int*)p;   p += 256;
    int*   ecS    = (int*)p;   p += 256;
    float* oacc   = (float*)p; p += 256;
    int* count_f = (int*)x;
    int* excl_f  = (int*)((char*)x + 256 * 1024);
    int* cur_f   = (int*)((char*)x + 512 * 1024);
    int* count_s = (int*)((char*)x + 768 * 1024);
    int* excl_s  = (int*)((char*)x + 1024 * 1024);
    int* cur_s   = (int*)((char*)x + 1280 * 1024);

    hipMemsetAsync(x, 0, 1536 * 1024, stream);
    hipMemsetAsync(oacc, 0, B_GRAPHS * 4, stream);

    repr_prep<<<(L_LAYERS * 24576 + 255) / 256, 256, 0, stream>>>(fw1, fw2, w1t, w2t);
    repr_hist<<<N_EDGES / 256, 256, 0, stream>>>(R, src, dst, count_f, count_s, r_full);
    repr_scanA2<<<2 * NCHUNK, 256, 0, stream>>>(count_f, excl_f, bsumA,
                                                count_s, excl_s, bsumB);
    repr_scanB2<<<2, 256, 0, stream>>>(bsumA, bprefA, ecF, bsumB, bprefB, ecS);
    repr_scanC2<<<2 * NCHUNK, 256, 0, stream>>>(excl_f, bprefA, cur_f, rowptr,
                                                excl_s, bprefB, cur_s);
    repr_scatter<<<N_EDGES / 256, 256, 0, stream>>>(
        r_full, src, dst, cur_f, cur_s, ssrc_f, sdst_f, ssrc2, sdst2, r2);

    repr_embed_h<<<NBLK, 256, 0, stream>>>(
        emb, Z, fc_w, attn_l, attn_r, x, h, el, er);

    for (int l = 0; l < L_LAYERS; l++) {
        repr_alpha<<<(N_NODES * 16 + 255) / 256, 256, 0, stream>>>(
            ssrc_f, rowptr, el, er, md, agg);
        repr_msg<<<N_EDGES / TILE, 256, 0, stream>>>(
            ssrc2, sdst2, r2, ecS, el, er, md, h, offs, widths,
            w1t + (size_t)l * 8192, fb1 + (size_t)l * HID_DIM,
            w2t + (size_t)l * 16384, fb2 + (size_t)l * HD, agg);
        if (l < L_LAYERS - 1) {
            repr_mlp_h<<<NBLK, 256, 0, stream>>>(
                agg, mw1 + (size_t)l * 128 * 64, mb1 + l * 64,
                mw2 + (size_t)l * 64 * 64, mb2 + l * 64,
                fc_w + (size_t)(l + 1) * 64 * 128, attn_l + (l + 1) * 128,
                attn_r + (l + 1) * 128, x, h, el, er);
        } else {
            repr_mlp_out<<<NBLK, 256, 0, stream>>>(
                agg, mw1 + (size_t)l * 128 * 64, mb1 + l * 64,
                mw2 + (size_t)l * 64 * 64, mb2 + l * 64,
                ow1, ob1, ow2, ob2, x, hh);
        }
    }
    repr_gsum<<<NCHUNK, 256, 0, stream>>>(hh, gids, oacc);
    repr_final<<<1, 64, 0, stream>>>(oacc, (float*)d_out);
}